// Round 1
// baseline (1136.236 us; speedup 1.0000x reference)
//
#include <hip/hip_runtime.h>

// VQVAE forward: out = dec_table[argmin_k(||c_k||^2 - 2 * (x@W_enc+b_enc) . c_k)]
// Shapes: x[32768,80], W_enc[80,512], centroids[2048,512], W_dec[512,80]
#define N_TOK  32768
#define F_IN   80
#define D_DIM  512
#define K_CENT 2048
#define F_OUT  80
#define TM     16   // tokens per block in main kernel

// ---------------- prep: transpose centroids -> centT[512][2048] ----------------
__global__ void k_transpose(const float* __restrict__ cent, float* __restrict__ centT) {
    __shared__ float tile[64][65];
    int kb = blockIdx.x * 64;   // centroid rows
    int db = blockIdx.y * 64;   // dim cols
    int lx = threadIdx.x & 63, ly = threadIdx.x >> 6;  // 64 x 4
#pragma unroll
    for (int i = 0; i < 16; ++i) {
        int row = ly + i * 4;
        tile[row][lx] = cent[(size_t)(kb + row) * D_DIM + db + lx];
    }
    __syncthreads();
#pragma unroll
    for (int i = 0; i < 16; ++i) {
        int row = ly + i * 4;
        centT[(size_t)(db + row) * K_CENT + kb + lx] = tile[lx][row];
    }
}

// ---------------- prep: centroid squared norms ----------------
__global__ void k_cnorm(const float* __restrict__ cent, float* __restrict__ cnorm) {
    int wave = threadIdx.x >> 6, lane = threadIdx.x & 63;
    int k = blockIdx.x * 4 + wave;
    const float* row = cent + (size_t)k * D_DIM;
    float s = 0.f;
#pragma unroll
    for (int j = 0; j < 8; ++j) { float v = row[lane + 64 * j]; s += v * v; }
#pragma unroll
    for (int off = 32; off; off >>= 1) s += __shfl_down(s, off);
    if (lane == 0) cnorm[k] = s;
}

// ---------------- prep: decoded-centroid table dec[k][f] = cent[k] @ W_dec + b_dec ----------------
__global__ void k_dec(const float* __restrict__ cent, const float* __restrict__ Wdec,
                      const float* __restrict__ bdec, float* __restrict__ dec) {
    __shared__ float cs[D_DIM];
    int k = blockIdx.x;
    for (int d = threadIdx.x; d < D_DIM; d += blockDim.x) cs[d] = cent[(size_t)k * D_DIM + d];
    __syncthreads();
    int f = threadIdx.x;
    if (f < F_OUT) {
        float a0 = 0.f, a1 = 0.f, a2 = 0.f, a3 = 0.f;
#pragma unroll 4
        for (int d = 0; d < D_DIM; d += 4) {
            a0 += cs[d + 0] * Wdec[(d + 0) * F_OUT + f];
            a1 += cs[d + 1] * Wdec[(d + 1) * F_OUT + f];
            a2 += cs[d + 2] * Wdec[(d + 2) * F_OUT + f];
            a3 += cs[d + 3] * Wdec[(d + 3) * F_OUT + f];
        }
        dec[(size_t)k * F_OUT + f] = a0 + a1 + a2 + a3 + bdec[f];
    }
}

// ---------------- main: fused encoder + distance + argmin ----------------
// Block: 256 threads, 16 tokens. Encoder computes z-tile in LDS, then streams
// all 2048 centroids (via centT) computing dist = cnorm - 2*dot, running argmin.
__global__ __launch_bounds__(256) void k_main(
    const float* __restrict__ x, const float* __restrict__ Wenc,
    const float* __restrict__ benc, const float* __restrict__ centT,
    const float* __restrict__ cnorm, int* __restrict__ idxOut) {

    __shared__ float xs[TM * F_IN];     // 16*80 f32 = 5 KB
    __shared__ float zs[TM][D_DIM];     // 16*512 f32 = 32 KB (reused for reduction)
    float* pv = &zs[0][0];              // [256][16] f32 partial min vals
    int*   pi = (int*)(&zs[0][0] + 256 * TM);  // [256][16] argmin idx

    const int tid = threadIdx.x;
    const int tok0 = blockIdx.x * TM;

    // load x tile (coalesced)
    for (int e = tid; e < TM * F_IN; e += 256) xs[e] = x[(size_t)tok0 * F_IN + e];
    __syncthreads();

    // ---- encoder: thread owns 2 output dims d0=2*tid, d0+1 ----
    {
        float acc0[TM], acc1[TM];
#pragma unroll
        for (int t = 0; t < TM; ++t) { acc0[t] = 0.f; acc1[t] = 0.f; }
        const float2 b2 = ((const float2*)benc)[tid];
#pragma unroll 4
        for (int f4 = 0; f4 < F_IN; f4 += 4) {
            float2 w0 = ((const float2*)(Wenc + (size_t)(f4 + 0) * D_DIM))[tid];
            float2 w1 = ((const float2*)(Wenc + (size_t)(f4 + 1) * D_DIM))[tid];
            float2 w2 = ((const float2*)(Wenc + (size_t)(f4 + 2) * D_DIM))[tid];
            float2 w3 = ((const float2*)(Wenc + (size_t)(f4 + 3) * D_DIM))[tid];
#pragma unroll
            for (int t = 0; t < TM; ++t) {
                float4 xv = *(const float4*)&xs[t * F_IN + f4];
                acc0[t] += xv.x * w0.x + xv.y * w1.x + xv.z * w2.x + xv.w * w3.x;
                acc1[t] += xv.x * w0.y + xv.y * w1.y + xv.z * w2.y + xv.w * w3.y;
            }
        }
#pragma unroll
        for (int t = 0; t < TM; ++t) {
            *(float2*)&zs[t][2 * tid] = make_float2(acc0[t] + b2.x, acc1[t] + b2.y);
        }
    }
    __syncthreads();

    // ---- distance + running argmin ----
    float minv[TM]; int mini[TM];
#pragma unroll
    for (int t = 0; t < TM; ++t) { minv[t] = 3.4e38f; mini[t] = 0; }

    for (int iter = 0; iter < 2; ++iter) {
        float acc[4][TM];
#pragma unroll
        for (int j = 0; j < 4; ++j)
#pragma unroll
            for (int t = 0; t < TM; ++t) acc[j][t] = 0.f;

        const int cbase = iter * 1024 + tid;   // thread's 4 centroids: cbase + j*256
        for (int d4 = 0; d4 < D_DIM; d4 += 4) {
            float cv[4][4];
#pragma unroll
            for (int dd = 0; dd < 4; ++dd) {
                const float* cp = centT + (size_t)(d4 + dd) * K_CENT + cbase;
                cv[dd][0] = cp[0]; cv[dd][1] = cp[256]; cv[dd][2] = cp[512]; cv[dd][3] = cp[768];
            }
#pragma unroll
            for (int t = 0; t < TM; ++t) {
                float4 zv = *(const float4*)&zs[t][d4];
#pragma unroll
                for (int j = 0; j < 4; ++j) {
                    acc[j][t] += zv.x * cv[0][j] + zv.y * cv[1][j]
                               + zv.z * cv[2][j] + zv.w * cv[3][j];
                }
            }
        }
#pragma unroll
        for (int j = 0; j < 4; ++j) {
            int c = cbase + j * 256;
            float cn = cnorm[c];
#pragma unroll
            for (int t = 0; t < TM; ++t) {
                float dist = cn - 2.f * acc[j][t];
                if (dist < minv[t]) { minv[t] = dist; mini[t] = c; }
            }
        }
    }

    // ---- block-wide argmin reduction (reuse zs as pv/pi) ----
    __syncthreads();
#pragma unroll
    for (int t = 0; t < TM; ++t) { pv[tid * TM + t] = minv[t]; pi[tid * TM + t] = mini[t]; }
    __syncthreads();
    {
        int t = tid & 15, g = tid >> 4;   // 16 groups x 16 tokens
        float bv = 3.4e38f; int bi = 0x7fffffff;
        for (int j = 0; j < 16; ++j) {
            int row = g + 16 * j;
            float v = pv[row * TM + t]; int i2 = pi[row * TM + t];
            if (v < bv || (v == bv && i2 < bi)) { bv = v; bi = i2; }
        }
        pv[g * TM + t] = bv; pi[g * TM + t] = bi;
    }
    __syncthreads();
    if (tid < TM) {
        int t = tid;
        float bv = 3.4e38f; int bi = 0x7fffffff;
        for (int g = 0; g < 16; ++g) {
            float v = pv[g * TM + t]; int i2 = pi[g * TM + t];
            if (v < bv || (v == bv && i2 < bi)) { bv = v; bi = i2; }
        }
        idxOut[tok0 + t] = bi;
    }
}

// ---------------- output gather: out[n] = dec[idx[n]] ----------------
__global__ void k_out(const float* __restrict__ dec, const int* __restrict__ idx,
                      float* __restrict__ out) {
    int e0 = blockIdx.x * 2560;
#pragma unroll
    for (int r = 0; r < 10; ++r) {
        int e = e0 + threadIdx.x + r * 256;
        int n = e / F_OUT, f = e - n * F_OUT;
        out[e] = dec[(size_t)idx[n] * F_OUT + f];
    }
}

extern "C" void kernel_launch(void* const* d_in, const int* in_sizes, int n_in,
                              void* d_out, int out_size, void* d_ws, size_t ws_size,
                              hipStream_t stream) {
    const float* x    = (const float*)d_in[0];
    const float* Wenc = (const float*)d_in[1];
    const float* benc = (const float*)d_in[2];
    const float* cent = (const float*)d_in[3];
    const float* Wdec = (const float*)d_in[4];
    const float* bdec = (const float*)d_in[5];
    float* out = (float*)d_out;

    float* centT = (float*)d_ws;                     // 512*2048 f32 = 4 MB
    float* cnorm = centT + (size_t)D_DIM * K_CENT;   // 2048 f32
    float* dec   = cnorm + K_CENT;                   // 2048*80 f32 = 640 KB
    int*   idx   = (int*)(dec + (size_t)K_CENT * F_OUT);  // 32768 i32

    k_transpose<<<dim3(K_CENT / 64, D_DIM / 64), 256, 0, stream>>>(cent, centT);
    k_cnorm<<<K_CENT / 4, 256, 0, stream>>>(cent, cnorm);
    k_dec<<<K_CENT, 128, 0, stream>>>(cent, Wdec, bdec, dec);
    k_main<<<N_TOK / TM, 256, 0, stream>>>(x, Wenc, benc, centT, cnorm, idx);
    k_out<<<N_TOK * F_OUT / 2560, 256, 0, stream>>>(dec, idx, out);
}

// Round 2
// 242.316 us; speedup vs baseline: 4.6891x; 4.6891x over previous
//
#include <hip/hip_runtime.h>
#include <hip/hip_bf16.h>

#define N_TOK  32768
#define F_IN   80
#define D_DIM  512
#define K_CENT 2048
#define F_OUT  80
#define TM     16

typedef __attribute__((ext_vector_type(8))) short    bf16x8;
typedef __attribute__((ext_vector_type(4))) float    fx4;
typedef __attribute__((ext_vector_type(8))) _Float16 hx8;

#define AS3 __attribute__((address_space(3)))
#define AS1 __attribute__((address_space(1)))

__device__ inline unsigned short f2bf(float f) {
    unsigned u = __float_as_uint(f);
    return (unsigned short)((u + 0x7FFFu + ((u >> 16) & 1u)) >> 16);
}

__device__ inline void gll16(const unsigned short* g, unsigned short* l) {
    __builtin_amdgcn_global_load_lds((const AS1 unsigned*)g, (AS3 unsigned*)l, 16, 0, 0);
}

// ============================ shared prep kernels ============================
__global__ void k_cnorm(const float* __restrict__ cent, float* __restrict__ cnorm) {
    int wave = threadIdx.x >> 6, lane = threadIdx.x & 63;
    int k = blockIdx.x * 4 + wave;
    const float* row = cent + (size_t)k * D_DIM;
    float s = 0.f;
#pragma unroll
    for (int j = 0; j < 8; ++j) { float v = row[lane + 64 * j]; s += v * v; }
#pragma unroll
    for (int off = 32; off; off >>= 1) s += __shfl_down(s, off);
    if (lane == 0) cnorm[k] = s;
}

__global__ void k_dec(const float* __restrict__ cent, const float* __restrict__ Wdec,
                      const float* __restrict__ bdec, float* __restrict__ dec) {
    __shared__ float cs[D_DIM];
    int k = blockIdx.x;
    for (int d = threadIdx.x; d < D_DIM; d += blockDim.x) cs[d] = cent[(size_t)k * D_DIM + d];
    __syncthreads();
    int f = threadIdx.x;
    if (f < F_OUT) {
        float a0 = 0.f, a1 = 0.f, a2 = 0.f, a3 = 0.f;
#pragma unroll 4
        for (int d = 0; d < D_DIM; d += 4) {
            a0 += cs[d + 0] * Wdec[(d + 0) * F_OUT + f];
            a1 += cs[d + 1] * Wdec[(d + 1) * F_OUT + f];
            a2 += cs[d + 2] * Wdec[(d + 2) * F_OUT + f];
            a3 += cs[d + 3] * Wdec[(d + 3) * F_OUT + f];
        }
        dec[(size_t)k * F_OUT + f] = a0 + a1 + a2 + a3 + bdec[f];
    }
}

__global__ void k_out(const float* __restrict__ dec, const int* __restrict__ idx,
                      float* __restrict__ out) {
    int e0 = blockIdx.x * 2560;
#pragma unroll
    for (int r = 0; r < 10; ++r) {
        int e = e0 + threadIdx.x + r * 256;
        int n = e / F_OUT, f = e - n * F_OUT;
        out[e] = dec[(size_t)idx[n] * F_OUT + f];
    }
}

// ============================ fast path ============================
// cbt: pre-tiled bf16 centroids: tile (nt,kt) -> [128][32], linear 4096 elems
__global__ void k_prep_cbt(const float* __restrict__ cent, unsigned short* __restrict__ cbt) {
    int e = blockIdx.x * 256 + threadIdx.x;   // 4096 blocks
    int n = e >> 9, k = e & 511;
    cbt[(size_t)((n >> 7) * 16 + (k >> 5)) * 4096 + (n & 127) * 32 + (k & 31)] = f2bf(cent[e]);
}

// encoder -> pre-tiled bf16 z: tile (mt,kt) -> [128][32]
__global__ __launch_bounds__(256) void k_enc(
    const float* __restrict__ x, const float* __restrict__ Wenc,
    const float* __restrict__ benc, unsigned short* __restrict__ zbt) {
    __shared__ float xs[TM * F_IN];
    const int tid = threadIdx.x;
    const int tok0 = blockIdx.x * TM;
    for (int e = tid; e < TM * F_IN; e += 256) xs[e] = x[(size_t)tok0 * F_IN + e];
    __syncthreads();
    float acc0[TM], acc1[TM];
#pragma unroll
    for (int t = 0; t < TM; ++t) { acc0[t] = 0.f; acc1[t] = 0.f; }
    const float2 b2 = ((const float2*)benc)[tid];
#pragma unroll 4
    for (int f4 = 0; f4 < F_IN; f4 += 4) {
        float2 w0 = ((const float2*)(Wenc + (size_t)(f4 + 0) * D_DIM))[tid];
        float2 w1 = ((const float2*)(Wenc + (size_t)(f4 + 1) * D_DIM))[tid];
        float2 w2 = ((const float2*)(Wenc + (size_t)(f4 + 2) * D_DIM))[tid];
        float2 w3 = ((const float2*)(Wenc + (size_t)(f4 + 3) * D_DIM))[tid];
#pragma unroll
        for (int t = 0; t < TM; ++t) {
            float4 xv = *(const float4*)&xs[t * F_IN + f4];
            acc0[t] += xv.x * w0.x + xv.y * w1.x + xv.z * w2.x + xv.w * w3.x;
            acc1[t] += xv.x * w0.y + xv.y * w1.y + xv.z * w2.y + xv.w * w3.y;
        }
    }
    const int d0 = 2 * tid;
    const int kt = d0 >> 5, kl = d0 & 31;
#pragma unroll
    for (int t = 0; t < TM; ++t) {
        int m = tok0 + t;
        unsigned short u0 = f2bf(acc0[t] + b2.x);
        unsigned short u1 = f2bf(acc1[t] + b2.y);
        size_t addr = (size_t)((m >> 7) * 16 + kt) * 4096 + (m & 127) * 32 + kl;
        *(unsigned*)&zbt[addr] = (unsigned)u0 | ((unsigned)u1 << 16);
    }
}

// 128x128x512 bf16 MFMA tile -> approx distances S (f16)
__global__ __launch_bounds__(256) void k_dist(
    const unsigned short* __restrict__ zbt, const unsigned short* __restrict__ cbt,
    const float* __restrict__ cnorm, _Float16* __restrict__ S) {
    __shared__ unsigned short lds[2][2][128 * 32];   // 32 KB: [buf][A/B][4096]

    const int tid = threadIdx.x;
    const int nt = blockIdx.x, mt = blockIdx.y;
    const int lane = tid & 63;
    const int wave = tid >> 6;
    const int wm = wave >> 1, wn = wave & 1;

    const unsigned short* Abase = zbt + (size_t)mt * 16 * 4096;
    const unsigned short* Bbase = cbt + (size_t)nt * 16 * 4096;
    const int toff = tid * 8;              // per-thread src element offset
    const int woff = (tid & ~63) * 8;      // wave-uniform LDS dest element offset

    fx4 acc[4][4] = {};

    // stage tile 0
    {
        unsigned short* lA = &lds[0][0][0];
        unsigned short* lB = &lds[0][1][0];
#pragma unroll
        for (int q = 0; q < 2; ++q) {
            gll16(Abase + q * 2048 + toff, lA + q * 2048 + woff);
            gll16(Bbase + q * 2048 + toff, lB + q * 2048 + woff);
        }
    }

    int cur = 0;
    const int ar = lane & 15, ko = (lane >> 4) * 8;
    for (int kk = 0; kk < 16; ++kk) {
        __syncthreads();   // drains vmcnt: buf[cur] staged; prior reads of buf[cur^1] done
        if (kk + 1 < 16) {
            unsigned short* lA = &lds[cur ^ 1][0][0];
            unsigned short* lB = &lds[cur ^ 1][1][0];
            const unsigned short* As = Abase + (kk + 1) * 4096;
            const unsigned short* Bs = Bbase + (kk + 1) * 4096;
#pragma unroll
            for (int q = 0; q < 2; ++q) {
                gll16(As + q * 2048 + toff, lA + q * 2048 + woff);
                gll16(Bs + q * 2048 + toff, lB + q * 2048 + woff);
            }
        }
        const unsigned short* A = &lds[cur][0][0];
        const unsigned short* B = &lds[cur][1][0];
        bf16x8 a[4], b[4];
#pragma unroll
        for (int i = 0; i < 4; ++i)
            a[i] = *(const bf16x8*)&A[(wm * 64 + i * 16 + ar) * 32 + ko];
#pragma unroll
        for (int j = 0; j < 4; ++j)
            b[j] = *(const bf16x8*)&B[(wn * 64 + j * 16 + ar) * 32 + ko];
#pragma unroll
        for (int i = 0; i < 4; ++i)
#pragma unroll
            for (int j = 0; j < 4; ++j)
                acc[i][j] = __builtin_amdgcn_mfma_f32_16x16x32_bf16(a[i], b[j], acc[i][j], 0, 0, 0);
        cur ^= 1;
    }

    // epilogue: dist = ||c||^2 - 2*dot -> f16 store
    const int mb = mt * 128 + wm * 64 + ((lane >> 4) << 2);
    const int nb = nt * 128 + wn * 64 + (lane & 15);
#pragma unroll
    for (int j = 0; j < 4; ++j) {
        float cn = cnorm[nb + j * 16];
#pragma unroll
        for (int i = 0; i < 4; ++i)
#pragma unroll
            for (int r = 0; r < 4; ++r) {
                float dist = cn - 2.0f * acc[i][j][r];
                S[(size_t)(mb + i * 16 + r) * K_CENT + (nb + j * 16)] = (_Float16)dist;
            }
    }
}

// per-token: find approx min + margin candidates; exact-refine multi-candidate tokens
__global__ __launch_bounds__(256) void k_refine(
    const _Float16* __restrict__ S, const float* __restrict__ x,
    const float* __restrict__ Wenc, const float* __restrict__ benc,
    const float* __restrict__ cent, const float* __restrict__ cnorm,
    int* __restrict__ idxOut) {
    const int lane = threadIdx.x & 63;
    const int wgid = blockIdx.x * 4 + (threadIdx.x >> 6);   // 8192 waves
    for (int it = 0; it < 4; ++it) {
        const int token = wgid + it * 8192;
        const _Float16* row = S + (size_t)token * K_CENT;
        float v[32];
#pragma unroll
        for (int q = 0; q < 4; ++q) {
            hx8 h = *(const hx8*)(row + q * 512 + lane * 8);
#pragma unroll
            for (int e = 0; e < 8; ++e) v[q * 8 + e] = (float)h[e];
        }
        // lane-local argmin (ascending n order -> strict < keeps smallest idx)
        float bv = 1e30f; int bi = 1 << 30;
#pragma unroll
        for (int q = 0; q < 4; ++q)
#pragma unroll
            for (int e = 0; e < 8; ++e) {
                float val = v[q * 8 + e];
                int n = q * 512 + lane * 8 + e;
                if (val < bv) { bv = val; bi = n; }
            }
#pragma unroll
        for (int off = 1; off < 64; off <<= 1) {
            float ov = __shfl_xor(bv, off); int oi = __shfl_xor(bi, off);
            if (ov < bv || (ov == bv && oi < bi)) { bv = ov; bi = oi; }
        }
        const float thr = bv + 2.0f;   // margin >> max approx error (~1.0 incl f16 store)
        unsigned cm = 0;
#pragma unroll
        for (int q = 0; q < 4; ++q)
#pragma unroll
            for (int e = 0; e < 8; ++e)
                if (v[q * 8 + e] <= thr) cm |= 1u << (q * 8 + e);
        int tot = __popc(cm);
#pragma unroll
        for (int off = 1; off < 64; off <<= 1) tot += __shfl_xor(tot, off);
        int ans = bi;
        if (tot > 1) {
            // recompute exact z (f32), lane owns dims lane*8..lane*8+7
            float z8[8];
#pragma unroll
            for (int j = 0; j < 8; ++j) z8[j] = benc[lane * 8 + j];
            const float* xr = x + (size_t)token * F_IN;
            const float* wp = Wenc + lane * 8;
            for (int f = 0; f < F_IN; ++f) {
                float xf = xr[f];
                fx4 w0 = *(const fx4*)(wp + (size_t)f * D_DIM);
                fx4 w1 = *(const fx4*)(wp + (size_t)f * D_DIM + 4);
                z8[0] += xf * w0.x; z8[1] += xf * w0.y; z8[2] += xf * w0.z; z8[3] += xf * w0.w;
                z8[4] += xf * w1.x; z8[5] += xf * w1.y; z8[6] += xf * w1.z; z8[7] += xf * w1.w;
            }
            float bestd = 1e30f; int bestn = -1;
            unsigned long long have = __ballot(cm != 0);
            while (have) {
                int src = __ffsll(have) - 1; have &= have - 1;
                unsigned scm = (unsigned)__shfl((int)cm, src);
                while (scm) {
                    int slot = __ffs(scm) - 1; scm &= scm - 1;
                    int n = (slot >> 3) * 512 + src * 8 + (slot & 7);
                    const float* cr = cent + (size_t)n * D_DIM + lane * 8;
                    fx4 c0 = *(const fx4*)cr, c1 = *(const fx4*)(cr + 4);
                    float dp = z8[0] * c0.x + z8[1] * c0.y + z8[2] * c0.z + z8[3] * c0.w
                             + z8[4] * c1.x + z8[5] * c1.y + z8[6] * c1.z + z8[7] * c1.w;
#pragma unroll
                    for (int off = 1; off < 64; off <<= 1) dp += __shfl_xor(dp, off);
                    float d = cnorm[n] - 2.0f * dp;
                    if (d < bestd || (d == bestd && n < bestn)) { bestd = d; bestn = n; }
                }
            }
            ans = bestn;
        }
        if (lane == 0) idxOut[token] = ans;
    }
}

// ============================ fallback path (round-1, known-good) ============================
__global__ void k_transpose(const float* __restrict__ cent, float* __restrict__ centT) {
    __shared__ float tile[64][65];
    int kb = blockIdx.x * 64, db = blockIdx.y * 64;
    int lx = threadIdx.x & 63, ly = threadIdx.x >> 6;
#pragma unroll
    for (int i = 0; i < 16; ++i) {
        int row = ly + i * 4;
        tile[row][lx] = cent[(size_t)(kb + row) * D_DIM + db + lx];
    }
    __syncthreads();
#pragma unroll
    for (int i = 0; i < 16; ++i) {
        int row = ly + i * 4;
        centT[(size_t)(db + row) * K_CENT + kb + lx] = tile[lx][row];
    }
}

__global__ __launch_bounds__(256) void k_main(
    const float* __restrict__ x, const float* __restrict__ Wenc,
    const float* __restrict__ benc, const float* __restrict__ centT,
    const float* __restrict__ cnorm, int* __restrict__ idxOut) {
    __shared__ float xs[TM * F_IN];
    __shared__ float zs[TM][D_DIM];
    float* pv = &zs[0][0];
    int*   pi = (int*)(&zs[0][0] + 256 * TM);
    const int tid = threadIdx.x;
    const int tok0 = blockIdx.x * TM;
    for (int e = tid; e < TM * F_IN; e += 256) xs[e] = x[(size_t)tok0 * F_IN + e];
    __syncthreads();
    {
        float acc0[TM], acc1[TM];
#pragma unroll
        for (int t = 0; t < TM; ++t) { acc0[t] = 0.f; acc1[t] = 0.f; }
        const float2 b2 = ((const float2*)benc)[tid];
#pragma unroll 4
        for (int f4 = 0; f4 < F_IN; f4 += 4) {
            float2 w0 = ((const float2*)(Wenc + (size_t)(f4 + 0) * D_DIM))[tid];
            float2 w1 = ((const float2*)(Wenc + (size_t)(f4 + 1) * D_DIM))[tid];
            float2 w2 = ((const float2*)(Wenc + (size_t)(f4 + 2) * D_DIM))[tid];
            float2 w3 = ((const float2*)(Wenc + (size_t)(f4 + 3) * D_DIM))[tid];
#pragma unroll
            for (int t = 0; t < TM; ++t) {
                float4 xv = *(const float4*)&xs[t * F_IN + f4];
                acc0[t] += xv.x * w0.x + xv.y * w1.x + xv.z * w2.x + xv.w * w3.x;
                acc1[t] += xv.x * w0.y + xv.y * w1.y + xv.z * w2.y + xv.w * w3.y;
            }
        }
#pragma unroll
        for (int t = 0; t < TM; ++t)
            *(float2*)&zs[t][2 * tid] = make_float2(acc0[t] + b2.x, acc1[t] + b2.y);
    }
    __syncthreads();
    float minv[TM]; int mini[TM];
#pragma unroll
    for (int t = 0; t < TM; ++t) { minv[t] = 3.4e38f; mini[t] = 0; }
    for (int iter = 0; iter < 2; ++iter) {
        float acc[4][TM];
#pragma unroll
        for (int j = 0; j < 4; ++j)
#pragma unroll
            for (int t = 0; t < TM; ++t) acc[j][t] = 0.f;
        const int cbase = iter * 1024 + tid;
        for (int d4 = 0; d4 < D_DIM; d4 += 4) {
            float cv[4][4];
#pragma unroll
            for (int dd = 0; dd < 4; ++dd) {
                const float* cp = centT + (size_t)(d4 + dd) * K_CENT + cbase;
                cv[dd][0] = cp[0]; cv[dd][1] = cp[256]; cv[dd][2] = cp[512]; cv[dd][3] = cp[768];
            }
#pragma unroll
            for (int t = 0; t < TM; ++t) {
                float4 zv = *(const float4*)&zs[t][d4];
#pragma unroll
                for (int j = 0; j < 4; ++j)
                    acc[j][t] += zv.x * cv[0][j] + zv.y * cv[1][j] + zv.z * cv[2][j] + zv.w * cv[3][j];
            }
        }
#pragma unroll
        for (int j = 0; j < 4; ++j) {
            int c = cbase + j * 256;
            float cn = cnorm[c];
#pragma unroll
            for (int t = 0; t < TM; ++t) {
                float dist = cn - 2.f * acc[j][t];
                if (dist < minv[t]) { minv[t] = dist; mini[t] = c; }
            }
        }
    }
    __syncthreads();
#pragma unroll
    for (int t = 0; t < TM; ++t) { pv[tid * TM + t] = minv[t]; pi[tid * TM + t] = mini[t]; }
    __syncthreads();
    {
        int t = tid & 15, g = tid >> 4;
        float bv = 3.4e38f; int bi = 0x7fffffff;
        for (int j = 0; j < 16; ++j) {
            int r2 = g + 16 * j;
            float vv = pv[r2 * TM + t]; int i2 = pi[r2 * TM + t];
            if (vv < bv || (vv == bv && i2 < bi)) { bv = vv; bi = i2; }
        }
        pv[g * TM + t] = bv; pi[g * TM + t] = bi;
    }
    __syncthreads();
    if (tid < TM) {
        int t = tid;
        float bv = 3.4e38f; int bi = 0x7fffffff;
        for (int g = 0; g < 16; ++g) {
            float vv = pv[g * TM + t]; int i2 = pi[g * TM + t];
            if (vv < bv || (vv == bv && i2 < bi)) { bv = vv; bi = i2; }
        }
        idxOut[tok0 + t] = bi;
    }
}

// ============================ launch ============================
extern "C" void kernel_launch(void* const* d_in, const int* in_sizes, int n_in,
                              void* d_out, int out_size, void* d_ws, size_t ws_size,
                              hipStream_t stream) {
    const float* x    = (const float*)d_in[0];
    const float* Wenc = (const float*)d_in[1];
    const float* benc = (const float*)d_in[2];
    const float* cent = (const float*)d_in[3];
    const float* Wdec = (const float*)d_in[4];
    const float* bdec = (const float*)d_in[5];
    float* out = (float*)d_out;

    const size_t S_B = (size_t)N_TOK * K_CENT * 2;       // 134217728
    const size_t Z_B = (size_t)N_TOK * D_DIM * 2;        //  33554432
    const size_t C_B = (size_t)K_CENT * D_DIM * 2;       //   2097152
    const size_t N_B = (size_t)K_CENT * 4;               //      8192
    const size_t D_B = (size_t)K_CENT * F_OUT * 4;       //    655360
    const size_t I_B = (size_t)N_TOK * 4;                //    131072
    const size_t NEED = S_B + Z_B + C_B + N_B + D_B + I_B;

    if (ws_size >= NEED) {
        char* w = (char*)d_ws;
        _Float16*       Sb    = (_Float16*)w;                 w += S_B;
        unsigned short* zbt   = (unsigned short*)w;           w += Z_B;
        unsigned short* cbt   = (unsigned short*)w;           w += C_B;
        float*          cnorm = (float*)w;                    w += N_B;
        float*          dec   = (float*)w;                    w += D_B;
        int*            idx   = (int*)w;

        k_prep_cbt<<<4096, 256, 0, stream>>>(cent, cbt);
        k_cnorm<<<K_CENT / 4, 256, 0, stream>>>(cent, cnorm);
        k_dec<<<K_CENT, 128, 0, stream>>>(cent, Wdec, bdec, dec);
        k_enc<<<N_TOK / TM, 256, 0, stream>>>(x, Wenc, benc, zbt);
        k_dist<<<dim3(16, 256), 256, 0, stream>>>(zbt, cbt, cnorm, Sb);
        k_refine<<<2048, 256, 0, stream>>>(Sb, x, Wenc, benc, cent, cnorm, idx);
        k_out<<<N_TOK * F_OUT / 2560, 256, 0, stream>>>(dec, idx, out);
    } else {
        float* centT = (float*)d_ws;
        float* cnorm = centT + (size_t)D_DIM * K_CENT;
        float* dec   = cnorm + K_CENT;
        int*   idx   = (int*)(dec + (size_t)K_CENT * F_OUT);
        k_transpose<<<dim3(K_CENT / 64, D_DIM / 64), 256, 0, stream>>>(cent, centT);
        k_cnorm<<<K_CENT / 4, 256, 0, stream>>>(cent, cnorm);
        k_dec<<<K_CENT, 128, 0, stream>>>(cent, Wdec, bdec, dec);
        k_main<<<N_TOK / TM, 256, 0, stream>>>(x, Wenc, benc, centT, cnorm, idx);
        k_out<<<N_TOK * F_OUT / 2560, 256, 0, stream>>>(dec, idx, out);
    }
}

// Round 3
// 224.771 us; speedup vs baseline: 5.0551x; 1.0781x over previous
//
#include <hip/hip_runtime.h>
#include <hip/hip_bf16.h>

#define N_TOK  32768
#define F_IN   80
#define D_DIM  512
#define K_CENT 2048
#define F_OUT  80
#define TM     16
#define MARGIN 0.75f

typedef __attribute__((ext_vector_type(8))) short    bf16x8;
typedef __attribute__((ext_vector_type(4))) float    fx4;

#define AS3 __attribute__((address_space(3)))
#define AS1 __attribute__((address_space(1)))

__device__ inline unsigned short f2bf(float f) {
    unsigned u = __float_as_uint(f);
    return (unsigned short)((u + 0x7FFFu + ((u >> 16) & 1u)) >> 16);
}

__device__ inline void gll16(const unsigned short* g, unsigned short* l) {
    __builtin_amdgcn_global_load_lds((const AS1 unsigned*)g, (AS3 unsigned*)l, 16, 0, 0);
}

// monotone float<->uint key (total order, handles negatives)
__device__ inline unsigned fkey(float f) {
    unsigned b = __float_as_uint(f);
    return b ^ ((b >> 31) ? 0xFFFFFFFFu : 0x80000000u);
}
__device__ inline float keyf(unsigned k) {
    unsigned b = k ^ ((k & 0x80000000u) ? 0x80000000u : 0xFFFFFFFFu);
    return __uint_as_float(b);
}

// ============================ prep kernels ============================
__global__ void k_cnorm(const float* __restrict__ cent, float* __restrict__ cnorm) {
    int wave = threadIdx.x >> 6, lane = threadIdx.x & 63;
    int k = blockIdx.x * 4 + wave;
    const float* row = cent + (size_t)k * D_DIM;
    float s = 0.f;
#pragma unroll
    for (int j = 0; j < 8; ++j) { float v = row[lane + 64 * j]; s += v * v; }
#pragma unroll
    for (int off = 32; off; off >>= 1) s += __shfl_down(s, off);
    if (lane == 0) cnorm[k] = s;
}

__global__ void k_dec(const float* __restrict__ cent, const float* __restrict__ Wdec,
                      const float* __restrict__ bdec, float* __restrict__ dec) {
    __shared__ float cs[D_DIM];
    int k = blockIdx.x;
    for (int d = threadIdx.x; d < D_DIM; d += blockDim.x) cs[d] = cent[(size_t)k * D_DIM + d];
    __syncthreads();
    int f = threadIdx.x;
    if (f < F_OUT) {
        float a0 = 0.f, a1 = 0.f, a2 = 0.f, a3 = 0.f;
#pragma unroll 4
        for (int d = 0; d < D_DIM; d += 4) {
            a0 += cs[d + 0] * Wdec[(d + 0) * F_OUT + f];
            a1 += cs[d + 1] * Wdec[(d + 1) * F_OUT + f];
            a2 += cs[d + 2] * Wdec[(d + 2) * F_OUT + f];
            a3 += cs[d + 3] * Wdec[(d + 3) * F_OUT + f];
        }
        dec[(size_t)k * F_OUT + f] = a0 + a1 + a2 + a3 + bdec[f];
    }
}

__global__ void k_prep_cbt(const float* __restrict__ cent, unsigned short* __restrict__ cbt) {
    int e = blockIdx.x * 256 + threadIdx.x;   // 4096 blocks
    int n = e >> 9, k = e & 511;
    cbt[(size_t)((n >> 7) * 16 + (k >> 5)) * 4096 + (n & 127) * 32 + (k & 31)] = f2bf(cent[e]);
}

// ============================ encoder (f32 exact) ============================
// writes: zbt (bf16, MFMA-tiled) + zf32 (exact z for merge's refine path)
__global__ __launch_bounds__(256) void k_enc(
    const float* __restrict__ x, const float* __restrict__ Wenc,
    const float* __restrict__ benc, unsigned short* __restrict__ zbt,
    float* __restrict__ zf32) {
    __shared__ float xs[TM * F_IN];
    const int tid = threadIdx.x;
    const int tok0 = blockIdx.x * TM;
    for (int e = tid; e < TM * F_IN; e += 256) xs[e] = x[(size_t)tok0 * F_IN + e];
    __syncthreads();
    float acc0[TM], acc1[TM];
#pragma unroll
    for (int t = 0; t < TM; ++t) { acc0[t] = 0.f; acc1[t] = 0.f; }
    const float2 b2 = ((const float2*)benc)[tid];
#pragma unroll 4
    for (int f4 = 0; f4 < F_IN; f4 += 4) {
        float2 w0 = ((const float2*)(Wenc + (size_t)(f4 + 0) * D_DIM))[tid];
        float2 w1 = ((const float2*)(Wenc + (size_t)(f4 + 1) * D_DIM))[tid];
        float2 w2 = ((const float2*)(Wenc + (size_t)(f4 + 2) * D_DIM))[tid];
        float2 w3 = ((const float2*)(Wenc + (size_t)(f4 + 3) * D_DIM))[tid];
#pragma unroll
        for (int t = 0; t < TM; ++t) {
            float4 xv = *(const float4*)&xs[t * F_IN + f4];
            acc0[t] += xv.x * w0.x + xv.y * w1.x + xv.z * w2.x + xv.w * w3.x;
            acc1[t] += xv.x * w0.y + xv.y * w1.y + xv.z * w2.y + xv.w * w3.y;
        }
    }
    const int d0 = 2 * tid;
    const int kt = d0 >> 5, kl = d0 & 31;
#pragma unroll
    for (int t = 0; t < TM; ++t) {
        int m = tok0 + t;
        float z0 = acc0[t] + b2.x, z1 = acc1[t] + b2.y;
        unsigned short u0 = f2bf(z0), u1 = f2bf(z1);
        size_t addr = (size_t)((m >> 7) * 16 + kt) * 4096 + (m & 127) * 32 + kl;
        *(unsigned*)&zbt[addr] = (unsigned)u0 | ((unsigned)u1 << 16);
        *(float2*)&zf32[(size_t)m * D_DIM + d0] = make_float2(z0, z1);
    }
}

// ============================ fused distance + tile-argmin ============================
// lists layout (token-major): token stride 1024B; per nt a 64B record:
//   [0]=count(u32), [8 + 8*s] = {f32 dist, u32 centroid_idx} for s<min(count,6)
__global__ __launch_bounds__(256) void k_dist(
    const unsigned short* __restrict__ zbt, const unsigned short* __restrict__ cbt,
    const float* __restrict__ cnorm, char* __restrict__ lists) {
    __shared__ unsigned short lds[2][2][128 * 32];   // 32 KB
    __shared__ unsigned tminK[128];
    __shared__ int cnt[128];

    const int tid = threadIdx.x;
    const int nt = blockIdx.x, mt = blockIdx.y;
    const int lane = tid & 63;
    const int wave = tid >> 6;
    const int wm = wave >> 1, wn = wave & 1;

    if (tid < 128) { tminK[tid] = 0xFFFFFFFFu; cnt[tid] = 0; }

    const unsigned short* Abase = zbt + (size_t)mt * 16 * 4096;
    const unsigned short* Bbase = cbt + (size_t)nt * 16 * 4096;
    const int toff = tid * 8;
    const int woff = (tid & ~63) * 8;

    fx4 acc[4][4] = {};

    {
        unsigned short* lA = &lds[0][0][0];
        unsigned short* lB = &lds[0][1][0];
#pragma unroll
        for (int q = 0; q < 2; ++q) {
            gll16(Abase + q * 2048 + toff, lA + q * 2048 + woff);
            gll16(Bbase + q * 2048 + toff, lB + q * 2048 + woff);
        }
    }

    int cur = 0;
    const int ar = lane & 15, ko = (lane >> 4) * 8;
    for (int kk = 0; kk < 16; ++kk) {
        __syncthreads();
        if (kk + 1 < 16) {
            unsigned short* lA = &lds[cur ^ 1][0][0];
            unsigned short* lB = &lds[cur ^ 1][1][0];
            const unsigned short* As = Abase + (kk + 1) * 4096;
            const unsigned short* Bs = Bbase + (kk + 1) * 4096;
#pragma unroll
            for (int q = 0; q < 2; ++q) {
                gll16(As + q * 2048 + toff, lA + q * 2048 + woff);
                gll16(Bs + q * 2048 + toff, lB + q * 2048 + woff);
            }
        }
        const unsigned short* A = &lds[cur][0][0];
        const unsigned short* B = &lds[cur][1][0];
        bf16x8 a[4], b[4];
#pragma unroll
        for (int i = 0; i < 4; ++i)
            a[i] = *(const bf16x8*)&A[(wm * 64 + i * 16 + ar) * 32 + ko];
#pragma unroll
        for (int j = 0; j < 4; ++j)
            b[j] = *(const bf16x8*)&B[(wn * 64 + j * 16 + ar) * 32 + ko];
#pragma unroll
        for (int i = 0; i < 4; ++i)
#pragma unroll
            for (int j = 0; j < 4; ++j)
                acc[i][j] = __builtin_amdgcn_mfma_f32_16x16x32_bf16(a[i], b[j], acc[i][j], 0, 0, 0);
        cur ^= 1;
    }

    // ---- epilogue: dist, per-token tile-min, candidate push ----
    const int g = lane >> 4;     // row sub-group
    const int cl = lane & 15;    // column within 16
#pragma unroll
    for (int j = 0; j < 4; ++j) {
        float cn = cnorm[nt * 128 + wn * 64 + j * 16 + cl];
#pragma unroll
        for (int i = 0; i < 4; ++i)
#pragma unroll
            for (int r = 0; r < 4; ++r)
                acc[i][j][r] = cn - 2.0f * acc[i][j][r];
    }
    // per-token min within tile: lane-min over j, 16-lane group reduce, LDS atomicMin
#pragma unroll
    for (int i = 0; i < 4; ++i)
#pragma unroll
        for (int r = 0; r < 4; ++r) {
            float m = fminf(fminf(acc[i][0][r], acc[i][1][r]),
                            fminf(acc[i][2][r], acc[i][3][r]));
#pragma unroll
            for (int off = 1; off < 16; off <<= 1) m = fminf(m, __shfl_xor(m, off));
            if (cl == 0) atomicMin(&tminK[wm * 64 + i * 16 + g * 4 + r], fkey(m));
        }
    __syncthreads();
    // push candidates within tileMin + MARGIN
#pragma unroll
    for (int i = 0; i < 4; ++i)
#pragma unroll
        for (int r = 0; r < 4; ++r) {
            const int tr = wm * 64 + i * 16 + g * 4 + r;
            const float thr = keyf(tminK[tr]) + MARGIN;
#pragma unroll
            for (int j = 0; j < 4; ++j) {
                float d = acc[i][j][r];
                if (d <= thr) {
                    int slot = atomicAdd(&cnt[tr], 1);
                    if (slot < 6) {
                        char* rec = lists + ((size_t)(mt * 128 + tr) * 1024) + nt * 64;
                        uint2 e;
                        e.x = __float_as_uint(d);
                        e.y = (unsigned)(nt * 128 + wn * 64 + j * 16 + cl);
                        *(uint2*)(rec + 8 + slot * 8) = e;
                    }
                }
            }
        }
    __syncthreads();
    if (tid < 128)
        *(int*)(lists + ((size_t)(mt * 128 + tid) * 1024) + nt * 64) = cnt[tid];
}

// ============================ merge + exact-refine + decode gather ============================
__global__ __launch_bounds__(256) void k_merge(
    const char* __restrict__ lists, const float* __restrict__ cnorm,
    const float* __restrict__ cent, const float* __restrict__ zf32,
    const float* __restrict__ dec, float* __restrict__ out) {
    const int lane = threadIdx.x & 63;
    const int wgid = blockIdx.x * 4 + (threadIdx.x >> 6);   // 8192 waves
    const int q = lane & 3;
    for (int it = 0; it < 4; ++it) {
        const int token = wgid + it * 8192;
        const char* base = lists + (size_t)token * 1024;
        uint4 w = *(const uint4*)(base + lane * 16);   // lane covers quarter q of tile lane>>2
        int myCnt = __shfl((int)w.x, lane & ~3);
        int c6 = myCnt < 6 ? myCnt : 6;
        float dA = 1e30f, dB = 1e30f; unsigned iA = 0xFFFFFFFFu, iB = 0xFFFFFFFFu;
        bool hA = false, hB = false;
        if (q == 0)      { dA = __uint_as_float(w.z); iA = w.w; hA = (0 < c6); }
        else if (q == 1) { dA = __uint_as_float(w.x); iA = w.y; hA = (1 < c6);
                           dB = __uint_as_float(w.z); iB = w.w; hB = (2 < c6); }
        else if (q == 2) { dA = __uint_as_float(w.x); iA = w.y; hA = (3 < c6);
                           dB = __uint_as_float(w.z); iB = w.w; hB = (4 < c6); }
        else             { dA = __uint_as_float(w.x); iA = w.y; hA = (5 < c6); }
        // lane lex-min then wave lex-min (dist, idx)
        float bv = 1e30f; unsigned bi = 0xFFFFFFFFu;
        if (hA) { bv = dA; bi = iA; }
        if (hB && (dB < bv || (dB == bv && iB < bi))) { bv = dB; bi = iB; }
#pragma unroll
        for (int off = 1; off < 64; off <<= 1) {
            float ov = __shfl_xor(bv, off);
            unsigned oi = (unsigned)__shfl_xor((int)bi, off);
            if (ov < bv || (ov == bv && oi < bi)) { bv = ov; bi = oi; }
        }
        const float thr = bv + MARGIN;
        int ns = (int)(hA && dA <= thr) + (int)(hB && dB <= thr);
#pragma unroll
        for (int off = 1; off < 64; off <<= 1) ns += __shfl_xor(ns, off);
        unsigned long long ovf = __ballot(q == 0 && (int)w.x > 6);
        int ans = (int)bi;
        if (ns > 1 || ovf != 0ULL) {
            const float* zr = zf32 + (size_t)token * D_DIM + lane * 8;
            fx4 z0 = *(const fx4*)zr, z1 = *(const fx4*)(zr + 4);
            float bd = 1e30f; int bn = 0x7FFFFFFF;
#pragma unroll
            for (int rep = 0; rep < 2; ++rep) {
                bool h = rep ? hB : hA;
                float d = rep ? dB : dA;
                unsigned idv = rep ? iB : iA;
                unsigned long long m = __ballot(h && d <= thr);
                while (m) {
                    int src = __ffsll((unsigned long long)m) - 1; m &= m - 1;
                    int ci = __shfl((int)idv, src);
                    const float* cr = cent + (size_t)ci * D_DIM + lane * 8;
                    fx4 c0 = *(const fx4*)cr, c1 = *(const fx4*)(cr + 4);
                    float dp = z0.x * c0.x + z0.y * c0.y + z0.z * c0.z + z0.w * c0.w
                             + z1.x * c1.x + z1.y * c1.y + z1.z * c1.z + z1.w * c1.w;
#pragma unroll
                    for (int off = 1; off < 64; off <<= 1) dp += __shfl_xor(dp, off);
                    float de = cnorm[ci] - 2.0f * dp;
                    if (de < bd || (de == bd && ci < bn)) { bd = de; bn = ci; }
                }
            }
            // overflowed tiles: exact-scan their full 128 centroids (rare)
            unsigned long long m = ovf;
            while (m) {
                int src = __ffsll((unsigned long long)m) - 1; m &= m - 1;
                int t = src >> 2;
                for (int n0 = 0; n0 < 128; ++n0) {
                    int ci = t * 128 + n0;
                    const float* cr = cent + (size_t)ci * D_DIM + lane * 8;
                    fx4 c0 = *(const fx4*)cr, c1 = *(const fx4*)(cr + 4);
                    float dp = z0.x * c0.x + z0.y * c0.y + z0.z * c0.z + z0.w * c0.w
                             + z1.x * c1.x + z1.y * c1.y + z1.z * c1.z + z1.w * c1.w;
#pragma unroll
                    for (int off = 1; off < 64; off <<= 1) dp += __shfl_xor(dp, off);
                    float de = cnorm[ci] - 2.0f * dp;
                    if (de < bd || (de == bd && ci < bn)) { bd = de; bn = ci; }
                }
            }
            ans = bn;
        }
        // decode gather: out[token] = dec[ans]
        const float* dr = dec + (size_t)ans * F_OUT;
        float* orow = out + (size_t)token * F_OUT;
        orow[lane] = dr[lane];
        if (lane < F_OUT - 64) orow[64 + lane] = dr[64 + lane];
    }
}

// ============================ fallback path (round-1, known-good) ============================
__global__ void k_transpose(const float* __restrict__ cent, float* __restrict__ centT) {
    __shared__ float tile[64][65];
    int kb = blockIdx.x * 64, db = blockIdx.y * 64;
    int lx = threadIdx.x & 63, ly = threadIdx.x >> 6;
#pragma unroll
    for (int i = 0; i < 16; ++i) {
        int row = ly + i * 4;
        tile[row][lx] = cent[(size_t)(kb + row) * D_DIM + db + lx];
    }
    __syncthreads();
#pragma unroll
    for (int i = 0; i < 16; ++i) {
        int row = ly + i * 4;
        centT[(size_t)(db + row) * K_CENT + kb + lx] = tile[lx][row];
    }
}

__global__ void k_out(const float* __restrict__ dec, const int* __restrict__ idx,
                      float* __restrict__ out) {
    int e0 = blockIdx.x * 2560;
#pragma unroll
    for (int r = 0; r < 10; ++r) {
        int e = e0 + threadIdx.x + r * 256;
        int n = e / F_OUT, f = e - n * F_OUT;
        out[e] = dec[(size_t)idx[n] * F_OUT + f];
    }
}

__global__ __launch_bounds__(256) void k_main(
    const float* __restrict__ x, const float* __restrict__ Wenc,
    const float* __restrict__ benc, const float* __restrict__ centT,
    const float* __restrict__ cnorm, int* __restrict__ idxOut) {
    __shared__ float xs[TM * F_IN];
    __shared__ float zs[TM][D_DIM];
    float* pv = &zs[0][0];
    int*   pi = (int*)(&zs[0][0] + 256 * TM);
    const int tid = threadIdx.x;
    const int tok0 = blockIdx.x * TM;
    for (int e = tid; e < TM * F_IN; e += 256) xs[e] = x[(size_t)tok0 * F_IN + e];
    __syncthreads();
    {
        float acc0[TM], acc1[TM];
#pragma unroll
        for (int t = 0; t < TM; ++t) { acc0[t] = 0.f; acc1[t] = 0.f; }
        const float2 b2 = ((const float2*)benc)[tid];
#pragma unroll 4
        for (int f4 = 0; f4 < F_IN; f4 += 4) {
            float2 w0 = ((const float2*)(Wenc + (size_t)(f4 + 0) * D_DIM))[tid];
            float2 w1 = ((const float2*)(Wenc + (size_t)(f4 + 1) * D_DIM))[tid];
            float2 w2 = ((const float2*)(Wenc + (size_t)(f4 + 2) * D_DIM))[tid];
            float2 w3 = ((const float2*)(Wenc + (size_t)(f4 + 3) * D_DIM))[tid];
#pragma unroll
            for (int t = 0; t < TM; ++t) {
                float4 xv = *(const float4*)&xs[t * F_IN + f4];
                acc0[t] += xv.x * w0.x + xv.y * w1.x + xv.z * w2.x + xv.w * w3.x;
                acc1[t] += xv.x * w0.y + xv.y * w1.y + xv.z * w2.y + xv.w * w3.y;
            }
        }
#pragma unroll
        for (int t = 0; t < TM; ++t)
            *(float2*)&zs[t][2 * tid] = make_float2(acc0[t] + b2.x, acc1[t] + b2.y);
    }
    __syncthreads();
    float minv[TM]; int mini[TM];
#pragma unroll
    for (int t = 0; t < TM; ++t) { minv[t] = 3.4e38f; mini[t] = 0; }
    for (int iter = 0; iter < 2; ++iter) {
        float acc[4][TM];
#pragma unroll
        for (int j = 0; j < 4; ++j)
#pragma unroll
            for (int t = 0; t < TM; ++t) acc[j][t] = 0.f;
        const int cbase = iter * 1024 + tid;
        for (int d4 = 0; d4 < D_DIM; d4 += 4) {
            float cv[4][4];
#pragma unroll
            for (int dd = 0; dd < 4; ++dd) {
                const float* cp = centT + (size_t)(d4 + dd) * K_CENT + cbase;
                cv[dd][0] = cp[0]; cv[dd][1] = cp[256]; cv[dd][2] = cp[512]; cv[dd][3] = cp[768];
            }
#pragma unroll
            for (int t = 0; t < TM; ++t) {
                float4 zv = *(const float4*)&zs[t][d4];
#pragma unroll
                for (int j = 0; j < 4; ++j)
                    acc[j][t] += zv.x * cv[0][j] + zv.y * cv[1][j] + zv.z * cv[2][j] + zv.w * cv[3][j];
            }
        }
#pragma unroll
        for (int j = 0; j < 4; ++j) {
            int c = cbase + j * 256;
            float cn = cnorm[c];
#pragma unroll
            for (int t = 0; t < TM; ++t) {
                float dist = cn - 2.f * acc[j][t];
                if (dist < minv[t]) { minv[t] = dist; mini[t] = c; }
            }
        }
    }
    __syncthreads();
#pragma unroll
    for (int t = 0; t < TM; ++t) { pv[tid * TM + t] = minv[t]; pi[tid * TM + t] = mini[t]; }
    __syncthreads();
    {
        int t = tid & 15, g = tid >> 4;
        float bv = 3.4e38f; int bi = 0x7fffffff;
        for (int j = 0; j < 16; ++j) {
            int r2 = g + 16 * j;
            float vv = pv[r2 * TM + t]; int i2 = pi[r2 * TM + t];
            if (vv < bv || (vv == bv && i2 < bi)) { bv = vv; bi = i2; }
        }
        pv[g * TM + t] = bv; pi[g * TM + t] = bi;
    }
    __syncthreads();
    if (tid < TM) {
        int t = tid;
        float bv = 3.4e38f; int bi = 0x7fffffff;
        for (int g = 0; g < 16; ++g) {
            float vv = pv[g * TM + t]; int i2 = pi[g * TM + t];
            if (vv < bv || (vv == bv && i2 < bi)) { bv = vv; bi = i2; }
        }
        idxOut[tok0 + t] = bi;
    }
}

// ============================ launch ============================
extern "C" void kernel_launch(void* const* d_in, const int* in_sizes, int n_in,
                              void* d_out, int out_size, void* d_ws, size_t ws_size,
                              hipStream_t stream) {
    const float* x    = (const float*)d_in[0];
    const float* Wenc = (const float*)d_in[1];
    const float* benc = (const float*)d_in[2];
    const float* cent = (const float*)d_in[3];
    const float* Wdec = (const float*)d_in[4];
    const float* bdec = (const float*)d_in[5];
    float* out = (float*)d_out;

    const size_t L_B = (size_t)N_TOK * 1024;             // 33554432 candidate lists
    const size_t Z_B = (size_t)N_TOK * D_DIM * 2;        // 33554432 zbt (bf16 tiled)
    const size_t ZF_B = (size_t)N_TOK * D_DIM * 4;       // 67108864 zf32
    const size_t C_B = (size_t)K_CENT * D_DIM * 2;       //  2097152 cbt
    const size_t N_B = (size_t)K_CENT * 4;               //     8192 cnorm
    const size_t D_B = (size_t)K_CENT * F_OUT * 4;       //   655360 dec
    const size_t NEED = L_B + Z_B + ZF_B + C_B + N_B + D_B;

    if (ws_size >= NEED) {
        char* w = (char*)d_ws;
        char*           lists = w;                            w += L_B;
        unsigned short* zbt   = (unsigned short*)w;           w += Z_B;
        float*          zf32  = (float*)w;                    w += ZF_B;
        unsigned short* cbt   = (unsigned short*)w;           w += C_B;
        float*          cnorm = (float*)w;                    w += N_B;
        float*          dec   = (float*)w;

        k_prep_cbt<<<4096, 256, 0, stream>>>(cent, cbt);
        k_cnorm<<<K_CENT / 4, 256, 0, stream>>>(cent, cnorm);
        k_dec<<<K_CENT, 128, 0, stream>>>(cent, Wdec, bdec, dec);
        k_enc<<<N_TOK / TM, 256, 0, stream>>>(x, Wenc, benc, zbt, zf32);
        k_dist<<<dim3(16, 256), 256, 0, stream>>>(zbt, cbt, cnorm, lists);
        k_merge<<<2048, 256, 0, stream>>>(lists, cnorm, cent, zf32, dec, out);
    } else {
        float* centT = (float*)d_ws;
        float* cnorm = centT + (size_t)D_DIM * K_CENT;
        float* dec   = cnorm + K_CENT;
        int*   idx   = (int*)(dec + (size_t)K_CENT * F_OUT);
        k_transpose<<<dim3(K_CENT / 64, D_DIM / 64), 256, 0, stream>>>(cent, centT);
        k_cnorm<<<K_CENT / 4, 256, 0, stream>>>(cent, cnorm);
        k_dec<<<K_CENT, 128, 0, stream>>>(cent, Wdec, bdec, dec);
        k_main<<<N_TOK / TM, 256, 0, stream>>>(x, Wenc, benc, centT, cnorm, idx);
        k_out<<<N_TOK * F_OUT / 2560, 256, 0, stream>>>(dec, idx, out);
    }
}

// Round 4
// 219.163 us; speedup vs baseline: 5.1844x; 1.0256x over previous
//
#include <hip/hip_runtime.h>
#include <hip/hip_bf16.h>

#define N_TOK  32768
#define F_IN   80
#define D_DIM  512
#define K_CENT 2048
#define F_OUT  80
#define TM     16
#define MARGIN 0.75f

typedef __attribute__((ext_vector_type(8))) short    bf16x8;
typedef __attribute__((ext_vector_type(4))) float    fx4;

#define AS3 __attribute__((address_space(3)))
#define AS1 __attribute__((address_space(1)))

__device__ inline unsigned short f2bf(float f) {
    unsigned u = __float_as_uint(f);
    return (unsigned short)((u + 0x7FFFu + ((u >> 16) & 1u)) >> 16);
}

__device__ inline void gll16(const unsigned short* g, unsigned short* l) {
    __builtin_amdgcn_global_load_lds((const AS1 unsigned*)g, (AS3 unsigned*)l, 16, 0, 0);
}

// monotone float<->uint key (total order, handles negatives)
__device__ inline unsigned fkey(float f) {
    unsigned b = __float_as_uint(f);
    return b ^ ((b >> 31) ? 0xFFFFFFFFu : 0x80000000u);
}
__device__ inline float keyf(unsigned k) {
    unsigned b = k ^ ((k & 0x80000000u) ? 0x80000000u : 0xFFFFFFFFu);
    return __uint_as_float(b);
}

// Fragment-linear tile layout: tile(rt, kt) of [128 rows][32 k] bf16 = 4096 elems.
// Stripe s = row>>4 (1 KB each). Within stripe, element for MFMA lane L, reg j
// (row = 16s + (L&15), k = (L>>4)*8 + j) lives at s*512 + L*8 + j.
// -> ds_read_b128 at (stripe*512 + lane*8): conflict-free; staging stays linear.
__device__ inline size_t frag_addr(int row, int k) {
    // row in [0,128), k in [0,32) within a tile
    int stripe = row >> 4;
    int L = ((k >> 3) << 4) + (row & 15);
    return (size_t)stripe * 512 + L * 8 + (k & 7);
}

// ============================ prep kernels ============================
__global__ void k_cnorm(const float* __restrict__ cent, float* __restrict__ cnorm) {
    int wave = threadIdx.x >> 6, lane = threadIdx.x & 63;
    int k = blockIdx.x * 4 + wave;
    const float* row = cent + (size_t)k * D_DIM;
    float s = 0.f;
#pragma unroll
    for (int j = 0; j < 8; ++j) { float v = row[lane + 64 * j]; s += v * v; }
#pragma unroll
    for (int off = 32; off; off >>= 1) s += __shfl_down(s, off);
    if (lane == 0) cnorm[k] = s;
}

__global__ void k_dec(const float* __restrict__ cent, const float* __restrict__ Wdec,
                      const float* __restrict__ bdec, float* __restrict__ dec) {
    __shared__ float cs[D_DIM];
    int k = blockIdx.x;
    for (int d = threadIdx.x; d < D_DIM; d += blockDim.x) cs[d] = cent[(size_t)k * D_DIM + d];
    __syncthreads();
    int f = threadIdx.x;
    if (f < F_OUT) {
        float a0 = 0.f, a1 = 0.f, a2 = 0.f, a3 = 0.f;
#pragma unroll 4
        for (int d = 0; d < D_DIM; d += 4) {
            a0 += cs[d + 0] * Wdec[(d + 0) * F_OUT + f];
            a1 += cs[d + 1] * Wdec[(d + 1) * F_OUT + f];
            a2 += cs[d + 2] * Wdec[(d + 2) * F_OUT + f];
            a3 += cs[d + 3] * Wdec[(d + 3) * F_OUT + f];
        }
        dec[(size_t)k * F_OUT + f] = a0 + a1 + a2 + a3 + bdec[f];
    }
}

__global__ void k_prep_cbt(const float* __restrict__ cent, unsigned short* __restrict__ cbt) {
    int e = blockIdx.x * 256 + threadIdx.x;   // 4096 blocks
    int n = e >> 9, k = e & 511;
    size_t tile = (size_t)((n >> 7) * 16 + (k >> 5));
    cbt[tile * 4096 + frag_addr(n & 127, k & 31)] = f2bf(cent[e]);
}

// ============================ encoder (f32 exact) ============================
__global__ __launch_bounds__(256) void k_enc(
    const float* __restrict__ x, const float* __restrict__ Wenc,
    const float* __restrict__ benc, unsigned short* __restrict__ zbt,
    float* __restrict__ zf32) {
    __shared__ float xs[TM * F_IN];
    const int tid = threadIdx.x;
    const int tok0 = blockIdx.x * TM;
    for (int e = tid; e < TM * F_IN; e += 256) xs[e] = x[(size_t)tok0 * F_IN + e];
    __syncthreads();
    float acc0[TM], acc1[TM];
#pragma unroll
    for (int t = 0; t < TM; ++t) { acc0[t] = 0.f; acc1[t] = 0.f; }
    const float2 b2 = ((const float2*)benc)[tid];
#pragma unroll 4
    for (int f4 = 0; f4 < F_IN; f4 += 4) {
        float2 w0 = ((const float2*)(Wenc + (size_t)(f4 + 0) * D_DIM))[tid];
        float2 w1 = ((const float2*)(Wenc + (size_t)(f4 + 1) * D_DIM))[tid];
        float2 w2 = ((const float2*)(Wenc + (size_t)(f4 + 2) * D_DIM))[tid];
        float2 w3 = ((const float2*)(Wenc + (size_t)(f4 + 3) * D_DIM))[tid];
#pragma unroll
        for (int t = 0; t < TM; ++t) {
            float4 xv = *(const float4*)&xs[t * F_IN + f4];
            acc0[t] += xv.x * w0.x + xv.y * w1.x + xv.z * w2.x + xv.w * w3.x;
            acc1[t] += xv.x * w0.y + xv.y * w1.y + xv.z * w2.y + xv.w * w3.y;
        }
    }
    const int d0 = 2 * tid;   // even -> both elems share one u32 slot pair
    const int kt = d0 >> 5, kl = d0 & 31;
#pragma unroll
    for (int t = 0; t < TM; ++t) {
        int m = tok0 + t;
        float z0 = acc0[t] + b2.x, z1 = acc1[t] + b2.y;
        unsigned short u0 = f2bf(z0), u1 = f2bf(z1);
        size_t addr = (size_t)((m >> 7) * 16 + kt) * 4096 + frag_addr(m & 127, kl);
        *(unsigned*)&zbt[addr] = (unsigned)u0 | ((unsigned)u1 << 16);
        *(float2*)&zf32[(size_t)m * D_DIM + d0] = make_float2(z0, z1);
    }
}

// ============================ fused distance + tile-argmin ============================
// lists layout (token-major): token stride 1024B; per nt a 64B record:
//   [0]=count(u32), [8 + 8*s] = {f32 dist, u32 centroid_idx} for s<min(count,6)
__global__ __launch_bounds__(256) void k_dist(
    const unsigned short* __restrict__ zbt, const unsigned short* __restrict__ cbt,
    const float* __restrict__ cnorm, char* __restrict__ lists) {
    __shared__ unsigned short lds[2][2][128 * 32];   // 32 KB
    __shared__ unsigned tminK[128];
    __shared__ int cnt[128];

    const int tid = threadIdx.x;
    // XCD-chunked bijective swizzle (4096 blocks, 8 XCDs): each XCD gets 32
    // consecutive mt's (keeps A-tiles + all of cbt L2-resident per XCD).
    const int bid = blockIdx.x;
    const int swz = (bid & 7) * 512 + (bid >> 3);
    const int mt = swz >> 4, nt = swz & 15;
    const int lane = tid & 63;
    const int wave = tid >> 6;
    const int wm = wave >> 1, wn = wave & 1;

    if (tid < 128) { tminK[tid] = 0xFFFFFFFFu; cnt[tid] = 0; }

    const unsigned short* Abase = zbt + (size_t)mt * 16 * 4096;
    const unsigned short* Bbase = cbt + (size_t)nt * 16 * 4096;
    const int toff = tid * 8;
    const int woff = (tid & ~63) * 8;

    fx4 acc[4][4] = {};

    {
        unsigned short* lA = &lds[0][0][0];
        unsigned short* lB = &lds[0][1][0];
#pragma unroll
        for (int q = 0; q < 2; ++q) {
            gll16(Abase + q * 2048 + toff, lA + q * 2048 + woff);
            gll16(Bbase + q * 2048 + toff, lB + q * 2048 + woff);
        }
    }

    int cur = 0;
    for (int kk = 0; kk < 16; ++kk) {
        __syncthreads();
        if (kk + 1 < 16) {
            unsigned short* lA = &lds[cur ^ 1][0][0];
            unsigned short* lB = &lds[cur ^ 1][1][0];
            const unsigned short* As = Abase + (kk + 1) * 4096;
            const unsigned short* Bs = Bbase + (kk + 1) * 4096;
#pragma unroll
            for (int q = 0; q < 2; ++q) {
                gll16(As + q * 2048 + toff, lA + q * 2048 + woff);
                gll16(Bs + q * 2048 + toff, lB + q * 2048 + woff);
            }
        }
        const unsigned short* A = &lds[cur][0][0];
        const unsigned short* B = &lds[cur][1][0];
        bf16x8 a[4], b[4];
        // fragment-linear: stripe*512 + lane*8 -> conflict-free ds_read_b128
#pragma unroll
        for (int i = 0; i < 4; ++i)
            a[i] = *(const bf16x8*)&A[(wm * 4 + i) * 512 + lane * 8];
#pragma unroll
        for (int j = 0; j < 4; ++j)
            b[j] = *(const bf16x8*)&B[(wn * 4 + j) * 512 + lane * 8];
#pragma unroll
        for (int i = 0; i < 4; ++i)
#pragma unroll
            for (int j = 0; j < 4; ++j)
                acc[i][j] = __builtin_amdgcn_mfma_f32_16x16x32_bf16(a[i], b[j], acc[i][j], 0, 0, 0);
        cur ^= 1;
    }

    // ---- epilogue: dist, per-token tile-min, candidate push ----
    const int g = lane >> 4;     // row sub-group
    const int cl = lane & 15;    // column within 16
#pragma unroll
    for (int j = 0; j < 4; ++j) {
        float cn = cnorm[nt * 128 + wn * 64 + j * 16 + cl];
#pragma unroll
        for (int i = 0; i < 4; ++i)
#pragma unroll
            for (int r = 0; r < 4; ++r)
                acc[i][j][r] = cn - 2.0f * acc[i][j][r];
    }
#pragma unroll
    for (int i = 0; i < 4; ++i)
#pragma unroll
        for (int r = 0; r < 4; ++r) {
            float m = fminf(fminf(acc[i][0][r], acc[i][1][r]),
                            fminf(acc[i][2][r], acc[i][3][r]));
#pragma unroll
            for (int off = 1; off < 16; off <<= 1) m = fminf(m, __shfl_xor(m, off));
            if (cl == 0) atomicMin(&tminK[wm * 64 + i * 16 + g * 4 + r], fkey(m));
        }
    __syncthreads();
#pragma unroll
    for (int i = 0; i < 4; ++i)
#pragma unroll
        for (int r = 0; r < 4; ++r) {
            const int tr = wm * 64 + i * 16 + g * 4 + r;
            const float thr = keyf(tminK[tr]) + MARGIN;
#pragma unroll
            for (int j = 0; j < 4; ++j) {
                float d = acc[i][j][r];
                if (d <= thr) {
                    int slot = atomicAdd(&cnt[tr], 1);
                    if (slot < 6) {
                        char* rec = lists + ((size_t)(mt * 128 + tr) * 1024) + nt * 64;
                        uint2 e;
                        e.x = __float_as_uint(d);
                        e.y = (unsigned)(nt * 128 + wn * 64 + j * 16 + cl);
                        *(uint2*)(rec + 8 + slot * 8) = e;
                    }
                }
            }
        }
    __syncthreads();
    if (tid < 128)
        *(int*)(lists + ((size_t)(mt * 128 + tid) * 1024) + nt * 64) = cnt[tid];
}

// ============================ merge + exact-refine + decode gather ============================
__global__ __launch_bounds__(256) void k_merge(
    const char* __restrict__ lists, const float* __restrict__ cnorm,
    const float* __restrict__ cent, const float* __restrict__ zf32,
    const float* __restrict__ dec, float* __restrict__ out) {
    const int lane = threadIdx.x & 63;
    const int wgid = blockIdx.x * 4 + (threadIdx.x >> 6);   // 8192 waves
    const int q = lane & 3;
    for (int it = 0; it < 4; ++it) {
        const int token = wgid + it * 8192;
        const char* base = lists + (size_t)token * 1024;
        uint4 w = *(const uint4*)(base + lane * 16);   // lane covers quarter q of tile lane>>2
        int myCnt = __shfl((int)w.x, lane & ~3);
        int c6 = myCnt < 6 ? myCnt : 6;
        float dA = 1e30f, dB = 1e30f; unsigned iA = 0xFFFFFFFFu, iB = 0xFFFFFFFFu;
        bool hA = false, hB = false;
        if (q == 0)      { dA = __uint_as_float(w.z); iA = w.w; hA = (0 < c6); }
        else if (q == 1) { dA = __uint_as_float(w.x); iA = w.y; hA = (1 < c6);
                           dB = __uint_as_float(w.z); iB = w.w; hB = (2 < c6); }
        else if (q == 2) { dA = __uint_as_float(w.x); iA = w.y; hA = (3 < c6);
                           dB = __uint_as_float(w.z); iB = w.w; hB = (4 < c6); }
        else             { dA = __uint_as_float(w.x); iA = w.y; hA = (5 < c6); }
        float bv = 1e30f; unsigned bi = 0xFFFFFFFFu;
        if (hA) { bv = dA; bi = iA; }
        if (hB && (dB < bv || (dB == bv && iB < bi))) { bv = dB; bi = iB; }
#pragma unroll
        for (int off = 1; off < 64; off <<= 1) {
            float ov = __shfl_xor(bv, off);
            unsigned oi = (unsigned)__shfl_xor((int)bi, off);
            if (ov < bv || (ov == bv && oi < bi)) { bv = ov; bi = oi; }
        }
        const float thr = bv + MARGIN;
        int ns = (int)(hA && dA <= thr) + (int)(hB && dB <= thr);
#pragma unroll
        for (int off = 1; off < 64; off <<= 1) ns += __shfl_xor(ns, off);
        unsigned long long ovf = __ballot(q == 0 && (int)w.x > 6);
        int ans = (int)bi;
        if (ns > 1 || ovf != 0ULL) {
            const float* zr = zf32 + (size_t)token * D_DIM + lane * 8;
            fx4 z0 = *(const fx4*)zr, z1 = *(const fx4*)(zr + 4);
            float bd = 1e30f; int bn = 0x7FFFFFFF;
#pragma unroll
            for (int rep = 0; rep < 2; ++rep) {
                bool h = rep ? hB : hA;
                float d = rep ? dB : dA;
                unsigned idv = rep ? iB : iA;
                unsigned long long m = __ballot(h && d <= thr);
                while (m) {
                    int src = __ffsll((unsigned long long)m) - 1; m &= m - 1;
                    int ci = __shfl((int)idv, src);
                    const float* cr = cent + (size_t)ci * D_DIM + lane * 8;
                    fx4 c0 = *(const fx4*)cr, c1 = *(const fx4*)(cr + 4);
                    float dp = z0.x * c0.x + z0.y * c0.y + z0.z * c0.z + z0.w * c0.w
                             + z1.x * c1.x + z1.y * c1.y + z1.z * c1.z + z1.w * c1.w;
#pragma unroll
                    for (int off = 1; off < 64; off <<= 1) dp += __shfl_xor(dp, off);
                    float de = cnorm[ci] - 2.0f * dp;
                    if (de < bd || (de == bd && ci < bn)) { bd = de; bn = ci; }
                }
            }
            unsigned long long m = ovf;
            while (m) {
                int src = __ffsll((unsigned long long)m) - 1; m &= m - 1;
                int t = src >> 2;
                for (int n0 = 0; n0 < 128; ++n0) {
                    int ci = t * 128 + n0;
                    const float* cr = cent + (size_t)ci * D_DIM + lane * 8;
                    fx4 c0 = *(const fx4*)cr, c1 = *(const fx4*)(cr + 4);
                    float dp = z0.x * c0.x + z0.y * c0.y + z0.z * c0.z + z0.w * c0.w
                             + z1.x * c1.x + z1.y * c1.y + z1.z * c1.z + z1.w * c1.w;
#pragma unroll
                    for (int off = 1; off < 64; off <<= 1) dp += __shfl_xor(dp, off);
                    float de = cnorm[ci] - 2.0f * dp;
                    if (de < bd || (de == bd && ci < bn)) { bd = de; bn = ci; }
                }
            }
            ans = bn;
        }
        const float* dr = dec + (size_t)ans * F_OUT;
        float* orow = out + (size_t)token * F_OUT;
        orow[lane] = dr[lane];
        if (lane < F_OUT - 64) orow[64 + lane] = dr[64 + lane];
    }
}

// ============================ fallback path (round-1, known-good) ============================
__global__ void k_transpose(const float* __restrict__ cent, float* __restrict__ centT) {
    __shared__ float tile[64][65];
    int kb = blockIdx.x * 64, db = blockIdx.y * 64;
    int lx = threadIdx.x & 63, ly = threadIdx.x >> 6;
#pragma unroll
    for (int i = 0; i < 16; ++i) {
        int row = ly + i * 4;
        tile[row][lx] = cent[(size_t)(kb + row) * D_DIM + db + lx];
    }
    __syncthreads();
#pragma unroll
    for (int i = 0; i < 16; ++i) {
        int row = ly + i * 4;
        centT[(size_t)(db + row) * K_CENT + kb + lx] = tile[lx][row];
    }
}

__global__ void k_out(const float* __restrict__ dec, const int* __restrict__ idx,
                      float* __restrict__ out) {
    int e0 = blockIdx.x * 2560;
#pragma unroll
    for (int r = 0; r < 10; ++r) {
        int e = e0 + threadIdx.x + r * 256;
        int n = e / F_OUT, f = e - n * F_OUT;
        out[e] = dec[(size_t)idx[n] * F_OUT + f];
    }
}

__global__ __launch_bounds__(256) void k_main(
    const float* __restrict__ x, const float* __restrict__ Wenc,
    const float* __restrict__ benc, const float* __restrict__ centT,
    const float* __restrict__ cnorm, int* __restrict__ idxOut) {
    __shared__ float xs[TM * F_IN];
    __shared__ float zs[TM][D_DIM];
    float* pv = &zs[0][0];
    int*   pi = (int*)(&zs[0][0] + 256 * TM);
    const int tid = threadIdx.x;
    const int tok0 = blockIdx.x * TM;
    for (int e = tid; e < TM * F_IN; e += 256) xs[e] = x[(size_t)tok0 * F_IN + e];
    __syncthreads();
    {
        float acc0[TM], acc1[TM];
#pragma unroll
        for (int t = 0; t < TM; ++t) { acc0[t] = 0.f; acc1[t] = 0.f; }
        const float2 b2 = ((const float2*)benc)[tid];
#pragma unroll 4
        for (int f4 = 0; f4 < F_IN; f4 += 4) {
            float2 w0 = ((const float2*)(Wenc + (size_t)(f4 + 0) * D_DIM))[tid];
            float2 w1 = ((const float2*)(Wenc + (size_t)(f4 + 1) * D_DIM))[tid];
            float2 w2 = ((const float2*)(Wenc + (size_t)(f4 + 2) * D_DIM))[tid];
            float2 w3 = ((const float2*)(Wenc + (size_t)(f4 + 3) * D_DIM))[tid];
#pragma unroll
            for (int t = 0; t < TM; ++t) {
                float4 xv = *(const float4*)&xs[t * F_IN + f4];
                acc0[t] += xv.x * w0.x + xv.y * w1.x + xv.z * w2.x + xv.w * w3.x;
                acc1[t] += xv.x * w0.y + xv.y * w1.y + xv.z * w2.y + xv.w * w3.y;
            }
        }
#pragma unroll
        for (int t = 0; t < TM; ++t)
            *(float2*)&zs[t][2 * tid] = make_float2(acc0[t] + b2.x, acc1[t] + b2.y);
    }
    __syncthreads();
    float minv[TM]; int mini[TM];
#pragma unroll
    for (int t = 0; t < TM; ++t) { minv[t] = 3.4e38f; mini[t] = 0; }
    for (int iter = 0; iter < 2; ++iter) {
        float acc[4][TM];
#pragma unroll
        for (int j = 0; j < 4; ++j)
#pragma unroll
            for (int t = 0; t < TM; ++t) acc[j][t] = 0.f;
        const int cbase = iter * 1024 + tid;
        for (int d4 = 0; d4 < D_DIM; d4 += 4) {
            float cv[4][4];
#pragma unroll
            for (int dd = 0; dd < 4; ++dd) {
                const float* cp = centT + (size_t)(d4 + dd) * K_CENT + cbase;
                cv[dd][0] = cp[0]; cv[dd][1] = cp[256]; cv[dd][2] = cp[512]; cv[dd][3] = cp[768];
            }
#pragma unroll
            for (int t = 0; t < TM; ++t) {
                float4 zv = *(const float4*)&zs[t][d4];
#pragma unroll
                for (int j = 0; j < 4; ++j)
                    acc[j][t] += zv.x * cv[0][j] + zv.y * cv[1][j] + zv.z * cv[2][j] + zv.w * cv[3][j];
            }
        }
#pragma unroll
        for (int j = 0; j < 4; ++j) {
            int c = cbase + j * 256;
            float cn = cnorm[c];
#pragma unroll
            for (int t = 0; t < TM; ++t) {
                float dist = cn - 2.f * acc[j][t];
                if (dist < minv[t]) { minv[t] = dist; mini[t] = c; }
            }
        }
    }
    __syncthreads();
#pragma unroll
    for (int t = 0; t < TM; ++t) { pv[tid * TM + t] = minv[t]; pi[tid * TM + t] = mini[t]; }
    __syncthreads();
    {
        int t = tid & 15, g = tid >> 4;
        float bv = 3.4e38f; int bi = 0x7fffffff;
        for (int j = 0; j < 16; ++j) {
            int r2 = g + 16 * j;
            float vv = pv[r2 * TM + t]; int i2 = pi[r2 * TM + t];
            if (vv < bv || (vv == bv && i2 < bi)) { bv = vv; bi = i2; }
        }
        pv[g * TM + t] = bv; pi[g * TM + t] = bi;
    }
    __syncthreads();
    if (tid < TM) {
        int t = tid;
        float bv = 3.4e38f; int bi = 0x7fffffff;
        for (int g = 0; g < 16; ++g) {
            float vv = pv[g * TM + t]; int i2 = pi[g * TM + t];
            if (vv < bv || (vv == bv && i2 < bi)) { bv = vv; bi = i2; }
        }
        idxOut[tok0 + t] = bi;
    }
}

// ============================ launch ============================
extern "C" void kernel_launch(void* const* d_in, const int* in_sizes, int n_in,
                              void* d_out, int out_size, void* d_ws, size_t ws_size,
                              hipStream_t stream) {
    const float* x    = (const float*)d_in[0];
    const float* Wenc = (const float*)d_in[1];
    const float* benc = (const float*)d_in[2];
    const float* cent = (const float*)d_in[3];
    const float* Wdec = (const float*)d_in[4];
    const float* bdec = (const float*)d_in[5];
    float* out = (float*)d_out;

    const size_t L_B = (size_t)N_TOK * 1024;             // 33554432 candidate lists
    const size_t Z_B = (size_t)N_TOK * D_DIM * 2;        // 33554432 zbt (bf16 tiled)
    const size_t ZF_B = (size_t)N_TOK * D_DIM * 4;       // 67108864 zf32
    const size_t C_B = (size_t)K_CENT * D_DIM * 2;       //  2097152 cbt
    const size_t N_B = (size_t)K_CENT * 4;               //     8192 cnorm
    const size_t D_B = (size_t)K_CENT * F_OUT * 4;       //   655360 dec
    const size_t NEED = L_B + Z_B + ZF_B + C_B + N_B + D_B;

    if (ws_size >= NEED) {
        char* w = (char*)d_ws;
        char*           lists = w;                            w += L_B;
        unsigned short* zbt   = (unsigned short*)w;           w += Z_B;
        float*          zf32  = (float*)w;                    w += ZF_B;
        unsigned short* cbt   = (unsigned short*)w;           w += C_B;
        float*          cnorm = (float*)w;                    w += N_B;
        float*          dec   = (float*)w;

        k_prep_cbt<<<4096, 256, 0, stream>>>(cent, cbt);
        k_cnorm<<<K_CENT / 4, 256, 0, stream>>>(cent, cnorm);
        k_dec<<<K_CENT, 128, 0, stream>>>(cent, Wdec, bdec, dec);
        k_enc<<<N_TOK / TM, 256, 0, stream>>>(x, Wenc, benc, zbt, zf32);
        k_dist<<<4096, 256, 0, stream>>>(zbt, cbt, cnorm, lists);
        k_merge<<<2048, 256, 0, stream>>>(lists, cnorm, cent, zf32, dec, out);
    } else {
        float* centT = (float*)d_ws;
        float* cnorm = centT + (size_t)D_DIM * K_CENT;
        float* dec   = cnorm + K_CENT;
        int*   idx   = (int*)(dec + (size_t)K_CENT * F_OUT);
        k_transpose<<<dim3(K_CENT / 64, D_DIM / 64), 256, 0, stream>>>(cent, centT);
        k_cnorm<<<K_CENT / 4, 256, 0, stream>>>(cent, cnorm);
        k_dec<<<K_CENT, 128, 0, stream>>>(cent, Wdec, bdec, dec);
        k_main<<<N_TOK / TM, 256, 0, stream>>>(x, Wenc, benc, centT, cnorm, idx);
        k_out<<<N_TOK * F_OUT / 2560, 256, 0, stream>>>(dec, idx, out);
    }
}

// Round 5
// 184.153 us; speedup vs baseline: 6.1701x; 1.1901x over previous
//
#include <hip/hip_runtime.h>
#include <hip/hip_bf16.h>

#define N_TOK  32768
#define F_IN   80
#define D_DIM  512
#define K_CENT 2048
#define F_OUT  80
#define TM     16
#define KP     96      // padded rank (F_IN -> 3 K-steps of 32)
#define MARGIN 1.0f

typedef __attribute__((ext_vector_type(8))) short    bf16x8;
typedef __attribute__((ext_vector_type(4))) float    fx4;

#define AS3 __attribute__((address_space(3)))
#define AS1 __attribute__((address_space(1)))

__device__ inline unsigned short f2bf(float f) {
    unsigned u = __float_as_uint(f);
    return (unsigned short)((u + 0x7FFFu + ((u >> 16) & 1u)) >> 16);
}

__device__ inline void gll16(const unsigned short* g, unsigned short* l) {
    __builtin_amdgcn_global_load_lds((const AS1 unsigned*)g, (AS3 unsigned*)l, 16, 0, 0);
}

__device__ inline unsigned fkey(float f) {
    unsigned b = __float_as_uint(f);
    return b ^ ((b >> 31) ? 0xFFFFFFFFu : 0x80000000u);
}
__device__ inline float keyf(unsigned k) {
    unsigned b = k ^ ((k & 0x80000000u) ? 0x80000000u : 0xFFFFFFFFu);
    return __uint_as_float(b);
}

// Fragment-linear tile: [128 rows][32 k] bf16 = 4096 elems, stripe s=row>>4,
// lane L = ((k>>3)<<4)+(row&15): elem at s*512 + L*8 + (k&7).
__device__ inline size_t frag_addr(int row, int k) {
    int stripe = row >> 4;
    int L = ((k >> 3) << 4) + (row & 15);
    return (size_t)stripe * 512 + L * 8 + (k & 7);
}

// ============================ prep kernels ============================
// cnorm[k] = ||c_k||^2 ; cadj[k] = ||c_k||^2 - 2 b.c_k
__global__ void k_cadj(const float* __restrict__ cent, const float* __restrict__ benc,
                       float* __restrict__ cnorm, float* __restrict__ cadj) {
    int wave = threadIdx.x >> 6, lane = threadIdx.x & 63;
    int k = blockIdx.x * 4 + wave;
    const float* row = cent + (size_t)k * D_DIM;
    float s = 0.f, t = 0.f;
#pragma unroll
    for (int j = 0; j < 8; ++j) {
        float c = row[lane + 64 * j];
        float b = benc[lane + 64 * j];
        s += c * c; t += b * c;
    }
#pragma unroll
    for (int off = 32; off; off >>= 1) { s += __shfl_down(s, off); t += __shfl_down(t, off); }
    if (lane == 0) { cnorm[k] = s; cadj[k] = s - 2.0f * t; }
}

__global__ void k_dec(const float* __restrict__ cent, const float* __restrict__ Wdec,
                      const float* __restrict__ bdec, float* __restrict__ dec) {
    __shared__ float cs[D_DIM];
    int k = blockIdx.x;
    for (int d = threadIdx.x; d < D_DIM; d += blockDim.x) cs[d] = cent[(size_t)k * D_DIM + d];
    __syncthreads();
    int f = threadIdx.x;
    if (f < F_OUT) {
        float a0 = 0.f, a1 = 0.f, a2 = 0.f, a3 = 0.f;
#pragma unroll 4
        for (int d = 0; d < D_DIM; d += 4) {
            a0 += cs[d + 0] * Wdec[(d + 0) * F_OUT + f];
            a1 += cs[d + 1] * Wdec[(d + 1) * F_OUT + f];
            a2 += cs[d + 2] * Wdec[(d + 2) * F_OUT + f];
            a3 += cs[d + 3] * Wdec[(d + 3) * F_OUT + f];
        }
        dec[(size_t)k * F_OUT + f] = a0 + a1 + a2 + a3 + bdec[f];
    }
}

// cent -> cbt bf16 tiled [16 nt][16 kt][4096]  (B-operand of the G GEMM)
__global__ void k_prep_cbt(const float* __restrict__ cent, unsigned short* __restrict__ cbt) {
    int e = blockIdx.x * 256 + threadIdx.x;   // 4096 blocks
    int n = e >> 9, k = e & 511;
    size_t tile = (size_t)((n >> 7) * 16 + (k >> 5));
    cbt[tile * 4096 + frag_addr(n & 127, k & 31)] = f2bf(cent[e]);
}

// Wenc [80,512] -> wbt bf16 tiled [16 kt][4096], rows 80..127 zero
__global__ void k_prep_wbt(const float* __restrict__ Wenc, unsigned short* __restrict__ wbt) {
    int kt = blockIdx.x;   // 16
    int tid = threadIdx.x;
    int a0 = tid * 16;
    int s = a0 >> 9;
    int L0 = (tid * 2) & 63;
    int row0 = s * 16 + (L0 & 15);
    int kg = kt * 32 + (L0 >> 4) * 8;
    unsigned short u[16];
#pragma unroll
    for (int rr = 0; rr < 2; ++rr) {
        int row = row0 + rr;
        if (row < F_IN) {
            const float* src = Wenc + (size_t)row * D_DIM + kg;
            float4 v0 = *(const float4*)src;
            float4 v1 = *(const float4*)(src + 4);
            u[rr*8+0]=f2bf(v0.x); u[rr*8+1]=f2bf(v0.y); u[rr*8+2]=f2bf(v0.z); u[rr*8+3]=f2bf(v0.w);
            u[rr*8+4]=f2bf(v1.x); u[rr*8+5]=f2bf(v1.y); u[rr*8+6]=f2bf(v1.z); u[rr*8+7]=f2bf(v1.w);
        } else {
#pragma unroll
            for (int j = 0; j < 8; ++j) u[rr*8+j] = 0;
        }
    }
    unsigned short* dst = wbt + (size_t)kt * 4096 + a0;
#pragma unroll
    for (int j = 0; j < 16; ++j) dst[j] = u[j];
}

// x [32768,80] -> xbt bf16 tiled [256 mt][3 kt][4096], k 80..95 zero
__global__ void k_prep_xbt(const float* __restrict__ x, unsigned short* __restrict__ xbt) {
    int tile = blockIdx.x;   // 768 = 256 mt * 3 kt
    int mt = tile / 3, kt = tile - mt * 3;
    int tid = threadIdx.x;
    int a0 = tid * 16;
    int s = a0 >> 9;
    int L0 = (tid * 2) & 63;
    int row0 = s * 16 + (L0 & 15);
    int kg = kt * 32 + (L0 >> 4) * 8;
    bool valid = kg < F_IN;   // whole 8-group valid or pad (80 % 8 == 0)
    unsigned short u[16];
#pragma unroll
    for (int rr = 0; rr < 2; ++rr) {
        int row = row0 + rr;
        if (valid) {
            const float* src = x + (size_t)(mt * 128 + row) * F_IN + kg;
            float4 v0 = *(const float4*)src;
            float4 v1 = *(const float4*)(src + 4);
            u[rr*8+0]=f2bf(v0.x); u[rr*8+1]=f2bf(v0.y); u[rr*8+2]=f2bf(v0.z); u[rr*8+3]=f2bf(v0.w);
            u[rr*8+4]=f2bf(v1.x); u[rr*8+5]=f2bf(v1.y); u[rr*8+6]=f2bf(v1.z); u[rr*8+7]=f2bf(v1.w);
        } else {
#pragma unroll
            for (int j = 0; j < 8; ++j) u[rr*8+j] = 0;
        }
    }
    unsigned short* dst = xbt + (size_t)tile * 4096 + a0;
#pragma unroll
    for (int j = 0; j < 16; ++j) dst[j] = u[j];
}

// G = Wenc @ cent^T  via bf16 MFMA: A=wbt [128 x 512], B=cbt slice [128 x 512].
// 16 blocks (nt). Epilogue stores bf16 G into Gbt [16 nt][3 kt][4096] (f<96).
__global__ __launch_bounds__(256) void k_gemm_g(
    const unsigned short* __restrict__ wbt, const unsigned short* __restrict__ cbt,
    unsigned short* __restrict__ Gbt) {
    __shared__ unsigned short lds[2][2][4096];
    const int tid = threadIdx.x;
    const int nt = blockIdx.x;
    const int lane = tid & 63;
    const int wave = tid >> 6;
    const int wm = wave >> 1, wn = wave & 1;

    const unsigned short* Bbase = cbt + (size_t)nt * 16 * 4096;
    const int toff = tid * 8;
    const int woff = (tid & ~63) * 8;

    fx4 acc[4][4] = {};
    {
#pragma unroll
        for (int q = 0; q < 2; ++q) {
            gll16(wbt + q * 2048 + toff, &lds[0][0][0] + q * 2048 + woff);
            gll16(Bbase + q * 2048 + toff, &lds[0][1][0] + q * 2048 + woff);
        }
    }
    int cur = 0;
    for (int kk = 0; kk < 16; ++kk) {
        __syncthreads();
        if (kk + 1 < 16) {
#pragma unroll
            for (int q = 0; q < 2; ++q) {
                gll16(wbt + (kk + 1) * 4096 + q * 2048 + toff, &lds[cur ^ 1][0][0] + q * 2048 + woff);
                gll16(Bbase + (kk + 1) * 4096 + q * 2048 + toff, &lds[cur ^ 1][1][0] + q * 2048 + woff);
            }
        }
        const unsigned short* A = &lds[cur][0][0];
        const unsigned short* B = &lds[cur][1][0];
        bf16x8 a[4], b[4];
#pragma unroll
        for (int i = 0; i < 4; ++i) a[i] = *(const bf16x8*)&A[(wm * 4 + i) * 512 + lane * 8];
#pragma unroll
        for (int j = 0; j < 4; ++j) b[j] = *(const bf16x8*)&B[(wn * 4 + j) * 512 + lane * 8];
#pragma unroll
        for (int i = 0; i < 4; ++i)
#pragma unroll
            for (int j = 0; j < 4; ++j)
                acc[i][j] = __builtin_amdgcn_mfma_f32_16x16x32_bf16(a[i], b[j], acc[i][j], 0, 0, 0);
        cur ^= 1;
    }
    const int g = lane >> 4, cl = lane & 15;
#pragma unroll
    for (int j = 0; j < 4; ++j) {
        int colLoc = wn * 64 + j * 16 + cl;   // centroid within 128
#pragma unroll
        for (int i = 0; i < 4; ++i)
#pragma unroll
            for (int r = 0; r < 4; ++r) {
                int f = wm * 64 + i * 16 + g * 4 + r;
                if (f < KP)
                    Gbt[(size_t)(nt * 3 + (f >> 5)) * 4096 + frag_addr(colLoc, f & 31)]
                        = f2bf(acc[i][j][r]);
            }
    }
}

// ============================ encoder (f32 exact, refine input) ============================
__global__ __launch_bounds__(256) void k_enc(
    const float* __restrict__ x, const float* __restrict__ Wenc,
    const float* __restrict__ benc, float* __restrict__ zf32) {
    __shared__ float xs[TM * F_IN];
    const int tid = threadIdx.x;
    const int tok0 = blockIdx.x * TM;
    for (int e = tid; e < TM * F_IN; e += 256) xs[e] = x[(size_t)tok0 * F_IN + e];
    __syncthreads();
    float acc0[TM], acc1[TM];
#pragma unroll
    for (int t = 0; t < TM; ++t) { acc0[t] = 0.f; acc1[t] = 0.f; }
    const float2 b2 = ((const float2*)benc)[tid];
#pragma unroll 4
    for (int f4 = 0; f4 < F_IN; f4 += 4) {
        float2 w0 = ((const float2*)(Wenc + (size_t)(f4 + 0) * D_DIM))[tid];
        float2 w1 = ((const float2*)(Wenc + (size_t)(f4 + 1) * D_DIM))[tid];
        float2 w2 = ((const float2*)(Wenc + (size_t)(f4 + 2) * D_DIM))[tid];
        float2 w3 = ((const float2*)(Wenc + (size_t)(f4 + 3) * D_DIM))[tid];
#pragma unroll
        for (int t = 0; t < TM; ++t) {
            float4 xv = *(const float4*)&xs[t * F_IN + f4];
            acc0[t] += xv.x * w0.x + xv.y * w1.x + xv.z * w2.x + xv.w * w3.x;
            acc1[t] += xv.x * w0.y + xv.y * w1.y + xv.z * w2.y + xv.w * w3.y;
        }
    }
    const int d0 = 2 * tid;
#pragma unroll
    for (int t = 0; t < TM; ++t) {
        int m = tok0 + t;
        *(float2*)&zf32[(size_t)m * D_DIM + d0] = make_float2(acc0[t] + b2.x, acc1[t] + b2.y);
    }
}

// ============================ fused distance + tile-argmin (rank-80) ============================
// A = xbt tile [128 x 96], B = Gbt tile [128 x 96]. Single-stage LDS (48 KB),
// ONE barrier, 3 K-steps x 16 MFMA. dist = cadj - 2*(x.G). Same lists format.
__global__ __launch_bounds__(256) void k_dist(
    const unsigned short* __restrict__ xbt, const unsigned short* __restrict__ Gbt,
    const float* __restrict__ cadj, char* __restrict__ lists) {
    __shared__ unsigned short lds[6 * 4096];   // A: [0,12288) B: [12288,24576)
    __shared__ unsigned tminK[128];
    __shared__ int cnt[128];

    const int tid = threadIdx.x;
    const int bid = blockIdx.x;
    const int swz = (bid & 7) * 512 + (bid >> 3);   // XCD-chunked bijective
    const int mt = swz >> 4, nt = swz & 15;
    const int lane = tid & 63;
    const int wave = tid >> 6;
    const int wm = wave >> 1, wn = wave & 1;

    if (tid < 128) { tminK[tid] = 0xFFFFFFFFu; cnt[tid] = 0; }

    const unsigned short* Abase = xbt + (size_t)mt * 3 * 4096;
    const unsigned short* Bbase = Gbt + (size_t)nt * 3 * 4096;
    const int toff = tid * 8;
    const int woff = (tid & ~63) * 8;

    // stage entire A (12288 elems) + B (12288 elems): 12 x gll16 per thread
#pragma unroll
    for (int q = 0; q < 6; ++q) gll16(Abase + q * 2048 + toff, lds + q * 2048 + woff);
#pragma unroll
    for (int q = 0; q < 6; ++q) gll16(Bbase + q * 2048 + toff, lds + 12288 + q * 2048 + woff);

    fx4 acc[4][4] = {};
    __syncthreads();   // single barrier: drains the 12 loads

#pragma unroll
    for (int kt = 0; kt < 3; ++kt) {
        const unsigned short* A = lds + kt * 4096;
        const unsigned short* B = lds + 12288 + kt * 4096;
        bf16x8 a[4], b[4];
#pragma unroll
        for (int i = 0; i < 4; ++i) a[i] = *(const bf16x8*)&A[(wm * 4 + i) * 512 + lane * 8];
#pragma unroll
        for (int j = 0; j < 4; ++j) b[j] = *(const bf16x8*)&B[(wn * 4 + j) * 512 + lane * 8];
#pragma unroll
        for (int i = 0; i < 4; ++i)
#pragma unroll
            for (int j = 0; j < 4; ++j)
                acc[i][j] = __builtin_amdgcn_mfma_f32_16x16x32_bf16(a[i], b[j], acc[i][j], 0, 0, 0);
    }

    // ---- epilogue: dist, per-token tile-min, candidate push ----
    const int g = lane >> 4;
    const int cl = lane & 15;
#pragma unroll
    for (int j = 0; j < 4; ++j) {
        float cn = cadj[nt * 128 + wn * 64 + j * 16 + cl];
#pragma unroll
        for (int i = 0; i < 4; ++i)
#pragma unroll
            for (int r = 0; r < 4; ++r)
                acc[i][j][r] = cn - 2.0f * acc[i][j][r];
    }
#pragma unroll
    for (int i = 0; i < 4; ++i)
#pragma unroll
        for (int r = 0; r < 4; ++r) {
            float m = fminf(fminf(acc[i][0][r], acc[i][1][r]),
                            fminf(acc[i][2][r], acc[i][3][r]));
#pragma unroll
            for (int off = 1; off < 16; off <<= 1) m = fminf(m, __shfl_xor(m, off));
            if (cl == 0) atomicMin(&tminK[wm * 64 + i * 16 + g * 4 + r], fkey(m));
        }
    __syncthreads();
#pragma unroll
    for (int i = 0; i < 4; ++i)
#pragma unroll
        for (int r = 0; r < 4; ++r) {
            const int tr = wm * 64 + i * 16 + g * 4 + r;
            const float thr = keyf(tminK[tr]) + MARGIN;
#pragma unroll
            for (int j = 0; j < 4; ++j) {
                float d = acc[i][j][r];
                if (d <= thr) {
                    int slot = atomicAdd(&cnt[tr], 1);
                    if (slot < 6) {
                        char* rec = lists + ((size_t)(mt * 128 + tr) * 1024) + nt * 64;
                        uint2 e;
                        e.x = __float_as_uint(d);
                        e.y = (unsigned)(nt * 128 + wn * 64 + j * 16 + cl);
                        *(uint2*)(rec + 8 + slot * 8) = e;
                    }
                }
            }
        }
    __syncthreads();
    if (tid < 128)
        *(int*)(lists + ((size_t)(mt * 128 + tid) * 1024) + nt * 64) = cnt[tid];
}

// ============================ merge + exact-refine + decode gather ============================
__global__ __launch_bounds__(256) void k_merge(
    const char* __restrict__ lists, const float* __restrict__ cnorm,
    const float* __restrict__ cent, const float* __restrict__ zf32,
    const float* __restrict__ dec, float* __restrict__ out) {
    const int lane = threadIdx.x & 63;
    const int wgid = blockIdx.x * 4 + (threadIdx.x >> 6);   // 8192 waves
    const int q = lane & 3;
    for (int it = 0; it < 4; ++it) {
        const int token = wgid + it * 8192;
        const char* base = lists + (size_t)token * 1024;
        uint4 w = *(const uint4*)(base + lane * 16);
        int myCnt = __shfl((int)w.x, lane & ~3);
        int c6 = myCnt < 6 ? myCnt : 6;
        float dA = 1e30f, dB = 1e30f; unsigned iA = 0xFFFFFFFFu, iB = 0xFFFFFFFFu;
        bool hA = false, hB = false;
        if (q == 0)      { dA = __uint_as_float(w.z); iA = w.w; hA = (0 < c6); }
        else if (q == 1) { dA = __uint_as_float(w.x); iA = w.y; hA = (1 < c6);
                           dB = __uint_as_float(w.z); iB = w.w; hB = (2 < c6); }
        else if (q == 2) { dA = __uint_as_float(w.x); iA = w.y; hA = (3 < c6);
                           dB = __uint_as_float(w.z); iB = w.w; hB = (4 < c6); }
        else             { dA = __uint_as_float(w.x); iA = w.y; hA = (5 < c6); }
        float bv = 1e30f; unsigned bi = 0xFFFFFFFFu;
        if (hA) { bv = dA; bi = iA; }
        if (hB && (dB < bv || (dB == bv && iB < bi))) { bv = dB; bi = iB; }
#pragma unroll
        for (int off = 1; off < 64; off <<= 1) {
            float ov = __shfl_xor(bv, off);
            unsigned oi = (unsigned)__shfl_xor((int)bi, off);
            if (ov < bv || (ov == bv && oi < bi)) { bv = ov; bi = oi; }
        }
        const float thr = bv + MARGIN;
        int ns = (int)(hA && dA <= thr) + (int)(hB && dB <= thr);
#pragma unroll
        for (int off = 1; off < 64; off <<= 1) ns += __shfl_xor(ns, off);
        unsigned long long ovf = __ballot(q == 0 && (int)w.x > 6);
        int ans = (int)bi;
        if (ns > 1 || ovf != 0ULL) {
            const float* zr = zf32 + (size_t)token * D_DIM + lane * 8;
            fx4 z0 = *(const fx4*)zr, z1 = *(const fx4*)(zr + 4);
            float bd = 1e30f; int bn = 0x7FFFFFFF;
#pragma unroll
            for (int rep = 0; rep < 2; ++rep) {
                bool h = rep ? hB : hA;
                float d = rep ? dB : dA;
                unsigned idv = rep ? iB : iA;
                unsigned long long m = __ballot(h && d <= thr);
                while (m) {
                    int src = __ffsll((unsigned long long)m) - 1; m &= m - 1;
                    int ci = __shfl((int)idv, src);
                    const float* cr = cent + (size_t)ci * D_DIM + lane * 8;
                    fx4 c0 = *(const fx4*)cr, c1 = *(const fx4*)(cr + 4);
                    float dp = z0.x * c0.x + z0.y * c0.y + z0.z * c0.z + z0.w * c0.w
                             + z1.x * c1.x + z1.y * c1.y + z1.z * c1.z + z1.w * c1.w;
#pragma unroll
                    for (int off = 1; off < 64; off <<= 1) dp += __shfl_xor(dp, off);
                    float de = cnorm[ci] - 2.0f * dp;
                    if (de < bd || (de == bd && ci < bn)) { bd = de; bn = ci; }
                }
            }
            unsigned long long m = ovf;
            while (m) {
                int src = __ffsll((unsigned long long)m) - 1; m &= m - 1;
                int t = src >> 2;
                for (int n0 = 0; n0 < 128; ++n0) {
                    int ci = t * 128 + n0;
                    const float* cr = cent + (size_t)ci * D_DIM + lane * 8;
                    fx4 c0 = *(const fx4*)cr, c1 = *(const fx4*)(cr + 4);
                    float dp = z0.x * c0.x + z0.y * c0.y + z0.z * c0.z + z0.w * c0.w
                             + z1.x * c1.x + z1.y * c1.y + z1.z * c1.z + z1.w * c1.w;
#pragma unroll
                    for (int off = 1; off < 64; off <<= 1) dp += __shfl_xor(dp, off);
                    float de = cnorm[ci] - 2.0f * dp;
                    if (de < bd || (de == bd && ci < bn)) { bd = de; bn = ci; }
                }
            }
            ans = bn;
        }
        const float* dr = dec + (size_t)ans * F_OUT;
        float* orow = out + (size_t)token * F_OUT;
        orow[lane] = dr[lane];
        if (lane < F_OUT - 64) orow[64 + lane] = dr[64 + lane];
    }
}

// ============================ fallback path (round-1, known-good) ============================
__global__ void k_transpose(const float* __restrict__ cent, float* __restrict__ centT) {
    __shared__ float tile[64][65];
    int kb = blockIdx.x * 64, db = blockIdx.y * 64;
    int lx = threadIdx.x & 63, ly = threadIdx.x >> 6;
#pragma unroll
    for (int i = 0; i < 16; ++i) {
        int row = ly + i * 4;
        tile[row][lx] = cent[(size_t)(kb + row) * D_DIM + db + lx];
    }
    __syncthreads();
#pragma unroll
    for (int i = 0; i < 16; ++i) {
        int row = ly + i * 4;
        centT[(size_t)(db + row) * K_CENT + kb + lx] = tile[lx][row];
    }
}

__global__ void k_out(const float* __restrict__ dec, const int* __restrict__ idx,
                      float* __restrict__ out) {
    int e0 = blockIdx.x * 2560;
#pragma unroll
    for (int r = 0; r < 10; ++r) {
        int e = e0 + threadIdx.x + r * 256;
        int n = e / F_OUT, f = e - n * F_OUT;
        out[e] = dec[(size_t)idx[n] * F_OUT + f];
    }
}

__global__ __launch_bounds__(256) void k_main(
    const float* __restrict__ x, const float* __restrict__ Wenc,
    const float* __restrict__ benc, const float* __restrict__ centT,
    const float* __restrict__ cnorm, int* __restrict__ idxOut) {
    __shared__ float xs[TM * F_IN];
    __shared__ float zs[TM][D_DIM];
    float* pv = &zs[0][0];
    int*   pi = (int*)(&zs[0][0] + 256 * TM);
    const int tid = threadIdx.x;
    const int tok0 = blockIdx.x * TM;
    for (int e = tid; e < TM * F_IN; e += 256) xs[e] = x[(size_t)tok0 * F_IN + e];
    __syncthreads();
    {
        float acc0[TM], acc1[TM];
#pragma unroll
        for (int t = 0; t < TM; ++t) { acc0[t] = 0.f; acc1[t] = 0.f; }
        const float2 b2 = ((const float2*)benc)[tid];
#pragma unroll 4
        for (int f4 = 0; f4 < F_IN; f4 += 4) {
            float2 w0 = ((const float2*)(Wenc + (size_t)(f4 + 0) * D_DIM))[tid];
            float2 w1 = ((const float2*)(Wenc + (size_t)(f4 + 1) * D_DIM))[tid];
            float2 w2 = ((const float2*)(Wenc + (size_t)(f4 + 2) * D_DIM))[tid];
            float2 w3 = ((const float2*)(Wenc + (size_t)(f4 + 3) * D_DIM))[tid];
#pragma unroll
            for (int t = 0; t < TM; ++t) {
                float4 xv = *(const float4*)&xs[t * F_IN + f4];
                acc0[t] += xv.x * w0.x + xv.y * w1.x + xv.z * w2.x + xv.w * w3.x;
                acc1[t] += xv.x * w0.y + xv.y * w1.y + xv.z * w2.y + xv.w * w3.y;
            }
        }
#pragma unroll
        for (int t = 0; t < TM; ++t)
            *(float2*)&zs[t][2 * tid] = make_float2(acc0[t] + b2.x, acc1[t] + b2.y);
    }
    __syncthreads();
    float minv[TM]; int mini[TM];
#pragma unroll
    for (int t = 0; t < TM; ++t) { minv[t] = 3.4e38f; mini[t] = 0; }
    for (int iter = 0; iter < 2; ++iter) {
        float acc[4][TM];
#pragma unroll
        for (int j = 0; j < 4; ++j)
#pragma unroll
            for (int t = 0; t < TM; ++t) acc[j][t] = 0.f;
        const int cbase = iter * 1024 + tid;
        for (int d4 = 0; d4 < D_DIM; d4 += 4) {
            float cv[4][4];
#pragma unroll
            for (int dd = 0; dd < 4; ++dd) {
                const float* cp = centT + (size_t)(d4 + dd) * K_CENT + cbase;
                cv[dd][0] = cp[0]; cv[dd][1] = cp[256]; cv[dd][2] = cp[512]; cv[dd][3] = cp[768];
            }
#pragma unroll
            for (int t = 0; t < TM; ++t) {
                float4 zv = *(const float4*)&zs[t][d4];
#pragma unroll
                for (int j = 0; j < 4; ++j)
                    acc[j][t] += zv.x * cv[0][j] + zv.y * cv[1][j] + zv.z * cv[2][j] + zv.w * cv[3][j];
            }
        }
#pragma unroll
        for (int j = 0; j < 4; ++j) {
            int c = cbase + j * 256;
            float cn = cnorm[c];
#pragma unroll
            for (int t = 0; t < TM; ++t) {
                float dist = cn - 2.f * acc[j][t];
                if (dist < minv[t]) { minv[t] = dist; mini[t] = c; }
            }
        }
    }
    __syncthreads();
#pragma unroll
    for (int t = 0; t < TM; ++t) { pv[tid * TM + t] = minv[t]; pi[tid * TM + t] = mini[t]; }
    __syncthreads();
    {
        int t = tid & 15, g = tid >> 4;
        float bv = 3.4e38f; int bi = 0x7fffffff;
        for (int j = 0; j < 16; ++j) {
            int r2 = g + 16 * j;
            float vv = pv[r2 * TM + t]; int i2 = pi[r2 * TM + t];
            if (vv < bv || (vv == bv && i2 < bi)) { bv = vv; bi = i2; }
        }
        pv[g * TM + t] = bv; pi[g * TM + t] = bi;
    }
    __syncthreads();
    if (tid < TM) {
        int t = tid;
        float bv = 3.4e38f; int bi = 0x7fffffff;
        for (int g = 0; g < 16; ++g) {
            float vv = pv[g * TM + t]; int i2 = pi[g * TM + t];
            if (vv < bv || (vv == bv && i2 < bi)) { bv = vv; bi = i2; }
        }
        idxOut[tok0 + t] = bi;
    }
}

// ============================ launch ============================
extern "C" void kernel_launch(void* const* d_in, const int* in_sizes, int n_in,
                              void* d_out, int out_size, void* d_ws, size_t ws_size,
                              hipStream_t stream) {
    const float* x    = (const float*)d_in[0];
    const float* Wenc = (const float*)d_in[1];
    const float* benc = (const float*)d_in[2];
    const float* cent = (const float*)d_in[3];
    const float* Wdec = (const float*)d_in[4];
    const float* bdec = (const float*)d_in[5];
    float* out = (float*)d_out;

    const size_t L_B  = (size_t)N_TOK * 1024;            // 33554432 candidate lists
    const size_t ZF_B = (size_t)N_TOK * D_DIM * 4;       // 67108864 zf32
    const size_t XB_B = (size_t)N_TOK * KP * 2;          //  6291456 xbt
    const size_t CB_B = (size_t)K_CENT * D_DIM * 2;      //  2097152 cbt
    const size_t WB_B = (size_t)128 * D_DIM * 2;         //   131072 wbt
    const size_t GB_B = (size_t)K_CENT * KP * 2;         //   393216 Gbt
    const size_t N_B  = (size_t)K_CENT * 4;              //     8192 cnorm
    const size_t A_B  = (size_t)K_CENT * 4;              //     8192 cadj
    const size_t D_B  = (size_t)K_CENT * F_OUT * 4;      //   655360 dec
    const size_t NEED = L_B + ZF_B + XB_B + CB_B + WB_B + GB_B + N_B + A_B + D_B;

    if (ws_size >= NEED) {
        char* w = (char*)d_ws;
        char*           lists = w;                            w += L_B;
        float*          zf32  = (float*)w;                    w += ZF_B;
        unsigned short* xbt   = (unsigned short*)w;           w += XB_B;
        unsigned short* cbt   = (unsigned short*)w;           w += CB_B;
        unsigned short* wbt   = (unsigned short*)w;           w += WB_B;
        unsigned short* Gbt   = (unsigned short*)w;           w += GB_B;
        float*          cnorm = (float*)w;                    w += N_B;
        float*          cadj  = (float*)w;                    w += A_B;
        float*          dec   = (float*)w;

        k_prep_cbt<<<4096, 256, 0, stream>>>(cent, cbt);
        k_prep_wbt<<<16, 256, 0, stream>>>(Wenc, wbt);
        k_prep_xbt<<<768, 256, 0, stream>>>(x, xbt);
        k_gemm_g<<<16, 256, 0, stream>>>(wbt, cbt, Gbt);
        k_cadj<<<K_CENT / 4, 256, 0, stream>>>(cent, benc, cnorm, cadj);
        k_dec<<<K_CENT, 128, 0, stream>>>(cent, Wdec, bdec, dec);
        k_enc<<<N_TOK / TM, 256, 0, stream>>>(x, Wenc, benc, zf32);
        k_dist<<<4096, 256, 0, stream>>>(xbt, Gbt, cadj, lists);
        k_merge<<<2048, 256, 0, stream>>>(lists, cnorm, cent, zf32, dec, out);
    } else {
        float* centT = (float*)d_ws;
        float* cnorm = centT + (size_t)D_DIM * K_CENT;
        float* cadj  = cnorm + K_CENT;
        float* dec   = cadj + K_CENT;
        int*   idx   = (int*)(dec + (size_t)K_CENT * F_OUT);
        k_transpose<<<dim3(K_CENT / 64, D_DIM / 64), 256, 0, stream>>>(cent, centT);
        k_cadj<<<K_CENT / 4, 256, 0, stream>>>(cent, benc, cnorm, cadj);
        k_dec<<<K_CENT, 128, 0, stream>>>(cent, Wdec, bdec, dec);
        k_main<<<N_TOK / TM, 256, 0, stream>>>(x, Wenc, benc, centT, cnorm, idx);
        k_out<<<N_TOK * F_OUT / 2560, 256, 0, stream>>>(dec, idx, out);
    }
}

// Round 6
// 133.275 us; speedup vs baseline: 8.5255x; 1.3818x over previous
//
#include <hip/hip_runtime.h>
#include <hip/hip_bf16.h>

#define N_TOK  32768
#define F_IN   80
#define D_DIM  512
#define K_CENT 2048
#define F_OUT  80
#define TM     16
#define KP     96
#define MARGIN 1.0f
#define M2     0.5f      // margin in acc units (dist = -2*acc)
#define SLOTS  32
#define RSTRIDE 264      // 8B header {cnt,max} + 32 * 8B records

typedef __attribute__((ext_vector_type(8))) short    bf16x8;
typedef __attribute__((ext_vector_type(4))) float    fx4;

#define AS3 __attribute__((address_space(3)))
#define AS1 __attribute__((address_space(1)))

__device__ inline unsigned short f2bf(float f) {
    unsigned u = __float_as_uint(f);
    return (unsigned short)((u + 0x7FFFu + ((u >> 16) & 1u)) >> 16);
}
__device__ inline float bf2f(unsigned short h) {
    return __uint_as_float((unsigned)h << 16);
}

__device__ inline void gll16(const unsigned short* g, unsigned short* l) {
    __builtin_amdgcn_global_load_lds((const AS1 unsigned*)g, (AS3 unsigned*)l, 16, 0, 0);
}

// Fragment-linear tile: [128 rows][32 k] bf16 = 4096 elems, stripe s=row>>4,
// lane L = ((k>>3)<<4)+(row&15): elem at s*512 + L*8 + (k&7).
__device__ inline size_t frag_addr(int row, int k) {
    int stripe = row >> 4;
    int L = ((k >> 3) << 4) + (row & 15);
    return (size_t)stripe * 512 + L * 8 + (k & 7);
}

// ============================ prep kernels ============================
// cnorm + fold -0.5*cadj (hi/lo bf16 split) into Gbt rows k=80,81.
// MUST run after k_gemm_g (stream-ordered).
__global__ void k_cadj2(const float* __restrict__ cent, const float* __restrict__ benc,
                        float* __restrict__ cnorm, unsigned short* __restrict__ Gbt) {
    int wave = threadIdx.x >> 6, lane = threadIdx.x & 63;
    int k = blockIdx.x * 4 + wave;
    const float* row = cent + (size_t)k * D_DIM;
    float s = 0.f, t = 0.f;
#pragma unroll
    for (int j = 0; j < 8; ++j) {
        float c = row[lane + 64 * j];
        float b = benc[lane + 64 * j];
        s += c * c; t += b * c;
    }
#pragma unroll
    for (int off = 32; off; off >>= 1) { s += __shfl_down(s, off); t += __shfl_down(t, off); }
    if (lane == 0) {
        cnorm[k] = s;
        float v = -0.5f * (s - 2.0f * t);
        unsigned short h = f2bf(v);
        unsigned short l = f2bf(v - bf2f(h));
        int nt = k >> 7, cl = k & 127;
        size_t tb = (size_t)(nt * 3 + 2) * 4096;   // kt=2 holds k=64..95
        Gbt[tb + frag_addr(cl, 16)] = h;           // k=80
        Gbt[tb + frag_addr(cl, 17)] = l;           // k=81
    }
}

__global__ void k_cnorm(const float* __restrict__ cent, float* __restrict__ cnorm) {
    int wave = threadIdx.x >> 6, lane = threadIdx.x & 63;
    int k = blockIdx.x * 4 + wave;
    const float* row = cent + (size_t)k * D_DIM;
    float s = 0.f;
#pragma unroll
    for (int j = 0; j < 8; ++j) { float v = row[lane + 64 * j]; s += v * v; }
#pragma unroll
    for (int off = 32; off; off >>= 1) s += __shfl_down(s, off);
    if (lane == 0) cnorm[k] = s;
}

__global__ void k_dec(const float* __restrict__ cent, const float* __restrict__ Wdec,
                      const float* __restrict__ bdec, float* __restrict__ dec) {
    __shared__ float cs[D_DIM];
    int k = blockIdx.x;
    for (int d = threadIdx.x; d < D_DIM; d += blockDim.x) cs[d] = cent[(size_t)k * D_DIM + d];
    __syncthreads();
    int f = threadIdx.x;
    if (f < F_OUT) {
        float a0 = 0.f, a1 = 0.f, a2 = 0.f, a3 = 0.f;
#pragma unroll 4
        for (int d = 0; d < D_DIM; d += 4) {
            a0 += cs[d + 0] * Wdec[(d + 0) * F_OUT + f];
            a1 += cs[d + 1] * Wdec[(d + 1) * F_OUT + f];
            a2 += cs[d + 2] * Wdec[(d + 2) * F_OUT + f];
            a3 += cs[d + 3] * Wdec[(d + 3) * F_OUT + f];
        }
        dec[(size_t)k * F_OUT + f] = a0 + a1 + a2 + a3 + bdec[f];
    }
}

__global__ void k_prep_cbt(const float* __restrict__ cent, unsigned short* __restrict__ cbt) {
    int e = blockIdx.x * 256 + threadIdx.x;
    int n = e >> 9, k = e & 511;
    size_t tile = (size_t)((n >> 7) * 16 + (k >> 5));
    cbt[tile * 4096 + frag_addr(n & 127, k & 31)] = f2bf(cent[e]);
}

__global__ void k_prep_wbt(const float* __restrict__ Wenc, unsigned short* __restrict__ wbt) {
    int kt = blockIdx.x;
    int tid = threadIdx.x;
    int a0 = tid * 16;
    int s = a0 >> 9;
    int L0 = (tid * 2) & 63;
    int row0 = s * 16 + (L0 & 15);
    int kg = kt * 32 + (L0 >> 4) * 8;
    unsigned short u[16];
#pragma unroll
    for (int rr = 0; rr < 2; ++rr) {
        int row = row0 + rr;
        if (row < F_IN) {
            const float* src = Wenc + (size_t)row * D_DIM + kg;
            float4 v0 = *(const float4*)src;
            float4 v1 = *(const float4*)(src + 4);
            u[rr*8+0]=f2bf(v0.x); u[rr*8+1]=f2bf(v0.y); u[rr*8+2]=f2bf(v0.z); u[rr*8+3]=f2bf(v0.w);
            u[rr*8+4]=f2bf(v1.x); u[rr*8+5]=f2bf(v1.y); u[rr*8+6]=f2bf(v1.z); u[rr*8+7]=f2bf(v1.w);
        } else {
#pragma unroll
            for (int j = 0; j < 8; ++j) u[rr*8+j] = 0;
        }
    }
    unsigned short* dst = wbt + (size_t)kt * 4096 + a0;
#pragma unroll
    for (int j = 0; j < 16; ++j) dst[j] = u[j];
}

// x -> xbt bf16 tiled [256 mt][3 kt][4096]; k=80,81 <- 1.0 ; k 82..95 <- 0
__global__ void k_prep_xbt(const float* __restrict__ x, unsigned short* __restrict__ xbt) {
    int tile = blockIdx.x;   // 768
    int mt = tile / 3, kt = tile - mt * 3;
    int tid = threadIdx.x;
    int a0 = tid * 16;
    int s = a0 >> 9;
    int L0 = (tid * 2) & 63;
    int row0 = s * 16 + (L0 & 15);
    int kg = kt * 32 + (L0 >> 4) * 8;
    unsigned short u[16];
#pragma unroll
    for (int rr = 0; rr < 2; ++rr) {
        int row = row0 + rr;
        if (kg < F_IN) {
            const float* src = x + (size_t)(mt * 128 + row) * F_IN + kg;
            float4 v0 = *(const float4*)src;
            float4 v1 = *(const float4*)(src + 4);
            u[rr*8+0]=f2bf(v0.x); u[rr*8+1]=f2bf(v0.y); u[rr*8+2]=f2bf(v0.z); u[rr*8+3]=f2bf(v0.w);
            u[rr*8+4]=f2bf(v1.x); u[rr*8+5]=f2bf(v1.y); u[rr*8+6]=f2bf(v1.z); u[rr*8+7]=f2bf(v1.w);
        } else {
#pragma unroll
            for (int j = 0; j < 8; ++j) u[rr*8+j] = (kg + j <= 81) ? (unsigned short)0x3F80 : (unsigned short)0;
        }
    }
    unsigned short* dst = xbt + (size_t)tile * 4096 + a0;
#pragma unroll
    for (int j = 0; j < 16; ++j) dst[j] = u[j];
}

// G = Wenc @ cent^T (bf16 MFMA). Stores rows f<80 only; rows 80/81 by k_cadj2.
__global__ __launch_bounds__(256) void k_gemm_g(
    const unsigned short* __restrict__ wbt, const unsigned short* __restrict__ cbt,
    unsigned short* __restrict__ Gbt) {
    __shared__ unsigned short lds[2][2][4096];
    const int tid = threadIdx.x;
    const int nt = blockIdx.x;
    const int lane = tid & 63;
    const int wave = tid >> 6;
    const int wm = wave >> 1, wn = wave & 1;

    const unsigned short* Bbase = cbt + (size_t)nt * 16 * 4096;
    const int toff = tid * 8;
    const int woff = (tid & ~63) * 8;

    fx4 acc[4][4] = {};
    {
#pragma unroll
        for (int q = 0; q < 2; ++q) {
            gll16(wbt + q * 2048 + toff, &lds[0][0][0] + q * 2048 + woff);
            gll16(Bbase + q * 2048 + toff, &lds[0][1][0] + q * 2048 + woff);
        }
    }
    int cur = 0;
    for (int kk = 0; kk < 16; ++kk) {
        __syncthreads();
        if (kk + 1 < 16) {
#pragma unroll
            for (int q = 0; q < 2; ++q) {
                gll16(wbt + (kk + 1) * 4096 + q * 2048 + toff, &lds[cur ^ 1][0][0] + q * 2048 + woff);
                gll16(Bbase + (kk + 1) * 4096 + q * 2048 + toff, &lds[cur ^ 1][1][0] + q * 2048 + woff);
            }
        }
        const unsigned short* A = &lds[cur][0][0];
        const unsigned short* B = &lds[cur][1][0];
        bf16x8 a[4], b[4];
#pragma unroll
        for (int i = 0; i < 4; ++i) a[i] = *(const bf16x8*)&A[(wm * 4 + i) * 512 + lane * 8];
#pragma unroll
        for (int j = 0; j < 4; ++j) b[j] = *(const bf16x8*)&B[(wn * 4 + j) * 512 + lane * 8];
#pragma unroll
        for (int i = 0; i < 4; ++i)
#pragma unroll
            for (int j = 0; j < 4; ++j)
                acc[i][j] = __builtin_amdgcn_mfma_f32_16x16x32_bf16(a[i], b[j], acc[i][j], 0, 0, 0);
        cur ^= 1;
    }
    const int g = lane >> 4, cl = lane & 15;
#pragma unroll
    for (int j = 0; j < 4; ++j) {
        int colLoc = wn * 64 + j * 16 + cl;
#pragma unroll
        for (int i = 0; i < 4; ++i)
#pragma unroll
            for (int r = 0; r < 4; ++r) {
                int f = wm * 64 + i * 16 + g * 4 + r;
                if (f < F_IN)
                    Gbt[(size_t)(nt * 3 + (f >> 5)) * 4096 + frag_addr(colLoc, f & 31)]
                        = f2bf(acc[i][j][r]);
            }
    }
}

// ============================ distance + per-token argmax + candidates ============================
// 256 blocks (1/CU), 4 waves x 32 tokens, all 2048 centroids streamed.
// Swapped operands: mfma(cent_frag, tok_frag) -> token = lane&15 (in-wave rows).
// acc = x.G - 0.5*cadj  =>  dist = -2*acc  =>  argmin dist = argmax acc.
__global__ __launch_bounds__(256) void k_dist2(
    const unsigned short* __restrict__ xbt, const unsigned short* __restrict__ Gbt,
    char* __restrict__ lists) {
    __shared__ unsigned short Bs[2][3 * 4096];   // 48 KB dbuf (centroid tiles)
    __shared__ int cnt[128];
    __shared__ float mxs[128];

    const int tid = threadIdx.x;
    const int mt = blockIdx.x;
    const int lane = tid & 63;
    const int wm = tid >> 6;          // wave owns tokens wm*32 .. wm*32+31
    const int col = lane & 15;
    const int hi = lane >> 4;

    if (tid < 128) cnt[tid] = 0;

    // token frags (mfma B-operand), kept in registers for all 16 tiles
    bf16x8 bfr[2][3];
    const unsigned short* Ab = xbt + (size_t)mt * 3 * 4096;
#pragma unroll
    for (int i = 0; i < 2; ++i)
#pragma unroll
        for (int kt = 0; kt < 3; ++kt)
            bfr[i][kt] = *(const bf16x8*)&Ab[kt * 4096 + (wm * 2 + i) * 512 + lane * 8];

    const int toff = tid * 8;
    const int woff = (tid & ~63) * 8;
    // stage centroid tile 0
#pragma unroll
    for (int q = 0; q < 6; ++q) gll16(Gbt + q * 2048 + toff, &Bs[0][0] + q * 2048 + woff);

    float rmax[2] = { -3.4e38f, -3.4e38f };
    int cur = 0;
    for (int nt = 0; nt < 16; ++nt) {
        __syncthreads();   // staging of tile nt complete; prior reads of cur^1 done
        if (nt + 1 < 16) {
#pragma unroll
            for (int q = 0; q < 6; ++q)
                gll16(Gbt + (size_t)(nt + 1) * 12288 + q * 2048 + toff,
                      &Bs[cur ^ 1][0] + q * 2048 + woff);
        }
        const unsigned short* B = &Bs[cur][0];
        fx4 acc[2][8];
#pragma unroll
        for (int i = 0; i < 2; ++i)
#pragma unroll
            for (int j = 0; j < 8; ++j) acc[i][j] = (fx4){0.f, 0.f, 0.f, 0.f};
#pragma unroll
        for (int kt = 0; kt < 3; ++kt) {
            bf16x8 a[8];
#pragma unroll
            for (int j = 0; j < 8; ++j)
                a[j] = *(const bf16x8*)&B[kt * 4096 + j * 512 + lane * 8];
#pragma unroll
            for (int i = 0; i < 2; ++i)
#pragma unroll
                for (int j = 0; j < 8; ++j)
                    acc[i][j] = __builtin_amdgcn_mfma_f32_16x16x32_bf16(a[j], bfr[i][kt], acc[i][j], 0, 0, 0);
        }
        // running max (2 shfl per i) + candidate push
#pragma unroll
        for (int i = 0; i < 2; ++i) {
            float mj[8];
#pragma unroll
            for (int j = 0; j < 8; ++j)
                mj[j] = fmaxf(fmaxf(acc[i][j][0], acc[i][j][1]), fmaxf(acc[i][j][2], acc[i][j][3]));
            float m = fmaxf(fmaxf(fmaxf(mj[0], mj[1]), fmaxf(mj[2], mj[3])),
                            fmaxf(fmaxf(mj[4], mj[5]), fmaxf(mj[6], mj[7])));
            float rm = fmaxf(rmax[i], m);
            rm = fmaxf(rm, __shfl_xor(rm, 16));
            rm = fmaxf(rm, __shfl_xor(rm, 32));
            rmax[i] = rm;
            const float th = rm - M2;
            const int tk = wm * 32 + i * 16 + col;
#pragma unroll
            for (int j = 0; j < 8; ++j)
#pragma unroll
                for (int r = 0; r < 4; ++r) {
                    float v = acc[i][j][r];
                    if (v >= th) {
                        int slot = atomicAdd(&cnt[tk], 1);
                        if (slot < SLOTS) {
                            uint2 e;
                            e.x = __float_as_uint(v);
                            e.y = (unsigned)(nt * 128 + j * 16 + hi * 4 + r);
                            *(uint2*)(lists + (size_t)(mt * 128 + tk) * RSTRIDE + 8 + slot * 8) = e;
                        }
                    }
                }
        }
        cur ^= 1;
    }
    if (hi == 0) { mxs[wm * 32 + col] = rmax[0]; mxs[wm * 32 + 16 + col] = rmax[1]; }
    __syncthreads();
    if (tid < 128) {
        uint2 h;
        h.x = (unsigned)cnt[tid];
        h.y = __float_as_uint(mxs[tid]);
        *(uint2*)(lists + (size_t)(mt * 128 + tid) * RSTRIDE) = h;
    }
}

// ============================ merge + exact-refine + decode gather ============================
__global__ __launch_bounds__(256) void k_merge2(
    const char* __restrict__ lists, const float* __restrict__ cnorm,
    const float* __restrict__ cent, const float* __restrict__ x,
    const float* __restrict__ Wenc, const float* __restrict__ benc,
    const float* __restrict__ dec, float* __restrict__ out) {
    const int lane = threadIdx.x & 63;
    const int wid = blockIdx.x * 4 + (threadIdx.x >> 6);   // 8192 waves
    for (int it = 0; it < 4; ++it) {
        const int token = wid + it * 8192;
        const char* base = lists + (size_t)token * RSTRIDE;
        uint2 w = (lane < 33) ? *(const uint2*)(base + 8 * lane) : make_uint2(0u, 0u);
        int cntv = __shfl((int)w.x, 0);
        float maxv = __uint_as_float((unsigned)__shfl((int)w.y, 0));
        const float th = maxv - M2;
        int c32 = cntv < SLOTS ? cntv : SLOTS;
        bool cand = (lane >= 1) && (lane - 1 < c32) && (__uint_as_float(w.x) >= th);
        unsigned long long bal = __ballot(cand);
        int ns = __popcll(bal);
        int ans;
        if (cntv <= SLOTS && ns == 1) {
            int src = __ffsll(bal) - 1;
            ans = __shfl((int)w.y, src);
        } else {
            // recompute exact z (lane owns dims lane*8..lane*8+7)
            float z8[8];
#pragma unroll
            for (int j = 0; j < 8; ++j) z8[j] = benc[lane * 8 + j];
            const float* xr = x + (size_t)token * F_IN;
            const float* wp = Wenc + lane * 8;
            for (int f = 0; f < F_IN; ++f) {
                float xf = xr[f];
                fx4 w0 = *(const fx4*)(wp + (size_t)f * D_DIM);
                fx4 w1 = *(const fx4*)(wp + (size_t)f * D_DIM + 4);
                z8[0] += xf * w0.x; z8[1] += xf * w0.y; z8[2] += xf * w0.z; z8[3] += xf * w0.w;
                z8[4] += xf * w1.x; z8[5] += xf * w1.y; z8[6] += xf * w1.z; z8[7] += xf * w1.w;
            }
            float bd = 1e30f; int bn = 0x7FFFFFFF;
            if (cntv <= SLOTS) {
                unsigned long long m = bal;
                while (m) {
                    int src = __ffsll(m) - 1; m &= m - 1;
                    int ci = __shfl((int)w.y, src);
                    const float* cr = cent + (size_t)ci * D_DIM + lane * 8;
                    fx4 c0 = *(const fx4*)cr, c1 = *(const fx4*)(cr + 4);
                    float dp = z8[0] * c0.x + z8[1] * c0.y + z8[2] * c0.z + z8[3] * c0.w
                             + z8[4] * c1.x + z8[5] * c1.y + z8[6] * c1.z + z8[7] * c1.w;
#pragma unroll
                    for (int off = 1; off < 64; off <<= 1) dp += __shfl_xor(dp, off);
                    float de = cnorm[ci] - 2.0f * dp;
                    if (de < bd || (de == bd && ci < bn)) { bd = de; bn = ci; }
                }
            } else {
                // overflow (astronomically rare): exact full scan
                for (int ci = 0; ci < K_CENT; ++ci) {
                    const float* cr = cent + (size_t)ci * D_DIM + lane * 8;
                    fx4 c0 = *(const fx4*)cr, c1 = *(const fx4*)(cr + 4);
                    float dp = z8[0] * c0.x + z8[1] * c0.y + z8[2] * c0.z + z8[3] * c0.w
                             + z8[4] * c1.x + z8[5] * c1.y + z8[6] * c1.z + z8[7] * c1.w;
#pragma unroll
                    for (int off = 1; off < 64; off <<= 1) dp += __shfl_xor(dp, off);
                    float de = cnorm[ci] - 2.0f * dp;
                    if (de < bd || (de == bd && ci < bn)) { bd = de; bn = ci; }
                }
            }
            ans = bn;
        }
        const float* dr = dec + (size_t)ans * F_OUT;
        float* orow = out + (size_t)token * F_OUT;
        orow[lane] = dr[lane];
        if (lane < F_OUT - 64) orow[64 + lane] = dr[64 + lane];
    }
}

// ============================ fallback path (round-1, known-good) ============================
__global__ void k_transpose(const float* __restrict__ cent, float* __restrict__ centT) {
    __shared__ float tile[64][65];
    int kb = blockIdx.x * 64, db = blockIdx.y * 64;
    int lx = threadIdx.x & 63, ly = threadIdx.x >> 6;
#pragma unroll
    for (int i = 0; i < 16; ++i) {
        int row = ly + i * 4;
        tile[row][lx] = cent[(size_t)(kb + row) * D_DIM + db + lx];
    }
    __syncthreads();
#pragma unroll
    for (int i = 0; i < 16; ++i) {
        int row = ly + i * 4;
        centT[(size_t)(db + row) * K_CENT + kb + lx] = tile[lx][row];
    }
}

__global__ void k_out(const float* __restrict__ dec, const int* __restrict__ idx,
                      float* __restrict__ out) {
    int e0 = blockIdx.x * 2560;
#pragma unroll
    for (int r = 0; r < 10; ++r) {
        int e = e0 + threadIdx.x + r * 256;
        int n = e / F_OUT, f = e - n * F_OUT;
        out[e] = dec[(size_t)idx[n] * F_OUT + f];
    }
}

__global__ __launch_bounds__(256) void k_main(
    const float* __restrict__ x, const float* __restrict__ Wenc,
    const float* __restrict__ benc, const float* __restrict__ centT,
    const float* __restrict__ cnorm, int* __restrict__ idxOut) {
    __shared__ float xs[TM * F_IN];
    __shared__ float zs[TM][D_DIM];
    float* pv = &zs[0][0];
    int*   pi = (int*)(&zs[0][0] + 256 * TM);
    const int tid = threadIdx.x;
    const int tok0 = blockIdx.x * TM;
    for (int e = tid; e < TM * F_IN; e += 256) xs[e] = x[(size_t)tok0 * F_IN + e];
    __syncthreads();
    {
        float acc0[TM], acc1[TM];
#pragma unroll
        for (int t = 0; t < TM; ++t) { acc0[t] = 0.f; acc1[t] = 0.f; }
        const float2 b2 = ((const float2*)benc)[tid];
#pragma unroll 4
        for (int f4 = 0; f4 < F_IN; f4 += 4) {
            float2 w0 = ((const float2*)(Wenc + (size_t)(f4 + 0) * D_DIM))[tid];
            float2 w1 = ((const float2*)(Wenc + (size_t)(f4 + 1) * D_DIM))[tid];
            float2 w2 = ((const float2*)(Wenc + (size_t)(f4 + 2) * D_DIM))[tid];
            float2 w3 = ((const float2*)(Wenc + (size_t)(f4 + 3) * D_DIM))[tid];
#pragma unroll
            for (int t = 0; t < TM; ++t) {
                float4 xv = *(const float4*)&xs[t * F_IN + f4];
                acc0[t] += xv.x * w0.x + xv.y * w1.x + xv.z * w2.x + xv.w * w3.x;
                acc1[t] += xv.x * w0.y + xv.y * w1.y + xv.z * w2.y + xv.w * w3.y;
            }
        }
#pragma unroll
        for (int t = 0; t < TM; ++t)
            *(float2*)&zs[t][2 * tid] = make_float2(acc0[t] + b2.x, acc1[t] + b2.y);
    }
    __syncthreads();
    float minv[TM]; int mini[TM];
#pragma unroll
    for (int t = 0; t < TM; ++t) { minv[t] = 3.4e38f; mini[t] = 0; }
    for (int iter = 0; iter < 2; ++iter) {
        float acc[4][TM];
#pragma unroll
        for (int j = 0; j < 4; ++j)
#pragma unroll
            for (int t = 0; t < TM; ++t) acc[j][t] = 0.f;
        const int cbase = iter * 1024 + tid;
        for (int d4 = 0; d4 < D_DIM; d4 += 4) {
            float cv[4][4];
#pragma unroll
            for (int dd = 0; dd < 4; ++dd) {
                const float* cp = centT + (size_t)(d4 + dd) * K_CENT + cbase;
                cv[dd][0] = cp[0]; cv[dd][1] = cp[256]; cv[dd][2] = cp[512]; cv[dd][3] = cp[768];
            }
#pragma unroll
            for (int t = 0; t < TM; ++t) {
                float4 zv = *(const float4*)&zs[t][d4];
#pragma unroll
                for (int j = 0; j < 4; ++j)
                    acc[j][t] += zv.x * cv[0][j] + zv.y * cv[1][j] + zv.z * cv[2][j] + zv.w * cv[3][j];
            }
        }
#pragma unroll
        for (int j = 0; j < 4; ++j) {
            int c = cbase + j * 256;
            float cn = cnorm[c];
#pragma unroll
            for (int t = 0; t < TM; ++t) {
                float dist = cn - 2.f * acc[j][t];
                if (dist < minv[t]) { minv[t] = dist; mini[t] = c; }
            }
        }
    }
    __syncthreads();
#pragma unroll
    for (int t = 0; t < TM; ++t) { pv[tid * TM + t] = minv[t]; pi[tid * TM + t] = mini[t]; }
    __syncthreads();
    {
        int t = tid & 15, g = tid >> 4;
        float bv = 3.4e38f; int bi = 0x7fffffff;
        for (int j = 0; j < 16; ++j) {
            int r2 = g + 16 * j;
            float vv = pv[r2 * TM + t]; int i2 = pi[r2 * TM + t];
            if (vv < bv || (vv == bv && i2 < bi)) { bv = vv; bi = i2; }
        }
        pv[g * TM + t] = bv; pi[g * TM + t] = bi;
    }
    __syncthreads();
    if (tid < TM) {
        int t = tid;
        float bv = 3.4e38f; int bi = 0x7fffffff;
        for (int g = 0; g < 16; ++g) {
            float vv = pv[g * TM + t]; int i2 = pi[g * TM + t];
            if (vv < bv || (vv == bv && i2 < bi)) { bv = vv; bi = i2; }
        }
        idxOut[tok0 + t] = bi;
    }
}

// ============================ launch ============================
extern "C" void kernel_launch(void* const* d_in, const int* in_sizes, int n_in,
                              void* d_out, int out_size, void* d_ws, size_t ws_size,
                              hipStream_t stream) {
    const float* x    = (const float*)d_in[0];
    const float* Wenc = (const float*)d_in[1];
    const float* benc = (const float*)d_in[2];
    const float* cent = (const float*)d_in[3];
    const float* Wdec = (const float*)d_in[4];
    const float* bdec = (const float*)d_in[5];
    float* out = (float*)d_out;

    const size_t L_B  = (size_t)N_TOK * RSTRIDE;         //  8650752 candidate lists
    const size_t XB_B = (size_t)N_TOK * KP * 2;          //  6291456 xbt
    const size_t CB_B = (size_t)K_CENT * D_DIM * 2;      //  2097152 cbt
    const size_t WB_B = (size_t)128 * D_DIM * 2;         //   131072 wbt
    const size_t GB_B = (size_t)K_CENT * KP * 2;         //   393216 Gbt
    const size_t N_B  = (size_t)K_CENT * 4;              //     8192 cnorm
    const size_t D_B  = (size_t)K_CENT * F_OUT * 4;      //   655360 dec
    const size_t NEED = L_B + XB_B + CB_B + WB_B + GB_B + N_B + D_B;

    if (ws_size >= NEED) {
        char* w = (char*)d_ws;
        char*           lists = w;                            w += L_B;
        unsigned short* xbt   = (unsigned short*)w;           w += XB_B;
        unsigned short* cbt   = (unsigned short*)w;           w += CB_B;
        unsigned short* wbt   = (unsigned short*)w;           w += WB_B;
        unsigned short* Gbt   = (unsigned short*)w;           w += GB_B;
        float*          cnorm = (float*)w;                    w += N_B;
        float*          dec   = (float*)w;

        k_prep_cbt<<<4096, 256, 0, stream>>>(cent, cbt);
        k_prep_wbt<<<16, 256, 0, stream>>>(Wenc, wbt);
        k_prep_xbt<<<768, 256, 0, stream>>>(x, xbt);
        k_gemm_g<<<16, 256, 0, stream>>>(wbt, cbt, Gbt);
        k_cadj2<<<K_CENT / 4, 256, 0, stream>>>(cent, benc, cnorm, Gbt);   // after gemm_g
        k_dec<<<K_CENT, 128, 0, stream>>>(cent, Wdec, bdec, dec);
        k_dist2<<<256, 256, 0, stream>>>(xbt, Gbt, lists);
        k_merge2<<<2048, 256, 0, stream>>>(lists, cnorm, cent, x, Wenc, benc, dec, out);
    } else {
        float* centT = (float*)d_ws;
        float* cnorm = centT + (size_t)D_DIM * K_CENT;
        float* dec   = cnorm + K_CENT;
        int*   idx   = (int*)(dec + (size_t)K_CENT * F_OUT);
        k_transpose<<<dim3(K_CENT / 64, D_DIM / 64), 256, 0, stream>>>(cent, centT);
        k_cnorm<<<K_CENT / 4, 256, 0, stream>>>(cent, cnorm);
        k_dec<<<K_CENT, 128, 0, stream>>>(cent, Wdec, bdec, dec);
        k_main<<<N_TOK / TM, 256, 0, stream>>>(x, Wenc, benc, centT, cnorm, idx);
        k_out<<<N_TOK * F_OUT / 2560, 256, 0, stream>>>(dec, idx, out);
    }
}

// Round 7
// 121.548 us; speedup vs baseline: 9.3481x; 1.0965x over previous
//
#include <hip/hip_runtime.h>
#include <hip/hip_bf16.h>

#define N_TOK  32768
#define F_IN   80
#define D_DIM  512
#define K_CENT 2048
#define F_OUT  80
#define TM     16
#define KP     96
#define M2     0.5f      // margin in acc units (dist = -2*acc)
#define SLOTS  32
#define RSTRIDE 264      // 8B header {cnt,max} + 32 * 8B records

typedef __attribute__((ext_vector_type(8)))  short bf16x8;
typedef __attribute__((ext_vector_type(4)))  float fx4;
typedef __attribute__((ext_vector_type(16))) float fx16;

#define AS3 __attribute__((address_space(3)))
#define AS1 __attribute__((address_space(1)))

__device__ inline unsigned short f2bf(float f) {
    unsigned u = __float_as_uint(f);
    return (unsigned short)((u + 0x7FFFu + ((u >> 16) & 1u)) >> 16);
}
__device__ inline float bf2f(unsigned short h) {
    return __uint_as_float((unsigned)h << 16);
}

__device__ inline void gll16(const unsigned short* g, unsigned short* l) {
    __builtin_amdgcn_global_load_lds((const AS1 unsigned*)g, (AS3 unsigned*)l, 16, 0, 0);
}

__device__ inline unsigned fkey(float f) {
    unsigned b = __float_as_uint(f);
    return b ^ ((b >> 31) ? 0xFFFFFFFFu : 0x80000000u);
}
__device__ inline float keyf(unsigned k) {
    unsigned b = k ^ ((k & 0x80000000u) ? 0x80000000u : 0xFFFFFFFFu);
    return __uint_as_float(b);
}

// 16x16x32 fragment-linear tile [128 rows][32 k] (gemm_g operands)
__device__ inline size_t frag_addr(int row, int k) {
    int stripe = row >> 4;
    int L = ((k >> 3) << 4) + (row & 15);
    return (size_t)stripe * 512 + L * 8 + (k & 7);
}

// 32x32x16 fragment-linear tile [128 rows][32 k] (dist2 operands):
// subtile = (row>>5)*2 + ((k>>4)&1); lane L = (row&31) + 32*((k>>3)&1)
__device__ inline size_t frag32_addr(int row, int k) {
    int sub = (row >> 5) * 2 + ((k >> 4) & 1);
    int L = (row & 31) + ((k >> 3) & 1) * 32;
    return (size_t)sub * 512 + L * 8 + (k & 7);
}

// ============================ fused prep: cbt + wbt + xbt ============================
__global__ void k_prep_all(const float* __restrict__ x, const float* __restrict__ Wenc,
                           const float* __restrict__ cent,
                           unsigned short* __restrict__ cbt, unsigned short* __restrict__ wbt,
                           unsigned short* __restrict__ xbt) {
    const int bid = blockIdx.x, tid = threadIdx.x;
    if (bid < 4096) {
        // cbt (old frag layout, gemm_g B-operand)
        int e = bid * 256 + tid;
        int n = e >> 9, k = e & 511;
        size_t tile = (size_t)((n >> 7) * 16 + (k >> 5));
        cbt[tile * 4096 + frag_addr(n & 127, k & 31)] = f2bf(cent[e]);
    } else if (bid < 4112) {
        // wbt (old frag layout, gemm_g A-operand), rows >= 80 zero
        int kt = bid - 4096;
        int a0 = tid * 16;
        int s = a0 >> 9;
        int L0 = (tid * 2) & 63;
        int row0 = s * 16 + (L0 & 15);
        int kg = kt * 32 + (L0 >> 4) * 8;
        unsigned short u[16];
#pragma unroll
        for (int rr = 0; rr < 2; ++rr) {
            int row = row0 + rr;
            if (row < F_IN) {
                const float* src = Wenc + (size_t)row * D_DIM + kg;
                float4 v0 = *(const float4*)src;
                float4 v1 = *(const float4*)(src + 4);
                u[rr*8+0]=f2bf(v0.x); u[rr*8+1]=f2bf(v0.y); u[rr*8+2]=f2bf(v0.z); u[rr*8+3]=f2bf(v0.w);
                u[rr*8+4]=f2bf(v1.x); u[rr*8+5]=f2bf(v1.y); u[rr*8+6]=f2bf(v1.z); u[rr*8+7]=f2bf(v1.w);
            } else {
#pragma unroll
                for (int j = 0; j < 8; ++j) u[rr*8+j] = 0;
            }
        }
        unsigned short* dst = wbt + (size_t)kt * 4096 + a0;
#pragma unroll
        for (int j = 0; j < 16; ++j) dst[j] = u[j];
    } else {
        // xbt (NEW frag32 layout, dist2 B-operand): dims 80,81 = 1.0 (cadj fold), 82..95 = 0
        int o = (bid - 4112) * 256 + tid;    // 393216 octets
        int m = o / 12;
        int ko = (o - m * 12) * 8;
        unsigned short u[8];
        if (ko < F_IN) {
            const float* src = x + (size_t)m * F_IN + ko;
            float4 v0 = *(const float4*)src;
            float4 v1 = *(const float4*)(src + 4);
            u[0]=f2bf(v0.x); u[1]=f2bf(v0.y); u[2]=f2bf(v0.z); u[3]=f2bf(v0.w);
            u[4]=f2bf(v1.x); u[5]=f2bf(v1.y); u[6]=f2bf(v1.z); u[7]=f2bf(v1.w);
        } else if (ko == 80) {
            u[0] = 0x3F80; u[1] = 0x3F80;
#pragma unroll
            for (int j = 2; j < 8; ++j) u[j] = 0;
        } else {
#pragma unroll
            for (int j = 0; j < 8; ++j) u[j] = 0;
        }
        int mt = m >> 7, kt = ko >> 5, row = m & 127, kl = ko & 31;
        size_t addr = (size_t)(mt * 3 + kt) * 4096 + frag32_addr(row, kl);
        uint4 p;
        p.x = (unsigned)u[0] | ((unsigned)u[1] << 16);
        p.y = (unsigned)u[2] | ((unsigned)u[3] << 16);
        p.z = (unsigned)u[4] | ((unsigned)u[5] << 16);
        p.w = (unsigned)u[6] | ((unsigned)u[7] << 16);
        *(uint4*)&xbt[addr] = p;
    }
}

// ============================ G = Wenc @ cent^T (bf16 MFMA, 8 waves) ============================
__global__ __launch_bounds__(512) void k_gemm_g(
    const unsigned short* __restrict__ wbt, const unsigned short* __restrict__ cbt,
    unsigned short* __restrict__ Gbt) {
    __shared__ unsigned short lds[2][2][4096];
    const int tid = threadIdx.x;
    const int nt = blockIdx.x;
    const int lane = tid & 63;
    const int wave = tid >> 6;
    const int wm = wave >> 2, wn = wave & 3;   // 2 M-groups x 4 N-groups

    const unsigned short* Bbase = cbt + (size_t)nt * 16 * 4096;
    const int woff = (tid & ~63) * 8;

    fx4 acc[4][2] = {};
    gll16(wbt + tid * 8, &lds[0][0][0] + woff);
    gll16(Bbase + tid * 8, &lds[0][1][0] + woff);

    int cur = 0;
    for (int kk = 0; kk < 16; ++kk) {
        __syncthreads();
        if (kk + 1 < 16) {
            gll16(wbt + (kk + 1) * 4096 + tid * 8, &lds[cur ^ 1][0][0] + woff);
            gll16(Bbase + (kk + 1) * 4096 + tid * 8, &lds[cur ^ 1][1][0] + woff);
        }
        const unsigned short* A = &lds[cur][0][0];
        const unsigned short* B = &lds[cur][1][0];
        bf16x8 a[4], b[2];
#pragma unroll
        for (int i = 0; i < 4; ++i) a[i] = *(const bf16x8*)&A[(wm * 4 + i) * 512 + lane * 8];
#pragma unroll
        for (int j = 0; j < 2; ++j) b[j] = *(const bf16x8*)&B[(wn * 2 + j) * 512 + lane * 8];
#pragma unroll
        for (int i = 0; i < 4; ++i)
#pragma unroll
            for (int j = 0; j < 2; ++j)
                acc[i][j] = __builtin_amdgcn_mfma_f32_16x16x32_bf16(a[i], b[j], acc[i][j], 0, 0, 0);
        cur ^= 1;
    }
    const int g = lane >> 4, cl = lane & 15;
#pragma unroll
    for (int j = 0; j < 2; ++j) {
        int colLoc = wn * 32 + j * 16 + cl;   // centroid within 128
#pragma unroll
        for (int i = 0; i < 4; ++i)
#pragma unroll
            for (int r = 0; r < 4; ++r) {
                int f = wm * 64 + i * 16 + g * 4 + r;
                if (f < F_IN)
                    Gbt[(size_t)(nt * 3 + (f >> 5)) * 4096 + frag32_addr(colLoc, f & 31)]
                        = f2bf(acc[i][j][r]);
            }
    }
}

// ============================ fused dec table + cnorm + cadj fold ============================
// 256 blocks x 8 centroids. Also writes Gbt rows k=80,81 (disjoint from gemm_g's f<80).
__global__ __launch_bounds__(256) void k_dec2(
    const float* __restrict__ cent, const float* __restrict__ benc,
    const float* __restrict__ Wdec, const float* __restrict__ bdec,
    float* __restrict__ cnorm, unsigned short* __restrict__ Gbt,
    float* __restrict__ dec) {
    __shared__ float cs[8][512];   // 16 KB
    const int tid = threadIdx.x;
    const int k0 = blockIdx.x * 8;
#pragma unroll
    for (int q = 0; q < 4; ++q) {
        int idx = q * 256 + tid;
        ((float4*)cs)[idx] = ((const float4*)(cent + (size_t)k0 * D_DIM))[idx];
    }
    __syncthreads();
    const int wave = tid >> 6, lane = tid & 63;
    // norms: wave w handles centroids w*2, w*2+1
    float bv[8];
#pragma unroll
    for (int j = 0; j < 8; ++j) bv[j] = benc[lane + 64 * j];
#pragma unroll
    for (int cc = 0; cc < 2; ++cc) {
        int c = wave * 2 + cc;
        float s = 0.f, t = 0.f;
#pragma unroll
        for (int j = 0; j < 8; ++j) {
            float cv = cs[c][lane + 64 * j];
            s += cv * cv; t += bv[j] * cv;
        }
#pragma unroll
        for (int off = 32; off; off >>= 1) { s += __shfl_down(s, off); t += __shfl_down(t, off); }
        if (lane == 0) {
            int k = k0 + c;
            cnorm[k] = s;
            float v = -0.5f * (s - 2.0f * t);
            unsigned short h = f2bf(v);
            unsigned short l = f2bf(v - bf2f(h));
            int nt = k >> 7, cl = k & 127;
            size_t tb = (size_t)(nt * 3 + 2) * 4096;
            Gbt[tb + frag32_addr(cl, 16)] = h;   // k=80
            Gbt[tb + frag32_addr(cl, 17)] = l;   // k=81
        }
    }
    // dec: thread (f = tid&127, cg = tid>>7) covers 4 centroids
    const int f = tid & 127, cg = tid >> 7;
    if (f < F_OUT) {
        float bd = bdec[f];
        float acc[4] = { bd, bd, bd, bd };
        for (int d = 0; d < D_DIM; d += 4) {
            float w0 = Wdec[(size_t)(d + 0) * F_OUT + f];
            float w1 = Wdec[(size_t)(d + 1) * F_OUT + f];
            float w2 = Wdec[(size_t)(d + 2) * F_OUT + f];
            float w3 = Wdec[(size_t)(d + 3) * F_OUT + f];
#pragma unroll
            for (int i = 0; i < 4; ++i) {
                fx4 c4 = *(const fx4*)&cs[cg * 4 + i][d];
                acc[i] += c4.x * w0 + c4.y * w1 + c4.z * w2 + c4.w * w3;
            }
        }
#pragma unroll
        for (int i = 0; i < 4; ++i)
            dec[(size_t)(k0 + cg * 4 + i) * F_OUT + f] = acc[i];
    }
}

// ============================ distance + per-token argmax + candidates ============================
// 256 blocks x 512 thr (8 waves = 4 token-groups x 2 centroid-halves), 32x32x16 MFMA.
// acc = x.G - 0.5*cadj  =>  argmin dist = argmax acc.
__global__ __launch_bounds__(512) void k_dist2(
    const unsigned short* __restrict__ xbt, const unsigned short* __restrict__ Gbt,
    char* __restrict__ lists) {
    __shared__ unsigned short Bs[2][12288];   // 48 KB dbuf (3 kt-tiles)
    __shared__ int cnt[128];
    __shared__ unsigned mxk[128];

    const int tid = threadIdx.x;
    const int mt = blockIdx.x;
    const int lane = tid & 63;
    const int wave = tid >> 6;
    const int tg = wave >> 1;       // token group: tokens tg*32..+31
    const int ch = wave & 1;        // centroid half: rows ch*64..+63 of tile
    const int col = lane & 31;
    const int hi = lane >> 5;

    if (tid < 128) { cnt[tid] = 0; mxk[tid] = 0u; }

    // token fragments (B operand), in registers for all 16 tiles
    bf16x8 bfr[6];
    const unsigned short* Ab = xbt + (size_t)mt * 3 * 4096;
#pragma unroll
    for (int kc = 0; kc < 6; ++kc)
        bfr[kc] = *(const bf16x8*)&Ab[(kc >> 1) * 4096 + (tg * 2 + (kc & 1)) * 512 + lane * 8];

    // stage centroid tile 0
#pragma unroll
    for (int q = 0; q < 3; ++q)
        gll16(Gbt + q * 4096 + tid * 8, &Bs[0][0] + q * 4096 + (tid & ~63) * 8);

    float rmax = -3.4e38f;
    int cur = 0;
    for (int nt = 0; nt < 16; ++nt) {
        __syncthreads();
        if (nt + 1 < 16) {
#pragma unroll
            for (int q = 0; q < 3; ++q)
                gll16(Gbt + (size_t)(nt + 1) * 12288 + q * 4096 + tid * 8,
                      &Bs[cur ^ 1][0] + q * 4096 + (tid & ~63) * 8);
        }
        const unsigned short* B = &Bs[cur][0];
        fx16 acc[2];
#pragma unroll
        for (int u = 0; u < 2; ++u)
#pragma unroll
            for (int r = 0; r < 16; ++r) acc[u][r] = 0.f;
#pragma unroll
        for (int kc = 0; kc < 6; ++kc) {
#pragma unroll
            for (int u = 0; u < 2; ++u) {
                bf16x8 a = *(const bf16x8*)&B[(kc >> 1) * 4096
                             + ((ch * 2 + u) * 2 + (kc & 1)) * 512 + lane * 8];
                acc[u] = __builtin_amdgcn_mfma_f32_32x32x16_bf16(a, bfr[kc], acc[u], 0, 0, 0);
            }
        }
        // epilogue: token-max (1 shfl) + margin push
        float m = acc[0][0];
#pragma unroll
        for (int r = 1; r < 16; ++r) m = fmaxf(m, acc[0][r]);
#pragma unroll
        for (int r = 0; r < 16; ++r) m = fmaxf(m, acc[1][r]);
        m = fmaxf(m, __shfl_xor(m, 32));
        rmax = fmaxf(rmax, m);
        const float th = rmax - M2;
        const int tk = tg * 32 + col;
#pragma unroll
        for (int u = 0; u < 2; ++u)
#pragma unroll
            for (int r = 0; r < 16; ++r) {
                float v = acc[u][r];
                if (v >= th) {
                    int slot = atomicAdd(&cnt[tk], 1);
                    if (slot < SLOTS) {
                        uint2 e;
                        e.x = __float_as_uint(v);
                        e.y = (unsigned)(nt * 128 + (ch * 2 + u) * 32
                                         + (r & 3) + 8 * (r >> 2) + 4 * hi);
                        *(uint2*)(lists + (size_t)(mt * 128 + tk) * RSTRIDE + 8 + slot * 8) = e;
                    }
                }
            }
        cur ^= 1;
    }
    if (lane < 32) atomicMax(&mxk[tg * 32 + lane], fkey(rmax));
    __syncthreads();
    if (tid < 128) {
        uint2 h;
        h.x = (unsigned)cnt[tid];
        h.y = __float_as_uint(keyf(mxk[tid]));
        *(uint2*)(lists + (size_t)(mt * 128 + tid) * RSTRIDE) = h;
    }
}

// ============================ merge + exact-refine + decode gather ============================
__global__ __launch_bounds__(256) void k_merge2(
    const char* __restrict__ lists, const float* __restrict__ cnorm,
    const float* __restrict__ cent, const float* __restrict__ x,
    const float* __restrict__ Wenc, const float* __restrict__ benc,
    const float* __restrict__ dec, float* __restrict__ out) {
    const int lane = threadIdx.x & 63;
    const int wid = blockIdx.x * 4 + (threadIdx.x >> 6);   // 8192 waves
    for (int it = 0; it < 4; ++it) {
        const int token = wid + it * 8192;
        const char* base = lists + (size_t)token * RSTRIDE;
        uint2 w = (lane < 33) ? *(const uint2*)(base + 8 * lane) : make_uint2(0u, 0u);
        int cntv = __shfl((int)w.x, 0);
        float maxv = __uint_as_float((unsigned)__shfl((int)w.y, 0));
        const float th = maxv - M2;
        int c32 = cntv < SLOTS ? cntv : SLOTS;
        bool cand = (lane >= 1) && (lane - 1 < c32) && (__uint_as_float(w.x) >= th);
        unsigned long long bal = __ballot(cand);
        int ns = __popcll(bal);
        int ans;
        if (cntv <= SLOTS && ns == 1) {
            int src = __ffsll(bal) - 1;
            ans = __shfl((int)w.y, src);
        } else {
            float z8[8];
#pragma unroll
            for (int j = 0; j < 8; ++j) z8[j] = benc[lane * 8 + j];
            const float* xr = x + (size_t)token * F_IN;
            const float* wp = Wenc + lane * 8;
            for (int f = 0; f < F_IN; ++f) {
                float xf = xr[f];
                fx4 w0 = *(const fx4*)(wp + (size_t)f * D_DIM);
                fx4 w1 = *(const fx4*)(wp + (size_t)f * D_DIM + 4);
                z8[0] += xf * w0.x; z8[1] += xf * w0.y; z8[2] += xf * w0.z; z8[3] += xf * w0.w;
                z8[4] += xf * w1.x; z8[5] += xf * w1.y; z8[6] += xf * w1.z; z8[7] += xf * w1.w;
            }
            float bd = 1e30f; int bn = 0x7FFFFFFF;
            if (cntv <= SLOTS) {
                unsigned long long m = bal;
                while (m) {
                    int src = __ffsll(m) - 1; m &= m - 1;
                    int ci = __shfl((int)w.y, src);
                    const float* cr = cent + (size_t)ci * D_DIM + lane * 8;
                    fx4 c0 = *(const fx4*)cr, c1 = *(const fx4*)(cr + 4);
                    float dp = z8[0] * c0.x + z8[1] * c0.y + z8[2] * c0.z + z8[3] * c0.w
                             + z8[4] * c1.x + z8[5] * c1.y + z8[6] * c1.z + z8[7] * c1.w;
#pragma unroll
                    for (int off = 1; off < 64; off <<= 1) dp += __shfl_xor(dp, off);
                    float de = cnorm[ci] - 2.0f * dp;
                    if (de < bd || (de == bd && ci < bn)) { bd = de; bn = ci; }
                }
            } else {
                for (int ci = 0; ci < K_CENT; ++ci) {
                    const float* cr = cent + (size_t)ci * D_DIM + lane * 8;
                    fx4 c0 = *(const fx4*)cr, c1 = *(const fx4*)(cr + 4);
                    float dp = z8[0] * c0.x + z8[1] * c0.y + z8[2] * c0.z + z8[3] * c0.w
                             + z8[4] * c1.x + z8[5] * c1.y + z8[6] * c1.z + z8[7] * c1.w;
#pragma unroll
                    for (int off = 1; off < 64; off <<= 1) dp += __shfl_xor(dp, off);
                    float de = cnorm[ci] - 2.0f * dp;
                    if (de < bd || (de == bd && ci < bn)) { bd = de; bn = ci; }
                }
            }
            ans = bn;
        }
        const float* dr = dec + (size_t)ans * F_OUT;
        float* orow = out + (size_t)token * F_OUT;
        orow[lane] = dr[lane];
        if (lane < F_OUT - 64) orow[64 + lane] = dr[64 + lane];
    }
}

// ============================ fallback path (round-1, known-good) ============================
__global__ void k_transpose(const float* __restrict__ cent, float* __restrict__ centT) {
    __shared__ float tile[64][65];
    int kb = blockIdx.x * 64, db = blockIdx.y * 64;
    int lx = threadIdx.x & 63, ly = threadIdx.x >> 6;
#pragma unroll
    for (int i = 0; i < 16; ++i) {
        int row = ly + i * 4;
        tile[row][lx] = cent[(size_t)(kb + row) * D_DIM + db + lx];
    }
    __syncthreads();
#pragma unroll
    for (int i = 0; i < 16; ++i) {
        int row = ly + i * 4;
        centT[(size_t)(db + row) * K_CENT + kb + lx] = tile[lx][row];
    }
}

__global__ void k_cnorm(const float* __restrict__ cent, float* __restrict__ cnorm) {
    int wave = threadIdx.x >> 6, lane = threadIdx.x & 63;
    int k = blockIdx.x * 4 + wave;
    const float* row = cent + (size_t)k * D_DIM;
    float s = 0.f;
#pragma unroll
    for (int j = 0; j < 8; ++j) { float v = row[lane + 64 * j]; s += v * v; }
#pragma unroll
    for (int off = 32; off; off >>= 1) s += __shfl_down(s, off);
    if (lane == 0) cnorm[k] = s;
}

__global__ void k_dec(const float* __restrict__ cent, const float* __restrict__ Wdec,
                      const float* __restrict__ bdec, float* __restrict__ dec) {
    __shared__ float cs[D_DIM];
    int k = blockIdx.x;
    for (int d = threadIdx.x; d < D_DIM; d += blockDim.x) cs[d] = cent[(size_t)k * D_DIM + d];
    __syncthreads();
    int f = threadIdx.x;
    if (f < F_OUT) {
        float a0 = 0.f, a1 = 0.f, a2 = 0.f, a3 = 0.f;
#pragma unroll 4
        for (int d = 0; d < D_DIM; d += 4) {
            a0 += cs[d + 0] * Wdec[(d + 0) * F_OUT + f];
            a1 += cs[d + 1] * Wdec[(d + 1) * F_OUT + f];
            a2 += cs[d + 2] * Wdec[(d + 2) * F_OUT + f];
            a3 += cs[d + 3] * Wdec[(d + 3) * F_OUT + f];
        }
        dec[(size_t)k * F_OUT + f] = a0 + a1 + a2 + a3 + bdec[f];
    }
}

__global__ void k_out(const float* __restrict__ dec, const int* __restrict__ idx,
                      float* __restrict__ out) {
    int e0 = blockIdx.x * 2560;
#pragma unroll
    for (int r = 0; r < 10; ++r) {
        int e = e0 + threadIdx.x + r * 256;
        int n = e / F_OUT, f = e - n * F_OUT;
        out[e] = dec[(size_t)idx[n] * F_OUT + f];
    }
}

__global__ __launch_bounds__(256) void k_main(
    const float* __restrict__ x, const float* __restrict__ Wenc,
    const float* __restrict__ benc, const float* __restrict__ centT,
    const float* __restrict__ cnorm, int* __restrict__ idxOut) {
    __shared__ float xs[TM * F_IN];
    __shared__ float zs[TM][D_DIM];
    float* pv = &zs[0][0];
    int*   pi = (int*)(&zs[0][0] + 256 * TM);
    const int tid = threadIdx.x;
    const int tok0 = blockIdx.x * TM;
    for (int e = tid; e < TM * F_IN; e += 256) xs[e] = x[(size_t)tok0 * F_IN + e];
    __syncthreads();
    {
        float acc0[TM], acc1[TM];
#pragma unroll
        for (int t = 0; t < TM; ++t) { acc0[t] = 0.f; acc1[t] = 0.f; }
        const float2 b2 = ((const float2*)benc)[tid];
#pragma unroll 4
        for (int f4 = 0; f4 < F_IN; f4 += 4) {
            float2 w0 = ((const float2*)(Wenc + (size_t)(f4 + 0) * D_DIM))[tid];
            float2 w1 = ((const float2*)(Wenc + (size_t)(f4 + 1) * D_DIM))[tid];
            float2 w2 = ((const float2*)(Wenc + (size_t)(f4 + 2) * D_DIM))[tid];
            float2 w3 = ((const float2*)(Wenc + (size_t)(f4 + 3) * D_DIM))[tid];
#pragma unroll
            for (int t = 0; t < TM; ++t) {
                float4 xv = *(const float4*)&xs[t * F_IN + f4];
                acc0[t] += xv.x * w0.x + xv.y * w1.x + xv.z * w2.x + xv.w * w3.x;
                acc1[t] += xv.x * w0.y + xv.y * w1.y + xv.z * w2.y + xv.w * w3.y;
            }
        }
#pragma unroll
        for (int t = 0; t < TM; ++t)
            *(float2*)&zs[t][2 * tid] = make_float2(acc0[t] + b2.x, acc1[t] + b2.y);
    }
    __syncthreads();
    float minv[TM]; int mini[TM];
#pragma unroll
    for (int t = 0; t < TM; ++t) { minv[t] = 3.4e38f; mini[t] = 0; }
    for (int iter = 0; iter < 2; ++iter) {
        float acc[4][TM];
#pragma unroll
        for (int j = 0; j < 4; ++j)
#pragma unroll
            for (int t = 0; t < TM; ++t) acc[j][t] = 0.f;
        const int cbase = iter * 1024 + tid;
        for (int d4 = 0; d4 < D_DIM; d4 += 4) {
            float cv[4][4];
#pragma unroll
            for (int dd = 0; dd < 4; ++dd) {
                const float* cp = centT + (size_t)(d4 + dd) * K_CENT + cbase;
                cv[dd][0] = cp[0]; cv[dd][1] = cp[256]; cv[dd][2] = cp[512]; cv[dd][3] = cp[768];
            }
#pragma unroll
            for (int t = 0; t < TM; ++t) {
                float4 zv = *(const float4*)&zs[t][d4];
#pragma unroll
                for (int j = 0; j < 4; ++j)
                    acc[j][t] += zv.x * cv[0][j] + zv.y * cv[1][j] + zv.z * cv[2][j] + zv.w * cv[3][j];
            }
        }
#pragma unroll
        for (int j = 0; j < 4; ++j) {
            int c = cbase + j * 256;
            float cn = cnorm[c];
#pragma unroll
            for (int t = 0; t < TM; ++t) {
                float dist = cn - 2.f * acc[j][t];
                if (dist < minv[t]) { minv[t] = dist; mini[t] = c; }
            }
        }
    }
    __syncthreads();
#pragma unroll
    for (int t = 0; t < TM; ++t) { pv[tid * TM + t] = minv[t]; pi[tid * TM + t] = mini[t]; }
    __syncthreads();
    {
        int t = tid & 15, g = tid >> 4;
        float bv = 3.4e38f; int bi = 0x7fffffff;
        for (int j = 0; j < 16; ++j) {
            int r2 = g + 16 * j;
            float vv = pv[r2 * TM + t]; int i2 = pi[r2 * TM + t];
            if (vv < bv || (vv == bv && i2 < bi)) { bv = vv; bi = i2; }
        }
        pv[g * TM + t] = bv; pi[g * TM + t] = bi;
    }
    __syncthreads();
    if (tid < TM) {
        int t = tid;
        float bv = 3.4e38f; int bi = 0x7fffffff;
        for (int g = 0; g < 16; ++g) {
            float vv = pv[g * TM + t]; int i2 = pi[g * TM + t];
            if (vv < bv || (vv == bv && i2 < bi)) { bv = vv; bi = i2; }
        }
        idxOut[tok0 + t] = bi;
    }
}

// ============================ launch ============================
extern "C" void kernel_launch(void* const* d_in, const int* in_sizes, int n_in,
                              void* d_out, int out_size, void* d_ws, size_t ws_size,
                              hipStream_t stream) {
    const float* x    = (const float*)d_in[0];
    const float* Wenc = (const float*)d_in[1];
    const float* benc = (const float*)d_in[2];
    const float* cent = (const float*)d_in[3];
    const float* Wdec = (const float*)d_in[4];
    const float* bdec = (const float*)d_in[5];
    float* out = (float*)d_out;

    const size_t L_B  = (size_t)N_TOK * RSTRIDE;         //  8650752 candidate lists
    const size_t XB_B = (size_t)N_TOK * KP * 2;          //  6291456 xbt
    const size_t CB_B = (size_t)K_CENT * D_DIM * 2;      //  2097152 cbt
    const size_t WB_B = (size_t)128 * D_DIM * 2;         //   131072 wbt
    const size_t GB_B = (size_t)K_CENT * KP * 2;         //   393216 Gbt
    const size_t N_B  = (size_t)K_CENT * 4;              //     8192 cnorm
    const size_t D_B  = (size_t)K_CENT * F_OUT * 4;      //   655360 dec
    const size_t NEED = L_B + XB_B + CB_B + WB_B + GB_B + N_B + D_B;

    if (ws_size >= NEED) {
        char* w = (char*)d_ws;
        char*           lists = w;                            w += L_B;
        unsigned short* xbt   = (unsigned short*)w;           w += XB_B;
        unsigned short* cbt   = (unsigned short*)w;           w += CB_B;
        unsigned short* wbt   = (unsigned short*)w;           w += WB_B;
        unsigned short* Gbt   = (unsigned short*)w;           w += GB_B;
        float*          cnorm = (float*)w;                    w += N_B;
        float*          dec   = (float*)w;

        k_prep_all<<<5648, 256, 0, stream>>>(x, Wenc, cent, cbt, wbt, xbt);
        k_gemm_g<<<16, 512, 0, stream>>>(wbt, cbt, Gbt);
        k_dec2<<<256, 256, 0, stream>>>(cent, benc, Wdec, bdec, cnorm, Gbt, dec);
        k_dist2<<<256, 512, 0, stream>>>(xbt, Gbt, lists);
        k_merge2<<<2048, 256, 0, stream>>>(lists, cnorm, cent, x, Wenc, benc, dec, out);
    } else {
        float* centT = (float*)d_ws;
        float* cnorm = centT + (size_t)D_DIM * K_CENT;
        float* dec   = cnorm + K_CENT;
        int*   idx   = (int*)(dec + (size_t)K_CENT * F_OUT);
        k_transpose<<<dim3(K_CENT / 64, D_DIM / 64), 256, 0, stream>>>(cent, centT);
        k_cnorm<<<K_CENT / 4, 256, 0, stream>>>(cent, cnorm);
        k_dec<<<K_CENT, 128, 0, stream>>>(cent, Wdec, bdec, dec);
        k_main<<<N_TOK / TM, 256, 0, stream>>>(x, Wenc, benc, centT, cnorm, idx);
        k_out<<<N_TOK * F_OUT / 2560, 256, 0, stream>>>(dec, idx, out);
    }
}

// Round 8
// 105.645 us; speedup vs baseline: 10.7552x; 1.1505x over previous
//
#include <hip/hip_runtime.h>
#include <hip/hip_bf16.h>

#define N_TOK  32768
#define F_IN   80
#define D_DIM  512
#define K_CENT 2048
#define F_OUT  80
#define TM     16
#define KP     96
#define M2     0.5f      // margin in acc units (dist = -2*acc)
#define QSLOTS 12
#define QREC   104       // 8B header {cnt,max} + 12 * 8B records
#define TREC   416       // 4 quarters per token

typedef __attribute__((ext_vector_type(8)))  short bf16x8;
typedef __attribute__((ext_vector_type(4)))  float fx4;
typedef __attribute__((ext_vector_type(16))) float fx16;

#define AS3 __attribute__((address_space(3)))
#define AS1 __attribute__((address_space(1)))

__device__ inline unsigned short f2bf(float f) {
    unsigned u = __float_as_uint(f);
    return (unsigned short)((u + 0x7FFFu + ((u >> 16) & 1u)) >> 16);
}
__device__ inline float bf2f(unsigned short h) {
    return __uint_as_float((unsigned)h << 16);
}

__device__ inline void gll16(const unsigned short* g, unsigned short* l) {
    __builtin_amdgcn_global_load_lds((const AS1 unsigned*)g, (AS3 unsigned*)l, 16, 0, 0);
}

__device__ inline unsigned fkey(float f) {
    unsigned b = __float_as_uint(f);
    return b ^ ((b >> 31) ? 0xFFFFFFFFu : 0x80000000u);
}
__device__ inline float keyf(unsigned k) {
    unsigned b = k ^ ((k & 0x80000000u) ? 0x80000000u : 0xFFFFFFFFu);
    return __uint_as_float(b);
}

// 16x16x32 fragment-linear tile [128 rows][32 k] (gemm_g operands)
__device__ inline size_t frag_addr(int row, int k) {
    int stripe = row >> 4;
    int L = ((k >> 3) << 4) + (row & 15);
    return (size_t)stripe * 512 + L * 8 + (k & 7);
}

// 32x32x16 fragment-linear tile [128 rows][32 k] (dist operands)
__device__ inline size_t frag32_addr(int row, int k) {
    int sub = (row >> 5) * 2 + ((k >> 4) & 1);
    int L = (row & 31) + ((k >> 3) & 1) * 32;
    return (size_t)sub * 512 + L * 8 + (k & 7);
}

// ============================ fused prep: cbt + wbt + xbt ============================
__global__ void k_prep_all(const float* __restrict__ x, const float* __restrict__ Wenc,
                           const float* __restrict__ cent,
                           unsigned short* __restrict__ cbt, unsigned short* __restrict__ wbt,
                           unsigned short* __restrict__ xbt) {
    const int bid = blockIdx.x, tid = threadIdx.x;
    if (bid < 512) {
        // cbt (16x16 frag layout): thread handles 8 consecutive k of one centroid
        int o = bid * 256 + tid;          // 131072 octets
        int n = o >> 6, ko = (o & 63) * 8;
        const float* src = cent + (size_t)n * D_DIM + ko;
        float4 v0 = *(const float4*)src;
        float4 v1 = *(const float4*)(src + 4);
        size_t tile = (size_t)((n >> 7) * 16 + (ko >> 5));
        uint4 p;
        p.x = (unsigned)f2bf(v0.x) | ((unsigned)f2bf(v0.y) << 16);
        p.y = (unsigned)f2bf(v0.z) | ((unsigned)f2bf(v0.w) << 16);
        p.z = (unsigned)f2bf(v1.x) | ((unsigned)f2bf(v1.y) << 16);
        p.w = (unsigned)f2bf(v1.z) | ((unsigned)f2bf(v1.w) << 16);
        *(uint4*)&cbt[tile * 4096 + frag_addr(n & 127, ko & 31)] = p;
    } else if (bid < 528) {
        // wbt (16x16 frag layout), rows >= 80 zero
        int kt = bid - 512;
        int a0 = tid * 16;
        int s = a0 >> 9;
        int L0 = (tid * 2) & 63;
        int row0 = s * 16 + (L0 & 15);
        int kg = kt * 32 + (L0 >> 4) * 8;
        unsigned short u[16];
#pragma unroll
        for (int rr = 0; rr < 2; ++rr) {
            int row = row0 + rr;
            if (row < F_IN) {
                const float* src = Wenc + (size_t)row * D_DIM + kg;
                float4 v0 = *(const float4*)src;
                float4 v1 = *(const float4*)(src + 4);
                u[rr*8+0]=f2bf(v0.x); u[rr*8+1]=f2bf(v0.y); u[rr*8+2]=f2bf(v0.z); u[rr*8+3]=f2bf(v0.w);
                u[rr*8+4]=f2bf(v1.x); u[rr*8+5]=f2bf(v1.y); u[rr*8+6]=f2bf(v1.z); u[rr*8+7]=f2bf(v1.w);
            } else {
#pragma unroll
                for (int j = 0; j < 8; ++j) u[rr*8+j] = 0;
            }
        }
        unsigned short* dst = wbt + (size_t)kt * 4096 + a0;
#pragma unroll
        for (int j = 0; j < 16; ++j) dst[j] = u[j];
    } else {
        // xbt (frag32 layout): dims 80,81 = 1.0 (cadj fold), 82..95 = 0
        int o = (bid - 528) * 256 + tid;    // 393216 octets
        int m = o / 12;
        int ko = (o - m * 12) * 8;
        unsigned short u[8];
        if (ko < F_IN) {
            const float* src = x + (size_t)m * F_IN + ko;
            float4 v0 = *(const float4*)src;
            float4 v1 = *(const float4*)(src + 4);
            u[0]=f2bf(v0.x); u[1]=f2bf(v0.y); u[2]=f2bf(v0.z); u[3]=f2bf(v0.w);
            u[4]=f2bf(v1.x); u[5]=f2bf(v1.y); u[6]=f2bf(v1.z); u[7]=f2bf(v1.w);
        } else if (ko == 80) {
            u[0] = 0x3F80; u[1] = 0x3F80;
#pragma unroll
            for (int j = 2; j < 8; ++j) u[j] = 0;
        } else {
#pragma unroll
            for (int j = 0; j < 8; ++j) u[j] = 0;
        }
        int mt = m >> 7, kt = ko >> 5, row = m & 127, kl = ko & 31;
        uint4 p;
        p.x = (unsigned)u[0] | ((unsigned)u[1] << 16);
        p.y = (unsigned)u[2] | ((unsigned)u[3] << 16);
        p.z = (unsigned)u[4] | ((unsigned)u[5] << 16);
        p.w = (unsigned)u[6] | ((unsigned)u[7] << 16);
        *(uint4*)&xbt[(size_t)(mt * 3 + kt) * 4096 + frag32_addr(row, kl)] = p;
    }
}

// ============================ G = Wenc @ cent^T (bf16 MFMA, 8 waves) ============================
// Writes f<96 (zero for f in [80,96)); k_cadjf later overwrites f=80,81.
__global__ __launch_bounds__(512) void k_gemm_g(
    const unsigned short* __restrict__ wbt, const unsigned short* __restrict__ cbt,
    unsigned short* __restrict__ Gbt) {
    __shared__ unsigned short lds[2][2][4096];
    const int tid = threadIdx.x;
    const int nt = blockIdx.x;
    const int lane = tid & 63;
    const int wave = tid >> 6;
    const int wm = wave >> 2, wn = wave & 3;   // 2 M-groups x 4 N-groups

    const unsigned short* Bbase = cbt + (size_t)nt * 16 * 4096;
    const int woff = (tid & ~63) * 8;

    fx4 acc[4][2] = {};
    gll16(wbt + tid * 8, &lds[0][0][0] + woff);
    gll16(Bbase + tid * 8, &lds[0][1][0] + woff);

    int cur = 0;
    for (int kk = 0; kk < 16; ++kk) {
        __syncthreads();
        if (kk + 1 < 16) {
            gll16(wbt + (kk + 1) * 4096 + tid * 8, &lds[cur ^ 1][0][0] + woff);
            gll16(Bbase + (kk + 1) * 4096 + tid * 8, &lds[cur ^ 1][1][0] + woff);
        }
        const unsigned short* A = &lds[cur][0][0];
        const unsigned short* B = &lds[cur][1][0];
        bf16x8 a[4], b[2];
#pragma unroll
        for (int i = 0; i < 4; ++i) a[i] = *(const bf16x8*)&A[(wm * 4 + i) * 512 + lane * 8];
#pragma unroll
        for (int j = 0; j < 2; ++j) b[j] = *(const bf16x8*)&B[(wn * 2 + j) * 512 + lane * 8];
#pragma unroll
        for (int i = 0; i < 4; ++i)
#pragma unroll
            for (int j = 0; j < 2; ++j)
                acc[i][j] = __builtin_amdgcn_mfma_f32_16x16x32_bf16(a[i], b[j], acc[i][j], 0, 0, 0);
        cur ^= 1;
    }
    const int g = lane >> 4, cl = lane & 15;
#pragma unroll
    for (int j = 0; j < 2; ++j) {
        int colLoc = wn * 32 + j * 16 + cl;   // centroid within 128
#pragma unroll
        for (int i = 0; i < 4; ++i)
#pragma unroll
            for (int r = 0; r < 4; ++r) {
                int f = wm * 64 + i * 16 + g * 4 + r;
                if (f < KP) {
                    unsigned short v = (f < F_IN) ? f2bf(acc[i][j][r]) : (unsigned short)0;
                    Gbt[(size_t)(nt * 3 + (f >> 5)) * 4096 + frag32_addr(colLoc, f & 31)] = v;
                }
            }
    }
}

// ============================ cnorm + cadj fold into Gbt k=80,81 (after gemm_g) ============================
__global__ void k_cadjf(const float* __restrict__ cent, const float* __restrict__ benc,
                        float* __restrict__ cnorm, unsigned short* __restrict__ Gbt) {
    int wave = threadIdx.x >> 6, lane = threadIdx.x & 63;
    int k = blockIdx.x * 4 + wave;
    const float* row = cent + (size_t)k * D_DIM;
    float s = 0.f, t = 0.f;
#pragma unroll
    for (int j = 0; j < 8; ++j) {
        float c = row[lane + 64 * j];
        float b = benc[lane + 64 * j];
        s += c * c; t += b * c;
    }
#pragma unroll
    for (int off = 32; off; off >>= 1) { s += __shfl_down(s, off); t += __shfl_down(t, off); }
    if (lane == 0) {
        cnorm[k] = s;
        float v = -0.5f * (s - 2.0f * t);
        unsigned short h = f2bf(v);
        unsigned short l = f2bf(v - bf2f(h));
        int nt = k >> 7, cl = k & 127;
        size_t tb = (size_t)(nt * 3 + 2) * 4096;   // kt=2 holds k=64..95
        Gbt[tb + frag32_addr(cl, 16)] = h;         // k=80
        Gbt[tb + frag32_addr(cl, 17)] = l;         // k=81
    }
}

// ============================ dec table (wide VALU, 512 blocks) ============================
__global__ __launch_bounds__(256) void k_dec3(
    const float* __restrict__ cent, const float* __restrict__ Wdec,
    const float* __restrict__ bdec, float* __restrict__ dec) {
    __shared__ float cs[4][D_DIM];   // 8 KB
    const int tid = threadIdx.x;
    const int k0 = blockIdx.x * 4;
#pragma unroll
    for (int q = 0; q < 2; ++q)
        ((float4*)cs)[q * 256 + tid] = ((const float4*)(cent + (size_t)k0 * D_DIM))[q * 256 + tid];
    __syncthreads();
    const int f = tid & 127, cg = tid >> 7;
    if (f < F_OUT) {
        const int c0 = cg * 2, c1 = cg * 2 + 1;
        float a0 = 0.f, b0 = 0.f, a1 = 0.f, b1 = 0.f;
        const float* wp = Wdec + f;
#pragma unroll 4
        for (int d = 0; d < D_DIM; d += 2) {
            float w0 = wp[(size_t)d * F_OUT];
            float w1 = wp[(size_t)(d + 1) * F_OUT];
            a0 += cs[c0][d] * w0;  b0 += cs[c0][d + 1] * w1;
            a1 += cs[c1][d] * w0;  b1 += cs[c1][d + 1] * w1;
        }
        float bd = bdec[f];
        dec[(size_t)(k0 + c0) * F_OUT + f] = a0 + b0 + bd;
        dec[(size_t)(k0 + c1) * F_OUT + f] = a1 + b1 + bd;
    }
}

// ============================ distance + per-token argmax + candidates ============================
// 1024 blocks = (256 mt) x (4 nt-quarters); 512 thr = 4 token-groups x 2 centroid-halves.
// 32x32x16 MFMA, swapped operands (token = lane&31). 4 tiles per block -> 3 blocks/CU overlap.
__global__ __launch_bounds__(512) void k_dist3(
    const unsigned short* __restrict__ xbt, const unsigned short* __restrict__ Gbt,
    char* __restrict__ lists) {
    __shared__ unsigned short Bs[2][12288];   // 48 KB dbuf
    __shared__ int cnt[128];
    __shared__ unsigned mxk[128];

    const int tid = threadIdx.x;
    const int bid = blockIdx.x;
    const int mt = bid >> 2, nq = bid & 3;
    const int lane = tid & 63;
    const int wave = tid >> 6;
    const int tg = wave >> 1;       // token group: tokens tg*32..+31
    const int ch = wave & 1;        // centroid half: rows ch*64..+63 of tile
    const int col = lane & 31;
    const int hi = lane >> 5;

    if (tid < 128) { cnt[tid] = 0; mxk[tid] = 0u; }

    // token fragments (B operand), registers for all 4 tiles
    bf16x8 bfr[6];
    const unsigned short* Ab = xbt + (size_t)mt * 12288;
#pragma unroll
    for (int kc = 0; kc < 6; ++kc)
        bfr[kc] = *(const bf16x8*)&Ab[(kc >> 1) * 4096 + (tg * 2 + (kc & 1)) * 512 + lane * 8];

    const int woff = (tid & ~63) * 8;
    const unsigned short* Gq = Gbt + (size_t)nq * 4 * 12288;
    // stage centroid tile 0
#pragma unroll
    for (int q = 0; q < 3; ++q)
        gll16(Gq + q * 4096 + tid * 8, &Bs[0][0] + q * 4096 + woff);

    float rmax = -3.4e38f;
    int cur = 0;
    for (int t4 = 0; t4 < 4; ++t4) {
        __syncthreads();   // drains staging of buf[cur]; prior reads of buf[cur^1] done
        if (t4 + 1 < 4) {
#pragma unroll
            for (int q = 0; q < 3; ++q)
                gll16(Gq + (size_t)(t4 + 1) * 12288 + q * 4096 + tid * 8,
                      &Bs[cur ^ 1][0] + q * 4096 + woff);
        }
        const unsigned short* B = &Bs[cur][0];
        fx16 acc[2];
#pragma unroll
        for (int u = 0; u < 2; ++u)
#pragma unroll
            for (int r = 0; r < 16; ++r) acc[u][r] = 0.f;
#pragma unroll
        for (int kc = 0; kc < 6; ++kc) {
#pragma unroll
            for (int u = 0; u < 2; ++u) {
                bf16x8 a = *(const bf16x8*)&B[(kc >> 1) * 4096
                             + ((ch * 2 + u) * 2 + (kc & 1)) * 512 + lane * 8];
                acc[u] = __builtin_amdgcn_mfma_f32_32x32x16_bf16(a, bfr[kc], acc[u], 0, 0, 0);
            }
        }
        // epilogue: per-token running max (1 shfl) + margin pushes
        float m = acc[0][0];
#pragma unroll
        for (int r = 1; r < 16; ++r) m = fmaxf(m, acc[0][r]);
#pragma unroll
        for (int r = 0; r < 16; ++r) m = fmaxf(m, acc[1][r]);
        m = fmaxf(m, __shfl_xor(m, 32));
        rmax = fmaxf(rmax, m);
        const float th = rmax - M2;
        const int tk = tg * 32 + col;
        char* qrec = lists + (size_t)(mt * 128 + tk) * TREC + nq * QREC;
#pragma unroll
        for (int u = 0; u < 2; ++u)
#pragma unroll
            for (int r = 0; r < 16; ++r) {
                float v = acc[u][r];
                if (v >= th) {
                    int slot = atomicAdd(&cnt[tk], 1);
                    if (slot < QSLOTS) {
                        uint2 e;
                        e.x = __float_as_uint(v);
                        e.y = (unsigned)((nq * 4 + t4) * 128 + (ch * 2 + u) * 32
                                         + (r & 3) + 8 * (r >> 2) + 4 * hi);
                        *(uint2*)(qrec + 8 + slot * 8) = e;
                    }
                }
            }
        cur ^= 1;
    }
    if (lane < 32) atomicMax(&mxk[tg * 32 + lane], fkey(rmax));
    __syncthreads();
    if (tid < 128) {
        uint2 h;
        h.x = (unsigned)cnt[tid];
        h.y = __float_as_uint(keyf(mxk[tid]));
        *(uint2*)(lists + (size_t)(mt * 128 + tid) * TREC + nq * QREC) = h;
    }
}

// ============================ merge 4 quarters + exact-refine + decode gather ============================
__global__ __launch_bounds__(256) void k_merge3(
    const char* __restrict__ lists, const float* __restrict__ cnorm,
    const float* __restrict__ cent, const float* __restrict__ x,
    const float* __restrict__ Wenc, const float* __restrict__ benc,
    const float* __restrict__ dec, float* __restrict__ out) {
    const int lane = threadIdx.x & 63;
    const int wid = blockIdx.x * 4 + (threadIdx.x >> 6);   // 8192 waves
    const int q = lane / 13, s = lane - q * 13;            // 4 quarters x 13 (hdr + 12 slots)
    for (int it = 0; it < 4; ++it) {
        const int token = wid + it * 8192;
        const char* base = lists + (size_t)token * TREC;
        uint2 w = make_uint2(0u, 0u);
        if (lane < 52) w = *(const uint2*)(base + q * QREC + s * 8);
        const bool ishdr = (lane < 52) && (s == 0);
        float gm = ishdr ? __uint_as_float(w.y) : -3.4e38f;
#pragma unroll
        for (int off = 1; off < 64; off <<= 1) gm = fmaxf(gm, __shfl_xor(gm, off));
        const float th = gm - M2;
        unsigned long long anyovf = __ballot(ishdr && ((int)w.x > QSLOTS));
        int qcnt = __shfl((int)w.x, q * 13);
        int c12 = qcnt < QSLOTS ? qcnt : QSLOTS;
        bool cand = (lane < 52) && (s >= 1) && (s - 1 < c12) && (__uint_as_float(w.x) >= th);
        unsigned long long bal = __ballot(cand);
        int ns = __popcll(bal);
        int ans;
        if (!anyovf && ns == 1) {
            ans = __shfl((int)w.y, __ffsll(bal) - 1);
        } else {
            // recompute exact z (lane owns dims lane*8..lane*8+7)
            float z8[8];
#pragma unroll
            for (int j = 0; j < 8; ++j) z8[j] = benc[lane * 8 + j];
            const float* xr = x + (size_t)token * F_IN;
            const float* wp = Wenc + lane * 8;
            for (int f = 0; f < F_IN; ++f) {
                float xf = xr[f];
                fx4 w0 = *(const fx4*)(wp + (size_t)f * D_DIM);
                fx4 w1 = *(const fx4*)(wp + (size_t)f * D_DIM + 4);
                z8[0] += xf * w0.x; z8[1] += xf * w0.y; z8[2] += xf * w0.z; z8[3] += xf * w0.w;
                z8[4] += xf * w1.x; z8[5] += xf * w1.y; z8[6] += xf * w1.z; z8[7] += xf * w1.w;
            }
            float bd = 1e30f; int bn = 0x7FFFFFFF;
            if (!anyovf) {
                unsigned long long m = bal;
                while (m) {
                    int src = __ffsll(m) - 1; m &= m - 1;
                    int ci = __shfl((int)w.y, src);
                    const float* cr = cent + (size_t)ci * D_DIM + lane * 8;
                    fx4 c0 = *(const fx4*)cr, c1 = *(const fx4*)(cr + 4);
                    float dp = z8[0] * c0.x + z8[1] * c0.y + z8[2] * c0.z + z8[3] * c0.w
                             + z8[4] * c1.x + z8[5] * c1.y + z8[6] * c1.z + z8[7] * c1.w;
#pragma unroll
                    for (int off = 1; off < 64; off <<= 1) dp += __shfl_xor(dp, off);
                    float de = cnorm[ci] - 2.0f * dp;
                    if (de < bd || (de == bd && ci < bn)) { bd = de; bn = ci; }
                }
            } else {
                // quarter overflowed (rare): exact full scan
                for (int ci = 0; ci < K_CENT; ++ci) {
                    const float* cr = cent + (size_t)ci * D_DIM + lane * 8;
                    fx4 c0 = *(const fx4*)cr, c1 = *(const fx4*)(cr + 4);
                    float dp = z8[0] * c0.x + z8[1] * c0.y + z8[2] * c0.z + z8[3] * c0.w
                             + z8[4] * c1.x + z8[5] * c1.y + z8[6] * c1.z + z8[7] * c1.w;
#pragma unroll
                    for (int off = 1; off < 64; off <<= 1) dp += __shfl_xor(dp, off);
                    float de = cnorm[ci] - 2.0f * dp;
                    if (de < bd || (de == bd && ci < bn)) { bd = de; bn = ci; }
                }
            }
            ans = bn;
        }
        const float* dr = dec + (size_t)ans * F_OUT;
        float* orow = out + (size_t)token * F_OUT;
        orow[lane] = dr[lane];
        if (lane < F_OUT - 64) orow[64 + lane] = dr[64 + lane];
    }
}

// ============================ fallback path (round-1, known-good) ============================
__global__ void k_transpose(const float* __restrict__ cent, float* __restrict__ centT) {
    __shared__ float tile[64][65];
    int kb = blockIdx.x * 64, db = blockIdx.y * 64;
    int lx = threadIdx.x & 63, ly = threadIdx.x >> 6;
#pragma unroll
    for (int i = 0; i < 16; ++i) {
        int row = ly + i * 4;
        tile[row][lx] = cent[(size_t)(kb + row) * D_DIM + db + lx];
    }
    __syncthreads();
#pragma unroll
    for (int i = 0; i < 16; ++i) {
        int row = ly + i * 4;
        centT[(size_t)(db + row) * K_CENT + kb + lx] = tile[lx][row];
    }
}

__global__ void k_cnorm(const float* __restrict__ cent, float* __restrict__ cnorm) {
    int wave = threadIdx.x >> 6, lane = threadIdx.x & 63;
    int k = blockIdx.x * 4 + wave;
    const float* row = cent + (size_t)k * D_DIM;
    float s = 0.f;
#pragma unroll
    for (int j = 0; j < 8; ++j) { float v = row[lane + 64 * j]; s += v * v; }
#pragma unroll
    for (int off = 32; off; off >>= 1) s += __shfl_down(s, off);
    if (lane == 0) cnorm[k] = s;
}

__global__ void k_dec(const float* __restrict__ cent, const float* __restrict__ Wdec,
                      const float* __restrict__ bdec, float* __restrict__ dec) {
    __shared__ float cs[D_DIM];
    int k = blockIdx.x;
    for (int d = threadIdx.x; d < D_DIM; d += blockDim.x) cs[d] = cent[(size_t)k * D_DIM + d];
    __syncthreads();
    int f = threadIdx.x;
    if (f < F_OUT) {
        float a0 = 0.f, a1 = 0.f, a2 = 0.f, a3 = 0.f;
#pragma unroll 4
        for (int d = 0; d < D_DIM; d += 4) {
            a0 += cs[d + 0] * Wdec[(d + 0) * F_OUT + f];
            a1 += cs[d + 1] * Wdec[(d + 1) * F_OUT + f];
            a2 += cs[d + 2] * Wdec[(d + 2) * F_OUT + f];
            a3 += cs[d + 3] * Wdec[(d + 3) * F_OUT + f];
        }
        dec[(size_t)k * F_OUT + f] = a0 + a1 + a2 + a3 + bdec[f];
    }
}

__global__ void k_out(const float* __restrict__ dec, const int* __restrict__ idx,
                      float* __restrict__ out) {
    int e0 = blockIdx.x * 2560;
#pragma unroll
    for (int r = 0; r < 10; ++r) {
        int e = e0 + threadIdx.x + r * 256;
        int n = e / F_OUT, f = e - n * F_OUT;
        out[e] = dec[(size_t)idx[n] * F_OUT + f];
    }
}

__global__ __launch_bounds__(256) void k_main(
    const float* __restrict__ x, const float* __restrict__ Wenc,
    const float* __restrict__ benc, const float* __restrict__ centT,
    const float* __restrict__ cnorm, int* __restrict__ idxOut) {
    __shared__ float xs[TM * F_IN];
    __shared__ float zs[TM][D_DIM];
    float* pv = &zs[0][0];
    int*   pi = (int*)(&zs[0][0] + 256 * TM);
    const int tid = threadIdx.x;
    const int tok0 = blockIdx.x * TM;
    for (int e = tid; e < TM * F_IN; e += 256) xs[e] = x[(size_t)tok0 * F_IN + e];
    __syncthreads();
    {
        float acc0[TM], acc1[TM];
#pragma unroll
        for (int t = 0; t < TM; ++t) { acc0[t] = 0.f; acc1[t] = 0.f; }
        const float2 b2 = ((const float2*)benc)[tid];
#pragma unroll 4
        for (int f4 = 0; f4 < F_IN; f4 += 4) {
            float2 w0 = ((const float2*)(Wenc + (size_t)(f4 + 0) * D_DIM))[tid];
            float2 w1 = ((const float2*)(Wenc + (size_t)(f4 + 1) * D_DIM))[tid];
            float2 w2 = ((const float2*)(Wenc + (size_t)(f4 + 2) * D_DIM))[tid];
            float2 w3 = ((const float2*)(Wenc + (size_t)(f4 + 3) * D_DIM))[tid];
#pragma unroll
            for (int t = 0; t < TM; ++t) {
                float4 xv = *(const float4*)&xs[t * F_IN + f4];
                acc0[t] += xv.x * w0.x + xv.y * w1.x + xv.z * w2.x + xv.w * w3.x;
                acc1[t] += xv.x * w0.y + xv.y * w1.y + xv.z * w2.y + xv.w * w3.y;
            }
        }
#pragma unroll
        for (int t = 0; t < TM; ++t)
            *(float2*)&zs[t][2 * tid] = make_float2(acc0[t] + b2.x, acc1[t] + b2.y);
    }
    __syncthreads();
    float minv[TM]; int mini[TM];
#pragma unroll
    for (int t = 0; t < TM; ++t) { minv[t] = 3.4e38f; mini[t] = 0; }
    for (int iter = 0; iter < 2; ++iter) {
        float acc[4][TM];
#pragma unroll
        for (int j = 0; j < 4; ++j)
#pragma unroll
            for (int t = 0; t < TM; ++t) acc[j][t] = 0.f;
        const int cbase = iter * 1024 + tid;
        for (int d4 = 0; d4 < D_DIM; d4 += 4) {
            float cv[4][4];
#pragma unroll
            for (int dd = 0; dd < 4; ++dd) {
                const float* cp = centT + (size_t)(d4 + dd) * K_CENT + cbase;
                cv[dd][0] = cp[0]; cv[dd][1] = cp[256]; cv[dd][2] = cp[512]; cv[dd][3] = cp[768];
            }
#pragma unroll
            for (int t = 0; t < TM; ++t) {
                float4 zv = *(const float4*)&zs[t][d4];
#pragma unroll
                for (int j = 0; j < 4; ++j)
                    acc[j][t] += zv.x * cv[0][j] + zv.y * cv[1][j] + zv.z * cv[2][j] + zv.w * cv[3][j];
            }
        }
#pragma unroll
        for (int j = 0; j < 4; ++j) {
            int c = cbase + j * 256;
            float cn = cnorm[c];
#pragma unroll
            for (int t = 0; t < TM; ++t) {
                float dist = cn - 2.f * acc[j][t];
                if (dist < minv[t]) { minv[t] = dist; mini[t] = c; }
            }
        }
    }
    __syncthreads();
#pragma unroll
    for (int t = 0; t < TM; ++t) { pv[tid * TM + t] = minv[t]; pi[tid * TM + t] = mini[t]; }
    __syncthreads();
    {
        int t = tid & 15, g = tid >> 4;
        float bv = 3.4e38f; int bi = 0x7fffffff;
        for (int j = 0; j < 16; ++j) {
            int r2 = g + 16 * j;
            float vv = pv[r2 * TM + t]; int i2 = pi[r2 * TM + t];
            if (vv < bv || (vv == bv && i2 < bi)) { bv = vv; bi = i2; }
        }
        pv[g * TM + t] = bv; pi[g * TM + t] = bi;
    }
    __syncthreads();
    if (tid < TM) {
        int t = tid;
        float bv = 3.4e38f; int bi = 0x7fffffff;
        for (int g = 0; g < 16; ++g) {
            float vv = pv[g * TM + t]; int i2 = pi[g * TM + t];
            if (vv < bv || (vv == bv && i2 < bi)) { bv = vv; bi = i2; }
        }
        idxOut[tok0 + t] = bi;
    }
}

// ============================ launch ============================
extern "C" void kernel_launch(void* const* d_in, const int* in_sizes, int n_in,
                              void* d_out, int out_size, void* d_ws, size_t ws_size,
                              hipStream_t stream) {
    const float* x    = (const float*)d_in[0];
    const float* Wenc = (const float*)d_in[1];
    const float* benc = (const float*)d_in[2];
    const float* cent = (const float*)d_in[3];
    const float* Wdec = (const float*)d_in[4];
    const float* bdec = (const float*)d_in[5];
    float* out = (float*)d_out;

    const size_t L_B  = (size_t)N_TOK * TREC;            // 13631488 candidate lists
    const size_t XB_B = (size_t)N_TOK * KP * 2;          //  6291456 xbt
    const size_t CB_B = (size_t)K_CENT * D_DIM * 2;      //  2097152 cbt
    const size_t WB_B = (size_t)128 * D_DIM * 2;         //   131072 wbt
    const size_t GB_B = (size_t)K_CENT * KP * 2;         //   393216 Gbt
    const size_t N_B  = (size_t)K_CENT * 4;              //     8192 cnorm
    const size_t D_B  = (size_t)K_CENT * F_OUT * 4;      //   655360 dec
    const size_t NEED = L_B + XB_B + CB_B + WB_B + GB_B + N_B + D_B;

    if (ws_size >= NEED) {
        char* w = (char*)d_ws;
        char*           lists = w;                            w += L_B;
        unsigned short* xbt   = (unsigned short*)w;           w += XB_B;
        unsigned short* cbt   = (unsigned short*)w;           w += CB_B;
        unsigned short* wbt   = (unsigned short*)w;           w += WB_B;
        unsigned short* Gbt   = (unsigned short*)w;           w += GB_B;
        float*          cnorm = (float*)w;                    w += N_B;
        float*          dec   = (float*)w;

        k_prep_all<<<2064, 256, 0, stream>>>(x, Wenc, cent, cbt, wbt, xbt);
        k_gemm_g<<<16, 512, 0, stream>>>(wbt, cbt, Gbt);
        k_cadjf<<<K_CENT / 4, 256, 0, stream>>>(cent, benc, cnorm, Gbt);   // after gemm_g
        k_dec3<<<K_CENT / 4, 256, 0, stream>>>(cent, Wdec, bdec, dec);
        k_dist3<<<1024, 512, 0, stream>>>(xbt, Gbt, lists);
        k_merge3<<<2048, 256, 0, stream>>>(lists, cnorm, cent, x, Wenc, benc, dec, out);
    } else {
        float* centT = (float*)d_ws;
        float* cnorm = centT + (size_t)D_DIM * K_CENT;
        float* dec   = cnorm + K_CENT;
        int*   idx   = (int*)(dec + (size_t)K_CENT * F_OUT);
        k_transpose<<<dim3(K_CENT / 64, D_DIM / 64), 256, 0, stream>>>(cent, centT);
        k_cnorm<<<K_CENT / 4, 256, 0, stream>>>(cent, cnorm);
        k_dec<<<K_CENT, 128, 0, stream>>>(cent, Wdec, bdec, dec);
        k_main<<<N_TOK / TM, 256, 0, stream>>>(x, Wenc, benc, centT, cnorm, idx);
        k_out<<<N_TOK * F_OUT / 2560, 256, 0, stream>>>(dec, idx, out);
    }
}